// Round 3
// baseline (5535.664 us; speedup 1.0000x reference)
//
#include <hip/hip_runtime.h>
#include <math.h>

#define NB 32
#define NT 512
#define ND 256
#define NH 4
#define NLAYER 6
#define TOUT 2048

// ---------------- workspace layout (float offsets) ----------------
#define OFF_X    0ull          // 4,194,304   x / fused  [B,T,256]
#define OFF_FFH  4194304ull    // 16,777,216  ffn hidden [16384,1024]; later dec d1 [B,2048,256]
#define OFF_QKV  20971520ull   // 12,582,912  qkv [16384,768]; later dec d2 [B,2048,128] (8,388,608)
#define OFF_WT   29360128ull   // 884,736     transposed conv weights (tail of qkv region)
#define OFF_ATTN 33554432ull   // 4,194,304   attn out; later dp h1
#define OFF_PROJ 37748736ull   // 4,194,304   proj / ff2 out; later dp h2
#define OFF_E    41943040ull   // 8192        emotion e [B,256]
#define OFF_INT  41951232ull   // 131072 ints: dur, starts, totals, tok

// ---------------- embedding + positional encoding ----------------
__global__ __launch_bounds__(256) void embed_kernel(const int* __restrict__ text,
                                                    const float* __restrict__ emb,
                                                    float* __restrict__ x)
{
    const int row = blockIdx.x;            // b*512 + t
    const int d = threadIdx.x;
    const int t = row & (NT - 1);
    const int id = text[row];
    const int j2 = (d >> 1) * 2;
    const float c = -9.210340371976184f / 256.0f;   // -ln(10000)/D
    float freq = expf((float)j2 * c);
    float ang = (float)t * freq;
    float pe = (d & 1) ? cosf(ang) : sinf(ang);
    x[(size_t)row * ND + d] = emb[(size_t)id * ND + d] + pe;
}

// ---------------- fp32 single-wave GEMM: 64x64 tile, 8x8 split-frag micro ----------------
template<bool RELU>
__global__ __launch_bounds__(64) void gemm64_kernel(const float* __restrict__ A,
                                                    const float* __restrict__ B,
                                                    const float* __restrict__ bias,
                                                    float* __restrict__ C,
                                                    int M, int N, int K)
{
    __shared__ __align__(16) float As[16 * 68];   // [k][m], pitch 68
    __shared__ __align__(16) float Bs[16 * 68];   // [k][n]
    const int lane = threadIdx.x;
    const int row0 = blockIdx.y * 64, col0 = blockIdx.x * 64;
    const int r0 = (lane >> 3) << 2;
    const int c0 = (lane & 7) << 2;
    float acc[8][8] = {};

    for (int k0 = 0; k0 < K; k0 += 16) {
#pragma unroll
        for (int it = 0; it < 4; ++it) {
            int r = it * 16 + (lane >> 2);
            int kq = (lane & 3) << 2;
            float4 v = *(const float4*)&A[(size_t)(row0 + r) * K + k0 + kq];
            As[(kq + 0) * 68 + r] = v.x;
            As[(kq + 1) * 68 + r] = v.y;
            As[(kq + 2) * 68 + r] = v.z;
            As[(kq + 3) * 68 + r] = v.w;
        }
#pragma unroll
        for (int it = 0; it < 4; ++it) {
            int kk = it * 4 + (lane >> 4);
            int n4 = (lane & 15) << 2;
            *(float4*)&Bs[kk * 68 + n4] =
                *(const float4*)&B[(size_t)(k0 + kk) * N + col0 + n4];
        }
        __syncthreads();
#pragma unroll
        for (int k = 0; k < 16; ++k) {
            float4 a0 = *(const float4*)&As[k * 68 + r0];
            float4 a1 = *(const float4*)&As[k * 68 + 32 + r0];
            float4 b0 = *(const float4*)&Bs[k * 68 + c0];
            float4 b1 = *(const float4*)&Bs[k * 68 + 32 + c0];
            float aa[8] = {a0.x, a0.y, a0.z, a0.w, a1.x, a1.y, a1.z, a1.w};
            float bb[8] = {b0.x, b0.y, b0.z, b0.w, b1.x, b1.y, b1.z, b1.w};
#pragma unroll
            for (int i = 0; i < 8; ++i)
#pragma unroll
                for (int j = 0; j < 8; ++j)
                    acc[i][j] = fmaf(aa[i], bb[j], acc[i][j]);
        }
        __syncthreads();
    }
    float4 bv0 = *(const float4*)(bias + col0 + c0);
    float4 bv1 = *(const float4*)(bias + col0 + 32 + c0);
    float bb[8] = {bv0.x, bv0.y, bv0.z, bv0.w, bv1.x, bv1.y, bv1.z, bv1.w};
#pragma unroll
    for (int ih = 0; ih < 2; ++ih)
#pragma unroll
        for (int i = 0; i < 4; ++i) {
            int row = row0 + ih * 32 + r0 + i;
#pragma unroll
            for (int jh = 0; jh < 2; ++jh) {
                float4 r;
                r.x = acc[ih * 4 + i][jh * 4 + 0] + bb[jh * 4 + 0];
                r.y = acc[ih * 4 + i][jh * 4 + 1] + bb[jh * 4 + 1];
                r.z = acc[ih * 4 + i][jh * 4 + 2] + bb[jh * 4 + 2];
                r.w = acc[ih * 4 + i][jh * 4 + 3] + bb[jh * 4 + 3];
                if (RELU) {
                    r.x = fmaxf(r.x, 0.f); r.y = fmaxf(r.y, 0.f);
                    r.z = fmaxf(r.z, 0.f); r.w = fmaxf(r.w, 0.f);
                }
                *(float4*)&C[(size_t)row * N + col0 + jh * 32 + c0] = r;
            }
        }
}

// ---------------- attention v2: online softmax, q-tile 64, chunk 64 ----------------
#define SWZ(blk, d) ((((blk) ^ (d)) & 15) << 2)

__global__ __launch_bounds__(256) void attn2_kernel(const float* __restrict__ qkv,
                                                    float* __restrict__ out)
{
    __shared__ float sQT[64 * 64];   // Q^T [d][r], swizzled blocks, pitch 64
    __shared__ float sKV[64 * 68];   // K^T [d][c] swizzled pitch 64; then V [c][d] pitch 68
    __shared__ float sPT[64 * 68];   // P^T [c][r], pitch 68
    __shared__ float sM[64], sL[64], sA[64];
    const int tid = threadIdx.x;
    const int tb = blockIdx.x, h = blockIdx.y, b = blockIdx.z;
    const int t0 = tb * 64;
    const size_t base = (size_t)b * NT * 768;
    const int qoff = h * 64;
    const int g4 = tid >> 4;    // 0..15
    const int l4 = tid & 15;    // 0..15

#pragma unroll
    for (int it = 0; it < 4; ++it) {
        int i = it * 256 + tid;
        int r = i >> 4, d4 = (i & 15) << 2;
        float4 v = *(const float4*)&qkv[base + (size_t)(t0 + r) * 768 + qoff + d4];
        float vv[4] = {v.x, v.y, v.z, v.w};
#pragma unroll
        for (int j = 0; j < 4; ++j)
            sQT[(d4 + j) * 64 + SWZ(r >> 2, d4 + j) + (r & 3)] = vv[j];
    }
    if (tid < 64) { sM[tid] = -3.0e38f; sL[tid] = 0.0f; }
    __syncthreads();

    float accO[4][4] = {};   // [d_i][r_j]

    for (int ch = 0; ch < 8; ++ch) {
        const int s0 = ch * 64;
        float4 kreg[4], vreg[4];
#pragma unroll
        for (int it = 0; it < 4; ++it) {
            int i = it * 256 + tid;
            int c = i >> 4, d4 = (i & 15) << 2;
            kreg[it] = *(const float4*)&qkv[base + (size_t)(s0 + c) * 768 + 256 + qoff + d4];
            vreg[it] = *(const float4*)&qkv[base + (size_t)(s0 + c) * 768 + 512 + qoff + d4];
        }
#pragma unroll
        for (int it = 0; it < 4; ++it) {
            int i = it * 256 + tid;
            int c = i >> 4, d4 = (i & 15) << 2;
            float kk[4] = {kreg[it].x, kreg[it].y, kreg[it].z, kreg[it].w};
#pragma unroll
            for (int j = 0; j < 4; ++j)
                sKV[(d4 + j) * 64 + SWZ(c >> 2, d4 + j) + (c & 3)] = kk[j];
        }
        __syncthreads();

        float acc[4][4] = {};
#pragma unroll 8
        for (int d = 0; d < 64; ++d) {
            float4 qa = *(const float4*)&sQT[d * 64 + SWZ(g4, d)];
            float4 kb = *(const float4*)&sKV[d * 64 + SWZ(l4, d)];
            float qq[4] = {qa.x, qa.y, qa.z, qa.w};
            float kk[4] = {kb.x, kb.y, kb.z, kb.w};
#pragma unroll
            for (int i = 0; i < 4; ++i)
#pragma unroll
                for (int j = 0; j < 4; ++j)
                    acc[i][j] = fmaf(qq[i], kk[j], acc[i][j]);
        }
#pragma unroll
        for (int i = 0; i < 4; ++i)
#pragma unroll
            for (int j = 0; j < 4; ++j)
                acc[i][j] *= 0.125f;

#pragma unroll
        for (int i = 0; i < 4; ++i) {
            float m = fmaxf(fmaxf(acc[i][0], acc[i][1]), fmaxf(acc[i][2], acc[i][3]));
#pragma unroll
            for (int o = 1; o < 16; o <<= 1) m = fmaxf(m, __shfl_xor(m, o));
            float mo = sM[g4 * 4 + i];
            float nm = fmaxf(mo, m);
            float al = expf(mo - nm);
            float s = 0.f;
#pragma unroll
            for (int j = 0; j < 4; ++j) {
                float p = expf(acc[i][j] - nm);
                acc[i][j] = p;
                s += p;
            }
#pragma unroll
            for (int o = 1; o < 16; o <<= 1) s += __shfl_xor(s, o);
            if (l4 == 0) {
                sM[g4 * 4 + i] = nm;
                sL[g4 * 4 + i] = sL[g4 * 4 + i] * al + s;
                sA[g4 * 4 + i] = al;
            }
        }
#pragma unroll
        for (int j = 0; j < 4; ++j)
            *(float4*)&sPT[(l4 * 4 + j) * 68 + g4 * 4] =
                make_float4(acc[0][j], acc[1][j], acc[2][j], acc[3][j]);
        __syncthreads();

#pragma unroll
        for (int it = 0; it < 4; ++it) {
            int i = it * 256 + tid;
            int c = i >> 4, d4 = (i & 15) << 2;
            *(float4*)&sKV[c * 68 + d4] = vreg[it];
        }
        __syncthreads();

        float4 alj = *(const float4*)&sA[l4 * 4];
        float alv[4] = {alj.x, alj.y, alj.z, alj.w};
#pragma unroll
        for (int i = 0; i < 4; ++i)
#pragma unroll
            for (int j = 0; j < 4; ++j)
                accO[i][j] *= alv[j];
#pragma unroll 8
        for (int c = 0; c < 64; ++c) {
            float4 va = *(const float4*)&sKV[c * 68 + g4 * 4];
            float4 pb = *(const float4*)&sPT[c * 68 + l4 * 4];
            float vv[4] = {va.x, va.y, va.z, va.w};
            float pp[4] = {pb.x, pb.y, pb.z, pb.w};
#pragma unroll
            for (int i = 0; i < 4; ++i)
#pragma unroll
                for (int j = 0; j < 4; ++j)
                    accO[i][j] = fmaf(vv[i], pp[j], accO[i][j]);
        }
        __syncthreads();
    }

    float4 lf = *(const float4*)&sL[l4 * 4];
    float linv[4] = {1.f / lf.x, 1.f / lf.y, 1.f / lf.z, 1.f / lf.w};
#pragma unroll
    for (int j = 0; j < 4; ++j) {
        float4 r;
        r.x = accO[0][j] * linv[j];
        r.y = accO[1][j] * linv[j];
        r.z = accO[2][j] * linv[j];
        r.w = accO[3][j] * linv[j];
        *(float4*)&out[((size_t)b * NT + t0 + l4 * 4 + j) * ND + qoff + g4 * 4] = r;
    }
}

// ---------------- x = LayerNorm(x + y) ----------------
__global__ __launch_bounds__(256) void add_ln_kernel(float* __restrict__ x,
                                                     const float* __restrict__ y,
                                                     const float* __restrict__ g,
                                                     const float* __restrict__ bta)
{
    __shared__ float red[8];
    const size_t row = blockIdx.x;
    const int d = threadIdx.x;
    float v = x[row * ND + d] + y[row * ND + d];
    float s = v;
#pragma unroll
    for (int o = 32; o; o >>= 1) s += __shfl_down(s, o);
    if ((d & 63) == 0) red[d >> 6] = s;
    __syncthreads();
    float m = (red[0] + red[1] + red[2] + red[3]) * (1.0f / 256.0f);
    float dv = v - m;
    float s2 = dv * dv;
#pragma unroll
    for (int o = 32; o; o >>= 1) s2 += __shfl_down(s2, o);
    if ((d & 63) == 0) red[4 + (d >> 6)] = s2;
    __syncthreads();
    float var = (red[4] + red[5] + red[6] + red[7]) * (1.0f / 256.0f);
    float r = 1.0f / sqrtf(var + 1e-5f);
    x[row * ND + d] = dv * r * g[d] + bta[d];
}

// ---------------- emotion MLP ----------------
__global__ __launch_bounds__(256) void emotion_kernel(const float* __restrict__ emo,
                                                      const float* __restrict__ We1,
                                                      const float* __restrict__ be1,
                                                      const float* __restrict__ We2,
                                                      const float* __restrict__ be2,
                                                      float* __restrict__ e)
{
    const int b = blockIdx.x, d = threadIdx.x;
    const float em = emo[b];
    float acc = be2[d];
    for (int j = 0; j < 64; ++j) {
        float h = fmaxf(em * We1[j] + be1[j], 0.0f);
        acc = fmaf(h, We2[j * ND + d], acc);
    }
    e[b * ND + d] = acc;
}

__global__ __launch_bounds__(256) void addfuse_kernel(float* __restrict__ x,
                                                      const float* __restrict__ e)
{
    const int row = blockIdx.x;
    const int d = threadIdx.x;
    x[(size_t)row * ND + d] += e[(row >> 9) * ND + d];
}

// ---------------- conv weight transpose: w[O,I,K] -> wt[k][c][o] ----------------
__global__ __launch_bounds__(256) void wtrans_kernel(const float* __restrict__ w,
                                                     float* __restrict__ wt,
                                                     int CIN, int COUT, int KS)
{
    int gid = blockIdx.x * 256 + threadIdx.x;
    int total = CIN * COUT * KS;
    if (gid >= total) return;
    int o = gid % COUT;
    int r = gid / COUT;
    int c = r % CIN;
    int k = r / CIN;
    wt[gid] = w[(o * CIN + c) * KS + k];
}

// ---------------- GEMM-style conv: t-major [B,T,CIN] -> [B,T,COUT] ----------------
// Single-wave WG computes TM t-positions x 64 out-channels. Input staged transposed
// [c][t] in LDS; the k-shift is resolved as compile-time register selects from two
// aligned b128 reads. Weights pre-transposed to [k][c][o] for coalesced staging.
template<int CIN, int KS, int TM, bool RELU, bool BN, bool GATHER>
__global__ __launch_bounds__(64, 2) void convg_kernel(const float* __restrict__ in,
                                                      const float* __restrict__ wt,
                                                      const float* __restrict__ bias,
                                                      const float* __restrict__ bng,
                                                      const float* __restrict__ bnb,
                                                      const float* __restrict__ bnm,
                                                      const float* __restrict__ bnv,
                                                      const int* __restrict__ tok,
                                                      float* __restrict__ out,
                                                      int T, int in_T, int COUT)
{
    constexpr int PAD = (KS - 1) / 2;
    constexpr int TEXT = TM + KS - 1;
    constexpr int PITCH = (TM == 64) ? 84 : 140;   // 16B-aligned rows, 2-way max on writes
    constexpr int RH = TM / 32;                    // row halves
    __shared__ __align__(16) float As[16 * PITCH];     // [ci][tlocal]
    __shared__ __align__(16) float Bs[16 * KS * 68];   // [(k*16+ci)][o], pitch 68
    const int lane = threadIdx.x;
    const int b = blockIdx.z;
    const int t0 = blockIdx.x * TM;
    const int o0 = blockIdx.y * 64;
    const int r0 = (lane >> 3) << 2;   // 0,4,...,28
    const int c0 = (lane & 7) << 2;    // 0,4,...,28
    float acc[RH * 4][8] = {};

    for (int cc = 0; cc < CIN; cc += 16) {
        // stage A transposed: As[ci][t], t in [0, TEXT), t_global = t0 - PAD + t
        for (int i = lane; i < TEXT * 4; i += 64) {
            int t = i >> 2, q = i & 3;
            int tg = t0 - PAD + t;
            float4 v = make_float4(0.f, 0.f, 0.f, 0.f);
            if (tg >= 0 && tg < T) {
                long row;
                if (GATHER) {
                    int tk = tok[b * T + tg];
                    row = (tk >= 0) ? ((long)b * in_T + tk) : -1;
                } else {
                    row = (long)b * T + tg;
                }
                if (row >= 0) v = *(const float4*)&in[row * CIN + cc + (q << 2)];
            }
            As[((q << 2) + 0) * PITCH + t] = v.x;
            As[((q << 2) + 1) * PITCH + t] = v.y;
            As[((q << 2) + 2) * PITCH + t] = v.z;
            As[((q << 2) + 3) * PITCH + t] = v.w;
        }
        // stage B: row = k*16 + ci, coalesced from wt[k][c][o]
        for (int i = lane; i < KS * 256; i += 64) {
            int row = i >> 4, o4 = (i & 15) << 2;
            int k = row >> 4, ci = row & 15;
            *(float4*)&Bs[row * 68 + o4] =
                *(const float4*)&wt[(size_t)(k * CIN + cc + ci) * COUT + o0 + o4];
        }
        __syncthreads();
#pragma unroll 4
        for (int ci = 0; ci < 16; ++ci) {
            float a[RH][8];
#pragma unroll
            for (int rh = 0; rh < RH; ++rh) {
                float4 A0 = *(const float4*)&As[ci * PITCH + rh * 32 + r0];
                float4 A1 = *(const float4*)&As[ci * PITCH + rh * 32 + r0 + 4];
                a[rh][0] = A0.x; a[rh][1] = A0.y; a[rh][2] = A0.z; a[rh][3] = A0.w;
                a[rh][4] = A1.x; a[rh][5] = A1.y; a[rh][6] = A1.z; a[rh][7] = A1.w;
            }
#pragma unroll
            for (int k = 0; k < KS; ++k) {
                float4 b0 = *(const float4*)&Bs[(k * 16 + ci) * 68 + c0];
                float4 b1 = *(const float4*)&Bs[(k * 16 + ci) * 68 + 32 + c0];
                float bb[8] = {b0.x, b0.y, b0.z, b0.w, b1.x, b1.y, b1.z, b1.w};
#pragma unroll
                for (int rh = 0; rh < RH; ++rh)
#pragma unroll
                    for (int i = 0; i < 4; ++i)
#pragma unroll
                        for (int j = 0; j < 8; ++j)
                            acc[rh * 4 + i][j] = fmaf(a[rh][i + k], bb[j], acc[rh * 4 + i][j]);
            }
        }
        __syncthreads();
    }

    // epilogue: bias, relu, then BN (reference order: bn(relu(conv)))
    float4 bi0 = *(const float4*)(bias + o0 + c0);
    float4 bi1 = *(const float4*)(bias + o0 + 32 + c0);
    float bb[8] = {bi0.x, bi0.y, bi0.z, bi0.w, bi1.x, bi1.y, bi1.z, bi1.w};
    float sc[8], sh[8];
    if (BN) {
        float4 g0 = *(const float4*)(bng + o0 + c0);
        float4 g1 = *(const float4*)(bng + o0 + 32 + c0);
        float4 t0v = *(const float4*)(bnb + o0 + c0);
        float4 t1v = *(const float4*)(bnb + o0 + 32 + c0);
        float4 m0 = *(const float4*)(bnm + o0 + c0);
        float4 m1 = *(const float4*)(bnm + o0 + 32 + c0);
        float4 v0 = *(const float4*)(bnv + o0 + c0);
        float4 v1 = *(const float4*)(bnv + o0 + 32 + c0);
        float gg[8] = {g0.x, g0.y, g0.z, g0.w, g1.x, g1.y, g1.z, g1.w};
        float tb[8] = {t0v.x, t0v.y, t0v.z, t0v.w, t1v.x, t1v.y, t1v.z, t1v.w};
        float mm[8] = {m0.x, m0.y, m0.z, m0.w, m1.x, m1.y, m1.z, m1.w};
        float vv[8] = {v0.x, v0.y, v0.z, v0.w, v1.x, v1.y, v1.z, v1.w};
#pragma unroll
        for (int j = 0; j < 8; ++j) {
            sc[j] = gg[j] / sqrtf(vv[j] + 1e-5f);
            sh[j] = tb[j] - mm[j] * sc[j];
        }
    }
#pragma unroll
    for (int rh = 0; rh < RH; ++rh)
#pragma unroll
        for (int i = 0; i < 4; ++i) {
            int r = t0 + rh * 32 + r0 + i;
#pragma unroll
            for (int jh = 0; jh < 2; ++jh) {
                float o4[4];
#pragma unroll
                for (int j = 0; j < 4; ++j) {
                    float yv = acc[rh * 4 + i][jh * 4 + j] + bb[jh * 4 + j];
                    if (RELU) yv = fmaxf(yv, 0.0f);
                    if (BN) yv = yv * sc[jh * 4 + j] + sh[jh * 4 + j];
                    o4[j] = yv;
                }
                *(float4*)&out[((size_t)b * T + r) * COUT + o0 + jh * 32 + c0] =
                    make_float4(o4[0], o4[1], o4[2], o4[3]);
            }
        }
}

// ---------------- duration: log_dur -> dur ----------------
__global__ __launch_bounds__(256) void dur_kernel(const float* __restrict__ h2,
                                                  const float* __restrict__ wo,
                                                  const float* __restrict__ bo,
                                                  int* __restrict__ dur)
{
    __shared__ float red[4];
    const int row = blockIdx.x;
    const int c = threadIdx.x;
    float s = h2[(size_t)row * ND + c] * wo[c];
#pragma unroll
    for (int o = 32; o; o >>= 1) s += __shfl_down(s, o);
    if ((c & 63) == 0) red[c >> 6] = s;
    __syncthreads();
    if (c == 0) {
        float ld = red[0] + red[1] + red[2] + red[3] + bo[0];
        float d = rintf(expf(ld));
        d = fminf(fmaxf(d, 1.0f), 8.0f);
        dur[row] = (int)d;
    }
}

__global__ __launch_bounds__(64) void scan_kernel(const int* __restrict__ dur,
                                                  int* __restrict__ starts,
                                                  int* __restrict__ totals)
{
    const int b = threadIdx.x;
    if (b >= NB) return;
    int acc = 0;
    for (int t = 0; t < NT; ++t) {
        starts[b * NT + t] = acc;
        acc += dur[b * NT + t];
    }
    totals[b] = acc;
}

__global__ __launch_bounds__(256) void tok_kernel(const int* __restrict__ starts,
                                                  const int* __restrict__ totals,
                                                  int* __restrict__ tok)
{
    const int gid = blockIdx.x * 256 + threadIdx.x;   // 65536
    const int b = gid >> 11, p = gid & (TOUT - 1);
    const int total = totals[b];
    int res = -1;
    if (p < total) {
        const int* st = starts + b * NT;
        int lo = 0, hi = NT - 1;
        while (lo < hi) {
            int mid = (lo + hi + 1) >> 1;
            if (st[mid] <= p) lo = mid; else hi = mid - 1;
        }
        res = lo;
    }
    tok[gid] = res;
}

// ---------------- decoder conv3: [B,2048,128] -> wav [B,2048] ----------------
__global__ __launch_bounds__(256) void conv3_kernel(const float* __restrict__ in,
                                                    const float* __restrict__ w,
                                                    const float* __restrict__ bias,
                                                    float* __restrict__ out)
{
    const int gid = blockIdx.x * 256 + threadIdx.x;   // 65536
    const int b = gid >> 11, t = gid & (TOUT - 1);
    float acc = bias[0];
#pragma unroll
    for (int k = 0; k < 5; ++k) {
        int t2 = t + k - 2;
        if (t2 < 0 || t2 >= TOUT) continue;
        const float* row = in + ((size_t)b * TOUT + t2) * 128;
        for (int c = 0; c < 128; ++c) acc = fmaf(row[c], w[c * 5 + k], acc);
    }
    out[gid] = acc;
}

// ---------------- orchestration ----------------
extern "C" void kernel_launch(void* const* d_in, const int* in_sizes, int n_in,
                              void* d_out, int out_size, void* d_ws, size_t ws_size,
                              hipStream_t stream)
{
    const int*   text    = (const int*)d_in[0];
    const float* emotion = (const float*)d_in[1];
    const float* emb     = (const float*)d_in[2];
    const float* Wqkv    = (const float*)d_in[3];
    const float* bqkv    = (const float*)d_in[4];
    const float* Wo      = (const float*)d_in[5];
    const float* bo      = (const float*)d_in[6];
    const float* W1      = (const float*)d_in[7];
    const float* b1      = (const float*)d_in[8];
    const float* W2      = (const float*)d_in[9];
    const float* b2      = (const float*)d_in[10];
    const float* ln1g    = (const float*)d_in[11];
    const float* ln1b    = (const float*)d_in[12];
    const float* ln2g    = (const float*)d_in[13];
    const float* ln2b    = (const float*)d_in[14];
    const float* We1     = (const float*)d_in[15];
    const float* be1     = (const float*)d_in[16];
    const float* We2     = (const float*)d_in[17];
    const float* be2     = (const float*)d_in[18];
    const float* dp_w1   = (const float*)d_in[19];
    const float* dp_b1   = (const float*)d_in[20];
    const float* dp_g1   = (const float*)d_in[21];
    const float* dp_bt1  = (const float*)d_in[22];
    const float* dp_m1   = (const float*)d_in[23];
    const float* dp_v1   = (const float*)d_in[24];
    const float* dp_w2   = (const float*)d_in[25];
    const float* dp_b2   = (const float*)d_in[26];
    const float* dp_g2   = (const float*)d_in[27];
    const float* dp_bt2  = (const float*)d_in[28];
    const float* dp_m2   = (const float*)d_in[29];
    const float* dp_v2   = (const float*)d_in[30];
    const float* dp_wo   = (const float*)d_in[31];
    const float* dp_bo   = (const float*)d_in[32];
    const float* dec_w1  = (const float*)d_in[33];
    const float* dec_b1  = (const float*)d_in[34];
    const float* dec_w2  = (const float*)d_in[35];
    const float* dec_b2  = (const float*)d_in[36];
    const float* dec_w3  = (const float*)d_in[37];
    const float* dec_b3  = (const float*)d_in[38];

    float* ws   = (float*)d_ws;
    float* x    = ws + OFF_X;
    float* ffh  = ws + OFF_FFH;
    float* qkvb = ws + OFF_QKV;
    float* attb = ws + OFF_ATTN;
    float* prjb = ws + OFF_PROJ;
    float* ebuf = ws + OFF_E;
    float* wtdp1 = ws + OFF_WT;            // 196608
    float* wtdp2 = wtdp1 + 196608;         // 196608
    float* wtd1  = wtdp2 + 196608;         // 327680
    float* wtd2  = wtd1 + 327680;          // 163840
    int*   ip     = (int*)(ws + OFF_INT);
    int*   durb   = ip;
    int*   startb = ip + 16384;
    int*   totb   = ip + 32768;
    int*   tokb   = ip + 32832;

    const int M = NB * NT;   // 16384

    embed_kernel<<<M, 256, 0, stream>>>(text, emb, x);

    for (int l = 0; l < NLAYER; ++l) {
        gemm64_kernel<false><<<dim3(12, M / 64), 64, 0, stream>>>(
            x, Wqkv + (size_t)l * ND * 3 * ND, bqkv + l * 3 * ND, qkvb, M, 3 * ND, ND);
        attn2_kernel<<<dim3(NT / 64, NH, NB), 256, 0, stream>>>(qkvb, attb);
        gemm64_kernel<false><<<dim3(4, M / 64), 64, 0, stream>>>(
            attb, Wo + (size_t)l * ND * ND, bo + l * ND, prjb, M, ND, ND);
        add_ln_kernel<<<M, 256, 0, stream>>>(x, prjb, ln1g + l * ND, ln1b + l * ND);
        gemm64_kernel<true><<<dim3(16, M / 64), 64, 0, stream>>>(
            x, W1 + (size_t)l * ND * 4 * ND, b1 + l * 4 * ND, ffh, M, 4 * ND, ND);
        gemm64_kernel<false><<<dim3(4, M / 64), 64, 0, stream>>>(
            ffh, W2 + (size_t)l * 4 * ND * ND, b2 + l * ND, prjb, M, ND, 4 * ND);
        add_ln_kernel<<<M, 256, 0, stream>>>(x, prjb, ln2g + l * ND, ln2b + l * ND);
    }

    emotion_kernel<<<NB, 256, 0, stream>>>(emotion, We1, be1, We2, be2, ebuf);
    addfuse_kernel<<<M, 256, 0, stream>>>(x, ebuf);

    // transpose conv weights to [k][c][o] (workspace is re-poisoned every call)
    wtrans_kernel<<<(256 * 256 * 3 + 255) / 256, 256, 0, stream>>>(dp_w1, wtdp1, 256, 256, 3);
    wtrans_kernel<<<(256 * 256 * 3 + 255) / 256, 256, 0, stream>>>(dp_w2, wtdp2, 256, 256, 3);
    wtrans_kernel<<<(256 * 256 * 5 + 255) / 256, 256, 0, stream>>>(dec_w1, wtd1, 256, 256, 5);
    wtrans_kernel<<<(128 * 256 * 5 + 255) / 256, 256, 0, stream>>>(dec_w2, wtd2, 256, 128, 5);

    // duration predictor convs (fp32 mandatory: feeds dur rounding)
    convg_kernel<256, 3, 64, true, true, false><<<dim3(NT / 64, 4, NB), 64, 0, stream>>>(
        x, wtdp1, dp_b1, dp_g1, dp_bt1, dp_m1, dp_v1, nullptr, attb, NT, NT, 256);
    convg_kernel<256, 3, 64, true, true, false><<<dim3(NT / 64, 4, NB), 64, 0, stream>>>(
        attb, wtdp2, dp_b2, dp_g2, dp_bt2, dp_m2, dp_v2, nullptr, prjb, NT, NT, 256);
    dur_kernel<<<M, 256, 0, stream>>>(prjb, dp_wo, dp_bo, durb);
    scan_kernel<<<1, 64, 0, stream>>>(durb, startb, totb);
    tok_kernel<<<NB * TOUT / 256, 256, 0, stream>>>(startb, totb, tokb);

    // decoder convs (TM=128 tiles; conv1 gathers regulated rows via tok[])
    convg_kernel<256, 5, 128, true, false, true><<<dim3(TOUT / 128, 4, NB), 64, 0, stream>>>(
        x, wtd1, dec_b1, nullptr, nullptr, nullptr, nullptr, tokb, ffh, TOUT, NT, 256);
    convg_kernel<256, 5, 128, true, false, false><<<dim3(TOUT / 128, 2, NB), 64, 0, stream>>>(
        ffh, wtd2, dec_b2, nullptr, nullptr, nullptr, nullptr, nullptr, qkvb, TOUT, TOUT, 128);
    conv3_kernel<<<NB * TOUT / 256, 256, 0, stream>>>(qkvb, dec_w3, dec_b3, (float*)d_out);
}

// Round 4
// 4600.809 us; speedup vs baseline: 1.2032x; 1.2032x over previous
//
#include <hip/hip_runtime.h>
#include <math.h>

#define NB 32
#define NT 512
#define ND 256
#define NH 4
#define NLAYER 6
#define TOUT 2048

// ---------------- workspace layout (float offsets) ----------------
#define OFF_X    0ull          // 4,194,304   x / fused  [B,T,256]
#define OFF_FFH  4194304ull    // 16,777,216  ffn hidden [16384,1024]; later dec d1 [B,2048,256]
#define OFF_QKV  20971520ull   // 12,582,912  qkv [16384,768]; later dec d2 [B,2048,128]
#define OFF_WT   29360128ull   // 884,736     transposed conv weights (tail of qkv region)
#define OFF_ATTN 33554432ull   // 4,194,304   attn out; later dp h1
#define OFF_PROJ 37748736ull   // 4,194,304   proj / ff2 out; later dp h2
#define OFF_E    41943040ull   // 8192        emotion e [B,256]
#define OFF_INT  41951232ull   // 131072 ints: dur, starts, totals, tok

// ---------------- embedding + positional encoding ----------------
__global__ __launch_bounds__(256) void embed_kernel(const int* __restrict__ text,
                                                    const float* __restrict__ emb,
                                                    float* __restrict__ x)
{
    const int row = blockIdx.x;            // b*512 + t
    const int d = threadIdx.x;
    const int t = row & (NT - 1);
    const int id = text[row];
    const int j2 = (d >> 1) * 2;
    const float c = -9.210340371976184f / 256.0f;   // -ln(10000)/D
    float freq = expf((float)j2 * c);
    float ang = (float)t * freq;
    float pe = (d & 1) ? cosf(ang) : sinf(ang);
    x[(size_t)row * ND + d] = emb[(size_t)id * ND + d] + pe;
}

// ---------------- fp32 multi-wave GEMM: 128x64 tile, 4 waves, 4x8 acc/lane ----------------
// block=256 (4 waves). Wave w computes rows [w*32, w*32+32) of the 128-row tile.
template<bool RELU>
__global__ __launch_bounds__(256, 4) void gemm256_kernel(const float* __restrict__ A,
                                                         const float* __restrict__ B,
                                                         const float* __restrict__ bias,
                                                         float* __restrict__ C,
                                                         int M, int N, int K)
{
    __shared__ __align__(16) float As[16 * 132];   // [k][m], pitch 132
    __shared__ __align__(16) float Bs[16 * 68];    // [k][n], pitch 68
    const int tid = threadIdx.x;
    const int lane = tid & 63, wave = tid >> 6;
    const int row0 = blockIdx.y * 128, col0 = blockIdx.x * 64;
    const int wt0 = wave * 32;
    const int r0 = (lane >> 3) << 2;   // 0..28
    const int c0 = (lane & 7) << 2;    // 0..28
    float acc[4][8] = {};

    for (int k0 = 0; k0 < K; k0 += 16) {
        // stage A transposed: As[k][m]  (128 rows x 16 k)
#pragma unroll
        for (int it = 0; it < 2; ++it) {
            int i = it * 256 + tid;
            int r = i >> 2, kq = (i & 3) << 2;
            float4 v = *(const float4*)&A[(size_t)(row0 + r) * K + k0 + kq];
            As[(kq + 0) * 132 + r] = v.x;
            As[(kq + 1) * 132 + r] = v.y;
            As[(kq + 2) * 132 + r] = v.z;
            As[(kq + 3) * 132 + r] = v.w;
        }
        // stage B natural: Bs[k][n]
        {
            int kk = tid >> 4, n4 = (tid & 15) << 2;
            *(float4*)&Bs[kk * 68 + n4] =
                *(const float4*)&B[(size_t)(k0 + kk) * N + col0 + n4];
        }
        __syncthreads();
#pragma unroll
        for (int k = 0; k < 16; ++k) {
            float4 av = *(const float4*)&As[k * 132 + wt0 + r0];
            float4 b0 = *(const float4*)&Bs[k * 68 + c0];
            float4 b1 = *(const float4*)&Bs[k * 68 + 32 + c0];
            float aa[4] = {av.x, av.y, av.z, av.w};
            float bb[8] = {b0.x, b0.y, b0.z, b0.w, b1.x, b1.y, b1.z, b1.w};
#pragma unroll
            for (int i = 0; i < 4; ++i)
#pragma unroll
                for (int j = 0; j < 8; ++j)
                    acc[i][j] = fmaf(aa[i], bb[j], acc[i][j]);
        }
        __syncthreads();
    }
    float4 bv0 = *(const float4*)(bias + col0 + c0);
    float4 bv1 = *(const float4*)(bias + col0 + 32 + c0);
    float bb[8] = {bv0.x, bv0.y, bv0.z, bv0.w, bv1.x, bv1.y, bv1.z, bv1.w};
#pragma unroll
    for (int i = 0; i < 4; ++i) {
        int row = row0 + wt0 + r0 + i;
#pragma unroll
        for (int jh = 0; jh < 2; ++jh) {
            float4 r;
            r.x = acc[i][jh * 4 + 0] + bb[jh * 4 + 0];
            r.y = acc[i][jh * 4 + 1] + bb[jh * 4 + 1];
            r.z = acc[i][jh * 4 + 2] + bb[jh * 4 + 2];
            r.w = acc[i][jh * 4 + 3] + bb[jh * 4 + 3];
            if (RELU) {
                r.x = fmaxf(r.x, 0.f); r.y = fmaxf(r.y, 0.f);
                r.z = fmaxf(r.z, 0.f); r.w = fmaxf(r.w, 0.f);
            }
            *(float4*)&C[(size_t)row * N + col0 + jh * 32 + c0] = r;
        }
    }
}

// ---------------- attention v2: online softmax, q-tile 64, chunk 64 ----------------
#define SWZ(blk, d) ((((blk) ^ (d)) & 15) << 2)

__global__ __launch_bounds__(256) void attn2_kernel(const float* __restrict__ qkv,
                                                    float* __restrict__ out)
{
    __shared__ float sQT[64 * 64];   // Q^T [d][r], swizzled blocks, pitch 64
    __shared__ float sKV[64 * 68];   // K^T [d][c] swizzled pitch 64; then V [c][d] pitch 68
    __shared__ float sPT[64 * 68];   // P^T [c][r], pitch 68
    __shared__ float sM[64], sL[64], sA[64];
    const int tid = threadIdx.x;
    const int tb = blockIdx.x, h = blockIdx.y, b = blockIdx.z;
    const int t0 = tb * 64;
    const size_t base = (size_t)b * NT * 768;
    const int qoff = h * 64;
    const int g4 = tid >> 4;    // 0..15
    const int l4 = tid & 15;    // 0..15

#pragma unroll
    for (int it = 0; it < 4; ++it) {
        int i = it * 256 + tid;
        int r = i >> 4, d4 = (i & 15) << 2;
        float4 v = *(const float4*)&qkv[base + (size_t)(t0 + r) * 768 + qoff + d4];
        float vv[4] = {v.x, v.y, v.z, v.w};
#pragma unroll
        for (int j = 0; j < 4; ++j)
            sQT[(d4 + j) * 64 + SWZ(r >> 2, d4 + j) + (r & 3)] = vv[j];
    }
    if (tid < 64) { sM[tid] = -3.0e38f; sL[tid] = 0.0f; }
    __syncthreads();

    float accO[4][4] = {};   // [d_i][r_j]

    for (int ch = 0; ch < 8; ++ch) {
        const int s0 = ch * 64;
        float4 kreg[4], vreg[4];
#pragma unroll
        for (int it = 0; it < 4; ++it) {
            int i = it * 256 + tid;
            int c = i >> 4, d4 = (i & 15) << 2;
            kreg[it] = *(const float4*)&qkv[base + (size_t)(s0 + c) * 768 + 256 + qoff + d4];
            vreg[it] = *(const float4*)&qkv[base + (size_t)(s0 + c) * 768 + 512 + qoff + d4];
        }
#pragma unroll
        for (int it = 0; it < 4; ++it) {
            int i = it * 256 + tid;
            int c = i >> 4, d4 = (i & 15) << 2;
            float kk[4] = {kreg[it].x, kreg[it].y, kreg[it].z, kreg[it].w};
#pragma unroll
            for (int j = 0; j < 4; ++j)
                sKV[(d4 + j) * 64 + SWZ(c >> 2, d4 + j) + (c & 3)] = kk[j];
        }
        __syncthreads();

        float acc[4][4] = {};
#pragma unroll 8
        for (int d = 0; d < 64; ++d) {
            float4 qa = *(const float4*)&sQT[d * 64 + SWZ(g4, d)];
            float4 kb = *(const float4*)&sKV[d * 64 + SWZ(l4, d)];
            float qq[4] = {qa.x, qa.y, qa.z, qa.w};
            float kk[4] = {kb.x, kb.y, kb.z, kb.w};
#pragma unroll
            for (int i = 0; i < 4; ++i)
#pragma unroll
                for (int j = 0; j < 4; ++j)
                    acc[i][j] = fmaf(qq[i], kk[j], acc[i][j]);
        }
#pragma unroll
        for (int i = 0; i < 4; ++i)
#pragma unroll
            for (int j = 0; j < 4; ++j)
                acc[i][j] *= 0.125f;

#pragma unroll
        for (int i = 0; i < 4; ++i) {
            float m = fmaxf(fmaxf(acc[i][0], acc[i][1]), fmaxf(acc[i][2], acc[i][3]));
#pragma unroll
            for (int o = 1; o < 16; o <<= 1) m = fmaxf(m, __shfl_xor(m, o));
            float mo = sM[g4 * 4 + i];
            float nm = fmaxf(mo, m);
            float al = expf(mo - nm);
            float s = 0.f;
#pragma unroll
            for (int j = 0; j < 4; ++j) {
                float p = expf(acc[i][j] - nm);
                acc[i][j] = p;
                s += p;
            }
#pragma unroll
            for (int o = 1; o < 16; o <<= 1) s += __shfl_xor(s, o);
            if (l4 == 0) {
                sM[g4 * 4 + i] = nm;
                sL[g4 * 4 + i] = sL[g4 * 4 + i] * al + s;
                sA[g4 * 4 + i] = al;
            }
        }
#pragma unroll
        for (int j = 0; j < 4; ++j)
            *(float4*)&sPT[(l4 * 4 + j) * 68 + g4 * 4] =
                make_float4(acc[0][j], acc[1][j], acc[2][j], acc[3][j]);
        __syncthreads();

#pragma unroll
        for (int it = 0; it < 4; ++it) {
            int i = it * 256 + tid;
            int c = i >> 4, d4 = (i & 15) << 2;
            *(float4*)&sKV[c * 68 + d4] = vreg[it];
        }
        __syncthreads();

        float4 alj = *(const float4*)&sA[l4 * 4];
        float alv[4] = {alj.x, alj.y, alj.z, alj.w};
#pragma unroll
        for (int i = 0; i < 4; ++i)
#pragma unroll
            for (int j = 0; j < 4; ++j)
                accO[i][j] *= alv[j];
#pragma unroll 8
        for (int c = 0; c < 64; ++c) {
            float4 va = *(const float4*)&sKV[c * 68 + g4 * 4];
            float4 pb = *(const float4*)&sPT[c * 68 + l4 * 4];
            float vv[4] = {va.x, va.y, va.z, va.w};
            float pp[4] = {pb.x, pb.y, pb.z, pb.w};
#pragma unroll
            for (int i = 0; i < 4; ++i)
#pragma unroll
                for (int j = 0; j < 4; ++j)
                    accO[i][j] = fmaf(vv[i], pp[j], accO[i][j]);
        }
        __syncthreads();
    }

    float4 lf = *(const float4*)&sL[l4 * 4];
    float linv[4] = {1.f / lf.x, 1.f / lf.y, 1.f / lf.z, 1.f / lf.w};
#pragma unroll
    for (int j = 0; j < 4; ++j) {
        float4 r;
        r.x = accO[0][j] * linv[j];
        r.y = accO[1][j] * linv[j];
        r.z = accO[2][j] * linv[j];
        r.w = accO[3][j] * linv[j];
        *(float4*)&out[((size_t)b * NT + t0 + l4 * 4 + j) * ND + qoff + g4 * 4] = r;
    }
}

// ---------------- x = LayerNorm(x + y) ----------------
__global__ __launch_bounds__(256) void add_ln_kernel(float* __restrict__ x,
                                                     const float* __restrict__ y,
                                                     const float* __restrict__ g,
                                                     const float* __restrict__ bta)
{
    __shared__ float red[8];
    const size_t row = blockIdx.x;
    const int d = threadIdx.x;
    float v = x[row * ND + d] + y[row * ND + d];
    float s = v;
#pragma unroll
    for (int o = 32; o; o >>= 1) s += __shfl_down(s, o);
    if ((d & 63) == 0) red[d >> 6] = s;
    __syncthreads();
    float m = (red[0] + red[1] + red[2] + red[3]) * (1.0f / 256.0f);
    float dv = v - m;
    float s2 = dv * dv;
#pragma unroll
    for (int o = 32; o; o >>= 1) s2 += __shfl_down(s2, o);
    if ((d & 63) == 0) red[4 + (d >> 6)] = s2;
    __syncthreads();
    float var = (red[4] + red[5] + red[6] + red[7]) * (1.0f / 256.0f);
    float r = 1.0f / sqrtf(var + 1e-5f);
    x[row * ND + d] = dv * r * g[d] + bta[d];
}

// ---------------- emotion MLP ----------------
__global__ __launch_bounds__(256) void emotion_kernel(const float* __restrict__ emo,
                                                      const float* __restrict__ We1,
                                                      const float* __restrict__ be1,
                                                      const float* __restrict__ We2,
                                                      const float* __restrict__ be2,
                                                      float* __restrict__ e)
{
    const int b = blockIdx.x, d = threadIdx.x;
    const float em = emo[b];
    float acc = be2[d];
    for (int j = 0; j < 64; ++j) {
        float h = fmaxf(em * We1[j] + be1[j], 0.0f);
        acc = fmaf(h, We2[j * ND + d], acc);
    }
    e[b * ND + d] = acc;
}

__global__ __launch_bounds__(256) void addfuse_kernel(float* __restrict__ x,
                                                      const float* __restrict__ e)
{
    const int row = blockIdx.x;
    const int d = threadIdx.x;
    x[(size_t)row * ND + d] += e[(row >> 9) * ND + d];
}

// ---------------- conv weight transpose: w[O,I,K] -> wt[k][c][o] ----------------
__global__ __launch_bounds__(256) void wtrans_kernel(const float* __restrict__ w,
                                                     float* __restrict__ wt,
                                                     int CIN, int COUT, int KS)
{
    int gid = blockIdx.x * 256 + threadIdx.x;
    int total = CIN * COUT * KS;
    if (gid >= total) return;
    int o = gid % COUT;
    int r = gid / COUT;
    int c = r % CIN;
    int k = r / CIN;
    wt[gid] = w[(o * CIN + c) * KS + k];
}

// ---------------- GEMM-style conv v4: 4 waves/WG, tile 128t x 64o ----------------
// Input t-major [B,T,CIN]; staged transposed As[ci][t]; k-shift = register select.
// Weights pre-transposed wt[k][c][o]. Wave w owns t-rows [w*32, w*32+32).
template<int CIN, int KS, bool RELU, bool BN, bool GATHER>
__global__ __launch_bounds__(256, 4) void convg_kernel(const float* __restrict__ in,
                                                       const float* __restrict__ wt,
                                                       const float* __restrict__ bias,
                                                       const float* __restrict__ bng,
                                                       const float* __restrict__ bnb,
                                                       const float* __restrict__ bnm,
                                                       const float* __restrict__ bnv,
                                                       const int* __restrict__ tok,
                                                       float* __restrict__ out,
                                                       int T, int in_T, int COUT)
{
    constexpr int TM = 128;
    constexpr int PAD = (KS - 1) / 2;
    constexpr int TEXT = TM + KS - 1;
    constexpr int PITCH = (TEXT + 3) & ~3;          // 132 for KS=3 and KS=5
    __shared__ __align__(16) float As[16 * PITCH];      // [ci][tlocal]
    __shared__ __align__(16) float Bs[16 * KS * 68];    // [(k*16+ci)][o], pitch 68
    const int tid = threadIdx.x;
    const int lane = tid & 63, wave = tid >> 6;
    const int b = blockIdx.z;
    const int t0 = blockIdx.x * TM;
    const int o0 = blockIdx.y * 64;
    const int wt0 = wave * 32;
    const int r0 = (lane >> 3) << 2;   // 0..28
    const int c0 = (lane & 7) << 2;    // 0..28
    float acc[4][8] = {};

    for (int cc = 0; cc < CIN; cc += 16) {
        // stage A transposed: As[ci][t], t_global = t0 - PAD + t
        for (int i = tid; i < TEXT * 4; i += 256) {
            int t = i >> 2, q = i & 3;
            int tg = t0 - PAD + t;
            float4 v = make_float4(0.f, 0.f, 0.f, 0.f);
            if (tg >= 0 && tg < T) {
                long row;
                if (GATHER) {
                    int tk = tok[b * T + tg];
                    row = (tk >= 0) ? ((long)b * in_T + tk) : -1;
                } else {
                    row = (long)b * T + tg;
                }
                if (row >= 0) v = *(const float4*)&in[row * CIN + cc + (q << 2)];
            }
            As[((q << 2) + 0) * PITCH + t] = v.x;
            As[((q << 2) + 1) * PITCH + t] = v.y;
            As[((q << 2) + 2) * PITCH + t] = v.z;
            As[((q << 2) + 3) * PITCH + t] = v.w;
        }
        // stage B: row = k*16 + ci, coalesced from wt[k][c][o]
        for (int i = tid; i < KS * 256; i += 256) {
            int row = i >> 4, o4 = (i & 15) << 2;
            int k = row >> 4, ci = row & 15;
            *(float4*)&Bs[row * 68 + o4] =
                *(const float4*)&wt[(size_t)(k * CIN + cc + ci) * COUT + o0 + o4];
        }
        __syncthreads();
#pragma unroll 2
        for (int ci = 0; ci < 16; ++ci) {
            float a[8];
            float4 A0 = *(const float4*)&As[ci * PITCH + wt0 + r0];
            float4 A1 = *(const float4*)&As[ci * PITCH + wt0 + r0 + 4];
            a[0] = A0.x; a[1] = A0.y; a[2] = A0.z; a[3] = A0.w;
            a[4] = A1.x; a[5] = A1.y; a[6] = A1.z; a[7] = A1.w;
#pragma unroll
            for (int k = 0; k < KS; ++k) {
                float4 b0 = *(const float4*)&Bs[(k * 16 + ci) * 68 + c0];
                float4 b1 = *(const float4*)&Bs[(k * 16 + ci) * 68 + 32 + c0];
                float bb[8] = {b0.x, b0.y, b0.z, b0.w, b1.x, b1.y, b1.z, b1.w};
#pragma unroll
                for (int i = 0; i < 4; ++i)
#pragma unroll
                    for (int j = 0; j < 8; ++j)
                        acc[i][j] = fmaf(a[i + k], bb[j], acc[i][j]);
            }
        }
        __syncthreads();
    }

    // epilogue: bias, relu, then BN (reference order: bn(relu(conv)))
    float4 bi0 = *(const float4*)(bias + o0 + c0);
    float4 bi1 = *(const float4*)(bias + o0 + 32 + c0);
    float bb[8] = {bi0.x, bi0.y, bi0.z, bi0.w, bi1.x, bi1.y, bi1.z, bi1.w};
    float sc[8], sh[8];
    if (BN) {
        float4 g0 = *(const float4*)(bng + o0 + c0);
        float4 g1 = *(const float4*)(bng + o0 + 32 + c0);
        float4 t0v = *(const float4*)(bnb + o0 + c0);
        float4 t1v = *(const float4*)(bnb + o0 + 32 + c0);
        float4 m0 = *(const float4*)(bnm + o0 + c0);
        float4 m1 = *(const float4*)(bnm + o0 + 32 + c0);
        float4 v0 = *(const float4*)(bnv + o0 + c0);
        float4 v1 = *(const float4*)(bnv + o0 + 32 + c0);
        float gg[8] = {g0.x, g0.y, g0.z, g0.w, g1.x, g1.y, g1.z, g1.w};
        float tb[8] = {t0v.x, t0v.y, t0v.z, t0v.w, t1v.x, t1v.y, t1v.z, t1v.w};
        float mm[8] = {m0.x, m0.y, m0.z, m0.w, m1.x, m1.y, m1.z, m1.w};
        float vv[8] = {v0.x, v0.y, v0.z, v0.w, v1.x, v1.y, v1.z, v1.w};
#pragma unroll
        for (int j = 0; j < 8; ++j) {
            sc[j] = gg[j] / sqrtf(vv[j] + 1e-5f);
            sh[j] = tb[j] - mm[j] * sc[j];
        }
    }
#pragma unroll
    for (int i = 0; i < 4; ++i) {
        int r = t0 + wt0 + r0 + i;
#pragma unroll
        for (int jh = 0; jh < 2; ++jh) {
            float o4[4];
#pragma unroll
            for (int j = 0; j < 4; ++j) {
                float yv = acc[i][jh * 4 + j] + bb[jh * 4 + j];
                if (RELU) yv = fmaxf(yv, 0.0f);
                if (BN) yv = yv * sc[jh * 4 + j] + sh[jh * 4 + j];
                o4[j] = yv;
            }
            *(float4*)&out[((size_t)b * T + r) * COUT + o0 + jh * 32 + c0] =
                make_float4(o4[0], o4[1], o4[2], o4[3]);
        }
    }
}

// ---------------- duration: log_dur -> dur ----------------
__global__ __launch_bounds__(256) void dur_kernel(const float* __restrict__ h2,
                                                  const float* __restrict__ wo,
                                                  const float* __restrict__ bo,
                                                  int* __restrict__ dur)
{
    __shared__ float red[4];
    const int row = blockIdx.x;
    const int c = threadIdx.x;
    float s = h2[(size_t)row * ND + c] * wo[c];
#pragma unroll
    for (int o = 32; o; o >>= 1) s += __shfl_down(s, o);
    if ((c & 63) == 0) red[c >> 6] = s;
    __syncthreads();
    if (c == 0) {
        float ld = red[0] + red[1] + red[2] + red[3] + bo[0];
        float d = rintf(expf(ld));
        d = fminf(fmaxf(d, 1.0f), 8.0f);
        dur[row] = (int)d;
    }
}

__global__ __launch_bounds__(64) void scan_kernel(const int* __restrict__ dur,
                                                  int* __restrict__ starts,
                                                  int* __restrict__ totals)
{
    const int b = threadIdx.x;
    if (b >= NB) return;
    int acc = 0;
    for (int t = 0; t < NT; ++t) {
        starts[b * NT + t] = acc;
        acc += dur[b * NT + t];
    }
    totals[b] = acc;
}

__global__ __launch_bounds__(256) void tok_kernel(const int* __restrict__ starts,
                                                  const int* __restrict__ totals,
                                                  int* __restrict__ tok)
{
    const int gid = blockIdx.x * 256 + threadIdx.x;   // 65536
    const int b = gid >> 11, p = gid & (TOUT - 1);
    const int total = totals[b];
    int res = -1;
    if (p < total) {
        const int* st = starts + b * NT;
        int lo = 0, hi = NT - 1;
        while (lo < hi) {
            int mid = (lo + hi + 1) >> 1;
            if (st[mid] <= p) lo = mid; else hi = mid - 1;
        }
        res = lo;
    }
    tok[gid] = res;
}

// ---------------- decoder conv3: [B,2048,128] -> wav [B,2048] ----------------
__global__ __launch_bounds__(256) void conv3_kernel(const float* __restrict__ in,
                                                    const float* __restrict__ w,
                                                    const float* __restrict__ bias,
                                                    float* __restrict__ out)
{
    const int gid = blockIdx.x * 256 + threadIdx.x;   // 65536
    const int b = gid >> 11, t = gid & (TOUT - 1);
    float acc = bias[0];
#pragma unroll
    for (int k = 0; k < 5; ++k) {
        int t2 = t + k - 2;
        if (t2 < 0 || t2 >= TOUT) continue;
        const float* row = in + ((size_t)b * TOUT + t2) * 128;
        for (int c = 0; c < 128; ++c) acc = fmaf(row[c], w[c * 5 + k], acc);
    }
    out[gid] = acc;
}

// ---------------- orchestration ----------------
extern "C" void kernel_launch(void* const* d_in, const int* in_sizes, int n_in,
                              void* d_out, int out_size, void* d_ws, size_t ws_size,
                              hipStream_t stream)
{
    const int*   text    = (const int*)d_in[0];
    const float* emotion = (const float*)d_in[1];
    const float* emb     = (const float*)d_in[2];
    const float* Wqkv    = (const float*)d_in[3];
    const float* bqkv    = (const float*)d_in[4];
    const float* Wo      = (const float*)d_in[5];
    const float* bo      = (const float*)d_in[6];
    const float* W1      = (const float*)d_in[7];
    const float* b1      = (const float*)d_in[8];
    const float* W2      = (const float*)d_in[9];
    const float* b2      = (const float*)d_in[10];
    const float* ln1g    = (const float*)d_in[11];
    const float* ln1b    = (const float*)d_in[12];
    const float* ln2g    = (const float*)d_in[13];
    const float* ln2b    = (const float*)d_in[14];
    const float* We1     = (const float*)d_in[15];
    const float* be1     = (const float*)d_in[16];
    const float* We2     = (const float*)d_in[17];
    const float* be2     = (const float*)d_in[18];
    const float* dp_w1   = (const float*)d_in[19];
    const float* dp_b1   = (const float*)d_in[20];
    const float* dp_g1   = (const float*)d_in[21];
    const float* dp_bt1  = (const float*)d_in[22];
    const float* dp_m1   = (const float*)d_in[23];
    const float* dp_v1   = (const float*)d_in[24];
    const float* dp_w2   = (const float*)d_in[25];
    const float* dp_b2   = (const float*)d_in[26];
    const float* dp_g2   = (const float*)d_in[27];
    const float* dp_bt2  = (const float*)d_in[28];
    const float* dp_m2   = (const float*)d_in[29];
    const float* dp_v2   = (const float*)d_in[30];
    const float* dp_wo   = (const float*)d_in[31];
    const float* dp_bo   = (const float*)d_in[32];
    const float* dec_w1  = (const float*)d_in[33];
    const float* dec_b1  = (const float*)d_in[34];
    const float* dec_w2  = (const float*)d_in[35];
    const float* dec_b2  = (const float*)d_in[36];
    const float* dec_w3  = (const float*)d_in[37];
    const float* dec_b3  = (const float*)d_in[38];

    float* ws   = (float*)d_ws;
    float* x    = ws + OFF_X;
    float* ffh  = ws + OFF_FFH;
    float* qkvb = ws + OFF_QKV;
    float* attb = ws + OFF_ATTN;
    float* prjb = ws + OFF_PROJ;
    float* ebuf = ws + OFF_E;
    float* wtdp1 = ws + OFF_WT;            // 196608
    float* wtdp2 = wtdp1 + 196608;         // 196608
    float* wtd1  = wtdp2 + 196608;         // 327680
    float* wtd2  = wtd1 + 327680;          // 163840
    int*   ip     = (int*)(ws + OFF_INT);
    int*   durb   = ip;
    int*   startb = ip + 16384;
    int*   totb   = ip + 32768;
    int*   tokb   = ip + 32832;

    const int M = NB * NT;   // 16384

    embed_kernel<<<M, 256, 0, stream>>>(text, emb, x);

    for (int l = 0; l < NLAYER; ++l) {
        gemm256_kernel<false><<<dim3(12, M / 128), 256, 0, stream>>>(
            x, Wqkv + (size_t)l * ND * 3 * ND, bqkv + l * 3 * ND, qkvb, M, 3 * ND, ND);
        attn2_kernel<<<dim3(NT / 64, NH, NB), 256, 0, stream>>>(qkvb, attb);
        gemm256_kernel<false><<<dim3(4, M / 128), 256, 0, stream>>>(
            attb, Wo + (size_t)l * ND * ND, bo + l * ND, prjb, M, ND, ND);
        add_ln_kernel<<<M, 256, 0, stream>>>(x, prjb, ln1g + l * ND, ln1b + l * ND);
        gemm256_kernel<true><<<dim3(16, M / 128), 256, 0, stream>>>(
            x, W1 + (size_t)l * ND * 4 * ND, b1 + l * 4 * ND, ffh, M, 4 * ND, ND);
        gemm256_kernel<false><<<dim3(4, M / 128), 256, 0, stream>>>(
            ffh, W2 + (size_t)l * 4 * ND * ND, b2 + l * ND, prjb, M, ND, 4 * ND);
        add_ln_kernel<<<M, 256, 0, stream>>>(x, prjb, ln2g + l * ND, ln2b + l * ND);
    }

    emotion_kernel<<<NB, 256, 0, stream>>>(emotion, We1, be1, We2, be2, ebuf);
    addfuse_kernel<<<M, 256, 0, stream>>>(x, ebuf);

    // transpose conv weights to [k][c][o]
    wtrans_kernel<<<(256 * 256 * 3 + 255) / 256, 256, 0, stream>>>(dp_w1, wtdp1, 256, 256, 3);
    wtrans_kernel<<<(256 * 256 * 3 + 255) / 256, 256, 0, stream>>>(dp_w2, wtdp2, 256, 256, 3);
    wtrans_kernel<<<(256 * 256 * 5 + 255) / 256, 256, 0, stream>>>(dec_w1, wtd1, 256, 256, 5);
    wtrans_kernel<<<(128 * 256 * 5 + 255) / 256, 256, 0, stream>>>(dec_w2, wtd2, 256, 128, 5);

    // duration predictor convs (fp32 mandatory: feeds dur rounding)
    convg_kernel<256, 3, true, true, false><<<dim3(NT / 128, 4, NB), 256, 0, stream>>>(
        x, wtdp1, dp_b1, dp_g1, dp_bt1, dp_m1, dp_v1, nullptr, attb, NT, NT, 256);
    convg_kernel<256, 3, true, true, false><<<dim3(NT / 128, 4, NB), 256, 0, stream>>>(
        attb, wtdp2, dp_b2, dp_g2, dp_bt2, dp_m2, dp_v2, nullptr, prjb, NT, NT, 256);
    dur_kernel<<<M, 256, 0, stream>>>(prjb, dp_wo, dp_bo, durb);
    scan_kernel<<<1, 64, 0, stream>>>(durb, startb, totb);
    tok_kernel<<<NB * TOUT / 256, 256, 0, stream>>>(startb, totb, tokb);

    // decoder convs (conv1 gathers regulated rows via tok[])
    convg_kernel<256, 5, true, false, true><<<dim3(TOUT / 128, 4, NB), 256, 0, stream>>>(
        x, wtd1, dec_b1, nullptr, nullptr, nullptr, nullptr, tokb, ffh, TOUT, NT, 256);
    convg_kernel<256, 5, true, false, false><<<dim3(TOUT / 128, 2, NB), 256, 0, stream>>>(
        ffh, wtd2, dec_b2, nullptr, nullptr, nullptr, nullptr, nullptr, qkvb, TOUT, TOUT, 128);
    conv3_kernel<<<NB * TOUT / 256, 256, 0, stream>>>(qkvb, dec_w3, dec_b3, (float*)d_out);
}

// Round 5
// 4000.864 us; speedup vs baseline: 1.3836x; 1.1500x over previous
//
#include <hip/hip_runtime.h>
#include <math.h>

#define NB 32
#define NT 512
#define ND 256
#define NH 4
#define NLAYER 6
#define TOUT 2048

typedef __attribute__((ext_vector_type(8))) short bf16x8;
typedef __attribute__((ext_vector_type(4))) float f32x4;

static __device__ __forceinline__ unsigned short f2b(float f) {
    union { float f; unsigned int u; } x; x.f = f;
    unsigned int u = x.u;
    return (unsigned short)((u + 0x7FFFu + ((u >> 16) & 1u)) >> 16);
}
static __device__ __forceinline__ float b2f(unsigned short s) {
    union { unsigned int u; float f; } x; x.u = ((unsigned int)s) << 16;
    return x.f;
}

// ---------------- workspace layout (float offsets) ----------------
#define OFF_X    0ull          // 4,194,304   x / fused [B,T,256]
#define OFF_FFH  4194304ull    // 16,777,216  ffn hidden; later d1b bf16 [B,2048,256]
#define OFF_QKV  20971520ull   // qkv [16384,768]
#define OFF_WT   29360128ull   // transposed conv weights (tail of qkv region, used post-transformer)
#define OFF_ATTN 33554432ull   // attn out / dp h1; later d2b bf16 [B,2048,128]
#define OFF_PROJ 37748736ull   // proj / ff2 out / dp h2
#define OFF_E    41943040ull   // emotion e [B,256]
#define OFF_INT  41951232ull   // ints: dur, starts, totals, tok

// ---------------- embedding + positional encoding ----------------
__global__ __launch_bounds__(256) void embed_kernel(const int* __restrict__ text,
                                                    const float* __restrict__ emb,
                                                    float* __restrict__ x)
{
    const int row = blockIdx.x;
    const int d = threadIdx.x;
    const int t = row & (NT - 1);
    const int id = text[row];
    const int j2 = (d >> 1) * 2;
    const float c = -9.210340371976184f / 256.0f;
    float freq = expf((float)j2 * c);
    float ang = (float)t * freq;
    float pe = (d & 1) ? cosf(ang) : sinf(ang);
    x[(size_t)row * ND + d] = emb[(size_t)id * ND + d] + pe;
}

// ---------------- fp32 GEMM 128x64 tile, 4 waves, 4x8 acc (for N=256 GEMMs) ----------------
template<bool RELU>
__global__ __launch_bounds__(256, 4) void gemm256_kernel(const float* __restrict__ A,
                                                         const float* __restrict__ B,
                                                         const float* __restrict__ bias,
                                                         float* __restrict__ C,
                                                         int M, int N, int K)
{
    __shared__ __align__(16) float As[16 * 132];
    __shared__ __align__(16) float Bs[16 * 68];
    const int tid = threadIdx.x;
    const int lane = tid & 63, wave = tid >> 6;
    const int row0 = blockIdx.y * 128, col0 = blockIdx.x * 64;
    const int wt0 = wave * 32;
    const int r0 = (lane >> 3) << 2;
    const int c0 = (lane & 7) << 2;
    float acc[4][8] = {};

    for (int k0 = 0; k0 < K; k0 += 16) {
#pragma unroll
        for (int it = 0; it < 2; ++it) {
            int i = it * 256 + tid;
            int r = i >> 2, kq = (i & 3) << 2;
            float4 v = *(const float4*)&A[(size_t)(row0 + r) * K + k0 + kq];
            As[(kq + 0) * 132 + r] = v.x;
            As[(kq + 1) * 132 + r] = v.y;
            As[(kq + 2) * 132 + r] = v.z;
            As[(kq + 3) * 132 + r] = v.w;
        }
        {
            int kk = tid >> 4, n4 = (tid & 15) << 2;
            *(float4*)&Bs[kk * 68 + n4] =
                *(const float4*)&B[(size_t)(k0 + kk) * N + col0 + n4];
        }
        __syncthreads();
#pragma unroll
        for (int k = 0; k < 16; ++k) {
            float4 av = *(const float4*)&As[k * 132 + wt0 + r0];
            float4 b0 = *(const float4*)&Bs[k * 68 + c0];
            float4 b1 = *(const float4*)&Bs[k * 68 + 32 + c0];
            float aa[4] = {av.x, av.y, av.z, av.w};
            float bb[8] = {b0.x, b0.y, b0.z, b0.w, b1.x, b1.y, b1.z, b1.w};
#pragma unroll
            for (int i = 0; i < 4; ++i)
#pragma unroll
                for (int j = 0; j < 8; ++j)
                    acc[i][j] = fmaf(aa[i], bb[j], acc[i][j]);
        }
        __syncthreads();
    }
    float4 bv0 = *(const float4*)(bias + col0 + c0);
    float4 bv1 = *(const float4*)(bias + col0 + 32 + c0);
    float bb[8] = {bv0.x, bv0.y, bv0.z, bv0.w, bv1.x, bv1.y, bv1.z, bv1.w};
#pragma unroll
    for (int i = 0; i < 4; ++i) {
        int row = row0 + wt0 + r0 + i;
#pragma unroll
        for (int jh = 0; jh < 2; ++jh) {
            float4 r;
            r.x = acc[i][jh * 4 + 0] + bb[jh * 4 + 0];
            r.y = acc[i][jh * 4 + 1] + bb[jh * 4 + 1];
            r.z = acc[i][jh * 4 + 2] + bb[jh * 4 + 2];
            r.w = acc[i][jh * 4 + 3] + bb[jh * 4 + 3];
            if (RELU) {
                r.x = fmaxf(r.x, 0.f); r.y = fmaxf(r.y, 0.f);
                r.z = fmaxf(r.z, 0.f); r.w = fmaxf(r.w, 0.f);
            }
            *(float4*)&C[(size_t)row * N + col0 + jh * 32 + c0] = r;
        }
    }
}

// ---------------- fp32 GEMM 128x128 tile, 4 waves, 8x8 acc (0.5 B/FLOP) ----------------
template<bool RELU>
__global__ __launch_bounds__(256, 4) void gemm128_kernel(const float* __restrict__ A,
                                                         const float* __restrict__ B,
                                                         const float* __restrict__ bias,
                                                         float* __restrict__ C,
                                                         int M, int N, int K)
{
    __shared__ __align__(16) float As[16 * 132];   // [k][m]
    __shared__ __align__(16) float Bs[16 * 132];   // [k][n]
    const int tid = threadIdx.x;
    const int row0 = blockIdx.y * 128, col0 = blockIdx.x * 128;
    const int rg = tid >> 4;        // 0..15
    const int cg = tid & 15;        // 0..15
    float acc[8][8] = {};

    for (int k0 = 0; k0 < K; k0 += 16) {
#pragma unroll
        for (int it = 0; it < 2; ++it) {
            int i = it * 256 + tid;
            int r = i >> 2, kq = (i & 3) << 2;
            float4 v = *(const float4*)&A[(size_t)(row0 + r) * K + k0 + kq];
            As[(kq + 0) * 132 + r] = v.x;
            As[(kq + 1) * 132 + r] = v.y;
            As[(kq + 2) * 132 + r] = v.z;
            As[(kq + 3) * 132 + r] = v.w;
        }
#pragma unroll
        for (int it = 0; it < 2; ++it) {
            int i = it * 256 + tid;
            int kk = i >> 5, n4 = (i & 31) << 2;
            *(float4*)&Bs[kk * 132 + n4] =
                *(const float4*)&B[(size_t)(k0 + kk) * N + col0 + n4];
        }
        __syncthreads();
#pragma unroll
        for (int k = 0; k < 16; ++k) {
            float4 a0 = *(const float4*)&As[k * 132 + rg * 4];
            float4 a1 = *(const float4*)&As[k * 132 + 64 + rg * 4];
            float4 b0 = *(const float4*)&Bs[k * 132 + cg * 4];
            float4 b1 = *(const float4*)&Bs[k * 132 + 64 + cg * 4];
            float aa[8] = {a0.x, a0.y, a0.z, a0.w, a1.x, a1.y, a1.z, a1.w};
            float bb[8] = {b0.x, b0.y, b0.z, b0.w, b1.x, b1.y, b1.z, b1.w};
#pragma unroll
            for (int i = 0; i < 8; ++i)
#pragma unroll
                for (int j = 0; j < 8; ++j)
                    acc[i][j] = fmaf(aa[i], bb[j], acc[i][j]);
        }
        __syncthreads();
    }
    float4 bv0 = *(const float4*)(bias + col0 + cg * 4);
    float4 bv1 = *(const float4*)(bias + col0 + 64 + cg * 4);
    float bb[8] = {bv0.x, bv0.y, bv0.z, bv0.w, bv1.x, bv1.y, bv1.z, bv1.w};
#pragma unroll
    for (int ih = 0; ih < 2; ++ih)
#pragma unroll
        for (int i = 0; i < 4; ++i) {
            int row = row0 + ih * 64 + rg * 4 + i;
#pragma unroll
            for (int jh = 0; jh < 2; ++jh) {
                float4 r;
                r.x = acc[ih * 4 + i][jh * 4 + 0] + bb[jh * 4 + 0];
                r.y = acc[ih * 4 + i][jh * 4 + 1] + bb[jh * 4 + 1];
                r.z = acc[ih * 4 + i][jh * 4 + 2] + bb[jh * 4 + 2];
                r.w = acc[ih * 4 + i][jh * 4 + 3] + bb[jh * 4 + 3];
                if (RELU) {
                    r.x = fmaxf(r.x, 0.f); r.y = fmaxf(r.y, 0.f);
                    r.z = fmaxf(r.z, 0.f); r.w = fmaxf(r.w, 0.f);
                }
                *(float4*)&C[(size_t)row * N + col0 + jh * 64 + cg * 4] = r;
            }
        }
}

// ---------------- attention v2: online softmax, q-tile 64, chunk 64 ----------------
#define SWZ(blk, d) ((((blk) ^ (d)) & 15) << 2)

__global__ __launch_bounds__(256) void attn2_kernel(const float* __restrict__ qkv,
                                                    float* __restrict__ out)
{
    __shared__ float sQT[64 * 64];
    __shared__ float sKV[64 * 68];
    __shared__ float sPT[64 * 68];
    __shared__ float sM[64], sL[64], sA[64];
    const int tid = threadIdx.x;
    const int tb = blockIdx.x, h = blockIdx.y, b = blockIdx.z;
    const int t0 = tb * 64;
    const size_t base = (size_t)b * NT * 768;
    const int qoff = h * 64;
    const int g4 = tid >> 4;
    const int l4 = tid & 15;

#pragma unroll
    for (int it = 0; it < 4; ++it) {
        int i = it * 256 + tid;
        int r = i >> 4, d4 = (i & 15) << 2;
        float4 v = *(const float4*)&qkv[base + (size_t)(t0 + r) * 768 + qoff + d4];
        float vv[4] = {v.x, v.y, v.z, v.w};
#pragma unroll
        for (int j = 0; j < 4; ++j)
            sQT[(d4 + j) * 64 + SWZ(r >> 2, d4 + j) + (r & 3)] = vv[j];
    }
    if (tid < 64) { sM[tid] = -3.0e38f; sL[tid] = 0.0f; }
    __syncthreads();

    float accO[4][4] = {};

    for (int ch = 0; ch < 8; ++ch) {
        const int s0 = ch * 64;
        float4 kreg[4], vreg[4];
#pragma unroll
        for (int it = 0; it < 4; ++it) {
            int i = it * 256 + tid;
            int c = i >> 4, d4 = (i & 15) << 2;
            kreg[it] = *(const float4*)&qkv[base + (size_t)(s0 + c) * 768 + 256 + qoff + d4];
            vreg[it] = *(const float4*)&qkv[base + (size_t)(s0 + c) * 768 + 512 + qoff + d4];
        }
#pragma unroll
        for (int it = 0; it < 4; ++it) {
            int i = it * 256 + tid;
            int c = i >> 4, d4 = (i & 15) << 2;
            float kk[4] = {kreg[it].x, kreg[it].y, kreg[it].z, kreg[it].w};
#pragma unroll
            for (int j = 0; j < 4; ++j)
                sKV[(d4 + j) * 64 + SWZ(c >> 2, d4 + j) + (c & 3)] = kk[j];
        }
        __syncthreads();

        float acc[4][4] = {};
#pragma unroll 8
        for (int d = 0; d < 64; ++d) {
            float4 qa = *(const float4*)&sQT[d * 64 + SWZ(g4, d)];
            float4 kb = *(const float4*)&sKV[d * 64 + SWZ(l4, d)];
            float qq[4] = {qa.x, qa.y, qa.z, qa.w};
            float kk[4] = {kb.x, kb.y, kb.z, kb.w};
#pragma unroll
            for (int i = 0; i < 4; ++i)
#pragma unroll
                for (int j = 0; j < 4; ++j)
                    acc[i][j] = fmaf(qq[i], kk[j], acc[i][j]);
        }
#pragma unroll
        for (int i = 0; i < 4; ++i)
#pragma unroll
            for (int j = 0; j < 4; ++j)
                acc[i][j] *= 0.125f;

#pragma unroll
        for (int i = 0; i < 4; ++i) {
            float m = fmaxf(fmaxf(acc[i][0], acc[i][1]), fmaxf(acc[i][2], acc[i][3]));
#pragma unroll
            for (int o = 1; o < 16; o <<= 1) m = fmaxf(m, __shfl_xor(m, o));
            float mo = sM[g4 * 4 + i];
            float nm = fmaxf(mo, m);
            float al = expf(mo - nm);
            float s = 0.f;
#pragma unroll
            for (int j = 0; j < 4; ++j) {
                float p = expf(acc[i][j] - nm);
                acc[i][j] = p;
                s += p;
            }
#pragma unroll
            for (int o = 1; o < 16; o <<= 1) s += __shfl_xor(s, o);
            if (l4 == 0) {
                sM[g4 * 4 + i] = nm;
                sL[g4 * 4 + i] = sL[g4 * 4 + i] * al + s;
                sA[g4 * 4 + i] = al;
            }
        }
#pragma unroll
        for (int j = 0; j < 4; ++j)
            *(float4*)&sPT[(l4 * 4 + j) * 68 + g4 * 4] =
                make_float4(acc[0][j], acc[1][j], acc[2][j], acc[3][j]);
        __syncthreads();

#pragma unroll
        for (int it = 0; it < 4; ++it) {
            int i = it * 256 + tid;
            int c = i >> 4, d4 = (i & 15) << 2;
            *(float4*)&sKV[c * 68 + d4] = vreg[it];
        }
        __syncthreads();

        float4 alj = *(const float4*)&sA[l4 * 4];
        float alv[4] = {alj.x, alj.y, alj.z, alj.w};
#pragma unroll
        for (int i = 0; i < 4; ++i)
#pragma unroll
            for (int j = 0; j < 4; ++j)
                accO[i][j] *= alv[j];
#pragma unroll 8
        for (int c = 0; c < 64; ++c) {
            float4 va = *(const float4*)&sKV[c * 68 + g4 * 4];
            float4 pb = *(const float4*)&sPT[c * 68 + l4 * 4];
            float vv[4] = {va.x, va.y, va.z, va.w};
            float pp[4] = {pb.x, pb.y, pb.z, pb.w};
#pragma unroll
            for (int i = 0; i < 4; ++i)
#pragma unroll
                for (int j = 0; j < 4; ++j)
                    accO[i][j] = fmaf(vv[i], pp[j], accO[i][j]);
        }
        __syncthreads();
    }

    float4 lf = *(const float4*)&sL[l4 * 4];
    float linv[4] = {1.f / lf.x, 1.f / lf.y, 1.f / lf.z, 1.f / lf.w};
#pragma unroll
    for (int j = 0; j < 4; ++j) {
        float4 r;
        r.x = accO[0][j] * linv[j];
        r.y = accO[1][j] * linv[j];
        r.z = accO[2][j] * linv[j];
        r.w = accO[3][j] * linv[j];
        *(float4*)&out[((size_t)b * NT + t0 + l4 * 4 + j) * ND + qoff + g4 * 4] = r;
    }
}

// ---------------- x = LayerNorm(x + y) ----------------
__global__ __launch_bounds__(256) void add_ln_kernel(float* __restrict__ x,
                                                     const float* __restrict__ y,
                                                     const float* __restrict__ g,
                                                     const float* __restrict__ bta)
{
    __shared__ float red[8];
    const size_t row = blockIdx.x;
    const int d = threadIdx.x;
    float v = x[row * ND + d] + y[row * ND + d];
    float s = v;
#pragma unroll
    for (int o = 32; o; o >>= 1) s += __shfl_down(s, o);
    if ((d & 63) == 0) red[d >> 6] = s;
    __syncthreads();
    float m = (red[0] + red[1] + red[2] + red[3]) * (1.0f / 256.0f);
    float dv = v - m;
    float s2 = dv * dv;
#pragma unroll
    for (int o = 32; o; o >>= 1) s2 += __shfl_down(s2, o);
    if ((d & 63) == 0) red[4 + (d >> 6)] = s2;
    __syncthreads();
    float var = (red[4] + red[5] + red[6] + red[7]) * (1.0f / 256.0f);
    float r = 1.0f / sqrtf(var + 1e-5f);
    x[row * ND + d] = dv * r * g[d] + bta[d];
}

// ---------------- emotion MLP ----------------
__global__ __launch_bounds__(256) void emotion_kernel(const float* __restrict__ emo,
                                                      const float* __restrict__ We1,
                                                      const float* __restrict__ be1,
                                                      const float* __restrict__ We2,
                                                      const float* __restrict__ be2,
                                                      float* __restrict__ e)
{
    const int b = blockIdx.x, d = threadIdx.x;
    const float em = emo[b];
    float acc = be2[d];
    for (int j = 0; j < 64; ++j) {
        float h = fmaxf(em * We1[j] + be1[j], 0.0f);
        acc = fmaf(h, We2[j * ND + d], acc);
    }
    e[b * ND + d] = acc;
}

__global__ __launch_bounds__(256) void addfuse_kernel(float* __restrict__ x,
                                                      const float* __restrict__ e)
{
    const int row = blockIdx.x;
    const int d = threadIdx.x;
    x[(size_t)row * ND + d] += e[(row >> 9) * ND + d];
}

// ---------------- conv weight transpose: w[O,I,K] -> wt[k][c][o] fp32 ----------------
__global__ __launch_bounds__(256) void wtrans_kernel(const float* __restrict__ w,
                                                     float* __restrict__ wt,
                                                     int CIN, int COUT, int KS)
{
    int gid = blockIdx.x * 256 + threadIdx.x;
    int total = CIN * COUT * KS;
    if (gid >= total) return;
    int o = gid % COUT;
    int r = gid / COUT;
    int c = r % CIN;
    int k = r / CIN;
    wt[gid] = w[(o * CIN + c) * KS + k];
}

// ---------------- conv weight transpose: w[O,I,K] -> wtb[k][o][c] bf16 ----------------
__global__ __launch_bounds__(256) void wtransb_kernel(const float* __restrict__ w,
                                                      unsigned short* __restrict__ wtb,
                                                      int CIN, int COUT, int KS)
{
    int gid = blockIdx.x * 256 + threadIdx.x;
    int total = CIN * COUT * KS;
    if (gid >= total) return;
    int c = gid % CIN;
    int r = gid / CIN;
    int o = r % COUT;
    int k = r / COUT;
    wtb[gid] = f2b(w[(o * CIN + c) * KS + k]);
}

// ---------------- fp32 GEMM-style conv (duration predictor; must stay fp32) ----------------
template<int CIN, int KS, bool RELU, bool BN, bool GATHER>
__global__ __launch_bounds__(256, 4) void convg_kernel(const float* __restrict__ in,
                                                       const float* __restrict__ wt,
                                                       const float* __restrict__ bias,
                                                       const float* __restrict__ bng,
                                                       const float* __restrict__ bnb,
                                                       const float* __restrict__ bnm,
                                                       const float* __restrict__ bnv,
                                                       const int* __restrict__ tok,
                                                       float* __restrict__ out,
                                                       int T, int in_T, int COUT)
{
    constexpr int TM = 128;
    constexpr int PAD = (KS - 1) / 2;
    constexpr int TEXT = TM + KS - 1;
    constexpr int PITCH = (TEXT + 3) & ~3;
    __shared__ __align__(16) float As[16 * PITCH];
    __shared__ __align__(16) float Bs[16 * KS * 68];
    const int tid = threadIdx.x;
    const int lane = tid & 63, wave = tid >> 6;
    const int b = blockIdx.z;
    const int t0 = blockIdx.x * TM;
    const int o0 = blockIdx.y * 64;
    const int wt0 = wave * 32;
    const int r0 = (lane >> 3) << 2;
    const int c0 = (lane & 7) << 2;
    float acc[4][8] = {};

    for (int cc = 0; cc < CIN; cc += 16) {
        for (int i = tid; i < TEXT * 4; i += 256) {
            int t = i >> 2, q = i & 3;
            int tg = t0 - PAD + t;
            float4 v = make_float4(0.f, 0.f, 0.f, 0.f);
            if (tg >= 0 && tg < T) {
                long row;
                if (GATHER) {
                    int tk = tok[b * T + tg];
                    row = (tk >= 0) ? ((long)b * in_T + tk) : -1;
                } else {
                    row = (long)b * T + tg;
                }
                if (row >= 0) v = *(const float4*)&in[row * CIN + cc + (q << 2)];
            }
            As[((q << 2) + 0) * PITCH + t] = v.x;
            As[((q << 2) + 1) * PITCH + t] = v.y;
            As[((q << 2) + 2) * PITCH + t] = v.z;
            As[((q << 2) + 3) * PITCH + t] = v.w;
        }
        for (int i = tid; i < KS * 256; i += 256) {
            int row = i >> 4, o4 = (i & 15) << 2;
            int k = row >> 4, ci = row & 15;
            *(float4*)&Bs[row * 68 + o4] =
                *(const float4*)&wt[(size_t)(k * CIN + cc + ci) * COUT + o0 + o4];
        }
        __syncthreads();
#pragma unroll 2
        for (int ci = 0; ci < 16; ++ci) {
            float a[8];
            float4 A0 = *(const float4*)&As[ci * PITCH + wt0 + r0];
            float4 A1 = *(const float4*)&As[ci * PITCH + wt0 + r0 + 4];
            a[0] = A0.x; a[1] = A0.y; a[2] = A0.z; a[3] = A0.w;
            a[4] = A1.x; a[5] = A1.y; a[6] = A1.z; a[7] = A1.w;
#pragma unroll
            for (int k = 0; k < KS; ++k) {
                float4 b0 = *(const float4*)&Bs[(k * 16 + ci) * 68 + c0];
                float4 b1 = *(const float4*)&Bs[(k * 16 + ci) * 68 + 32 + c0];
                float bb[8] = {b0.x, b0.y, b0.z, b0.w, b1.x, b1.y, b1.z, b1.w};
#pragma unroll
                for (int i = 0; i < 4; ++i)
#pragma unroll
                    for (int j = 0; j < 8; ++j)
                        acc[i][j] = fmaf(a[i + k], bb[j], acc[i][j]);
            }
        }
        __syncthreads();
    }

    float4 bi0 = *(const float4*)(bias + o0 + c0);
    float4 bi1 = *(const float4*)(bias + o0 + 32 + c0);
    float bb[8] = {bi0.x, bi0.y, bi0.z, bi0.w, bi1.x, bi1.y, bi1.z, bi1.w};
    float sc[8], sh[8];
    if (BN) {
        float4 g0 = *(const float4*)(bng + o0 + c0);
        float4 g1 = *(const float4*)(bng + o0 + 32 + c0);
        float4 t0v = *(const float4*)(bnb + o0 + c0);
        float4 t1v = *(const float4*)(bnb + o0 + 32 + c0);
        float4 m0 = *(const float4*)(bnm + o0 + c0);
        float4 m1 = *(const float4*)(bnm + o0 + 32 + c0);
        float4 v0 = *(const float4*)(bnv + o0 + c0);
        float4 v1 = *(const float4*)(bnv + o0 + 32 + c0);
        float gg[8] = {g0.x, g0.y, g0.z, g0.w, g1.x, g1.y, g1.z, g1.w};
        float tb[8] = {t0v.x, t0v.y, t0v.z, t0v.w, t1v.x, t1v.y, t1v.z, t1v.w};
        float mm[8] = {m0.x, m0.y, m0.z, m0.w, m1.x, m1.y, m1.z, m1.w};
        float vv[8] = {v0.x, v0.y, v0.z, v0.w, v1.x, v1.y, v1.z, v1.w};
#pragma unroll
        for (int j = 0; j < 8; ++j) {
            sc[j] = gg[j] / sqrtf(vv[j] + 1e-5f);
            sh[j] = tb[j] - mm[j] * sc[j];
        }
    }
#pragma unroll
    for (int i = 0; i < 4; ++i) {
        int r = t0 + wt0 + r0 + i;
#pragma unroll
        for (int jh = 0; jh < 2; ++jh) {
            float o4[4];
#pragma unroll
            for (int j = 0; j < 4; ++j) {
                float yv = acc[i][jh * 4 + j] + bb[jh * 4 + j];
                if (RELU) yv = fmaxf(yv, 0.0f);
                if (BN) yv = yv * sc[jh * 4 + j] + sh[jh * 4 + j];
                o4[j] = yv;
            }
            *(float4*)&out[((size_t)b * T + r) * COUT + o0 + jh * 32 + c0] =
                make_float4(o4[0], o4[1], o4[2], o4[3]);
        }
    }
}

// ---------------- bf16 MFMA conv (decoder; downstream of dur) ----------------
// Tile 128t x 64o per block (4 waves; wave owns 32 t-rows as 2 m-tiles).
// A staged in LDS [t][ci] bf16 pitch 40; B-frags read direct from global wtb[k][o][c] (L2).
template<int CIN, int KS, bool GATHER, bool IN_BF16>
__global__ __launch_bounds__(256) void convmf_kernel(const void* __restrict__ in_,
                                                     const unsigned short* __restrict__ wtb,
                                                     const float* __restrict__ bias,
                                                     const int* __restrict__ tok,
                                                     unsigned short* __restrict__ out,
                                                     int T, int in_T, int COUT)
{
    constexpr int TM = 128;
    constexpr int PAD = (KS - 1) / 2;
    constexpr int TEXT = TM + KS - 1;          // 132
    constexpr int PITCHA = 40;                 // shorts; rows 80B (16B-aligned)
    __shared__ __align__(16) unsigned short As[TEXT * PITCHA];
    const int tid = threadIdx.x;
    const int lane = tid & 63, wave = tid >> 6;
    const int m = lane & 15, quad = lane >> 4;
    const int b = blockIdx.z;
    const int t0 = blockIdx.x * TM;
    const int o0 = blockIdx.y * 64;
    const int woff = wave * 32;
    f32x4 acc[2][4] = {};

    const float* inf = (const float*)in_;
    const unsigned short* inb = (const unsigned short*)in_;

    for (int cc = 0; cc < CIN; cc += 32) {
        // stage A chunk: As[t][ci] bf16, t_global = t0 - PAD + t
        for (int i = tid; i < TEXT * 8; i += 256) {
            int t = i >> 3, ci4 = (i & 7) << 2;
            int tg = t0 - PAD + t;
            long row = -1;
            if (tg >= 0 && tg < T) {
                if (GATHER) {
                    int tk = tok[b * T + tg];
                    if (tk >= 0) row = (long)b * in_T + tk;
                } else {
                    row = (long)b * T + tg;
                }
            }
            unsigned short s4[4] = {0, 0, 0, 0};
            if (row >= 0) {
                if (IN_BF16) {
                    *(uint2*)s4 = *(const uint2*)&inb[row * CIN + cc + ci4];
                } else {
                    float4 v = *(const float4*)&inf[row * CIN + cc + ci4];
                    s4[0] = f2b(v.x); s4[1] = f2b(v.y);
                    s4[2] = f2b(v.z); s4[3] = f2b(v.w);
                }
            }
            *(uint2*)&As[t * PITCHA + ci4] = *(uint2*)s4;
        }
        __syncthreads();
#pragma unroll
        for (int tap = 0; tap < KS; ++tap) {
            bf16x8 a0 = *(const bf16x8*)&As[(woff + 0  + m + tap) * PITCHA + quad * 8];
            bf16x8 a1 = *(const bf16x8*)&As[(woff + 16 + m + tap) * PITCHA + quad * 8];
#pragma unroll
            for (int ot = 0; ot < 4; ++ot) {
                bf16x8 bf = *(const bf16x8*)&wtb[((size_t)tap * COUT + o0 + ot * 16 + m) * CIN + cc + quad * 8];
                acc[0][ot] = __builtin_amdgcn_mfma_f32_16x16x32_bf16(a0, bf, acc[0][ot], 0, 0, 0);
                acc[1][ot] = __builtin_amdgcn_mfma_f32_16x16x32_bf16(a1, bf, acc[1][ot], 0, 0, 0);
            }
        }
        __syncthreads();
    }

    // epilogue: bias + relu, store bf16. D layout: col = lane&15, row = quad*4 + reg
#pragma unroll
    for (int ot = 0; ot < 4; ++ot) {
        int o = o0 + ot * 16 + m;
        float bi = bias[o];
#pragma unroll
        for (int mt = 0; mt < 2; ++mt)
#pragma unroll
            for (int r = 0; r < 4; ++r) {
                int t = t0 + woff + mt * 16 + quad * 4 + r;
                float yv = fmaxf(acc[mt][ot][r] + bi, 0.0f);
                out[((size_t)b * T + t) * COUT + o] = f2b(yv);
            }
    }
}

// ---------------- duration: log_dur -> dur ----------------
__global__ __launch_bounds__(256) void dur_kernel(const float* __restrict__ h2,
                                                  const float* __restrict__ wo,
                                                  const float* __restrict__ bo,
                                                  int* __restrict__ dur)
{
    __shared__ float red[4];
    const int row = blockIdx.x;
    const int c = threadIdx.x;
    float s = h2[(size_t)row * ND + c] * wo[c];
#pragma unroll
    for (int o = 32; o; o >>= 1) s += __shfl_down(s, o);
    if ((c & 63) == 0) red[c >> 6] = s;
    __syncthreads();
    if (c == 0) {
        float ld = red[0] + red[1] + red[2] + red[3] + bo[0];
        float d = rintf(expf(ld));
        d = fminf(fmaxf(d, 1.0f), 8.0f);
        dur[row] = (int)d;
    }
}

__global__ __launch_bounds__(64) void scan_kernel(const int* __restrict__ dur,
                                                  int* __restrict__ starts,
                                                  int* __restrict__ totals)
{
    const int b = threadIdx.x;
    if (b >= NB) return;
    int acc = 0;
    for (int t = 0; t < NT; ++t) {
        starts[b * NT + t] = acc;
        acc += dur[b * NT + t];
    }
    totals[b] = acc;
}

__global__ __launch_bounds__(256) void tok_kernel(const int* __restrict__ starts,
                                                  const int* __restrict__ totals,
                                                  int* __restrict__ tok)
{
    const int gid = blockIdx.x * 256 + threadIdx.x;
    const int b = gid >> 11, p = gid & (TOUT - 1);
    const int total = totals[b];
    int res = -1;
    if (p < total) {
        const int* st = starts + b * NT;
        int lo = 0, hi = NT - 1;
        while (lo < hi) {
            int mid = (lo + hi + 1) >> 1;
            if (st[mid] <= p) lo = mid; else hi = mid - 1;
        }
        res = lo;
    }
    tok[gid] = res;
}

// ---------------- decoder conv3: bf16 [B,2048,128] -> wav fp32 [B,2048] ----------------
__global__ __launch_bounds__(256) void conv3_kernel(const unsigned short* __restrict__ in,
                                                    const float* __restrict__ w,
                                                    const float* __restrict__ bias,
                                                    float* __restrict__ out)
{
    const int gid = blockIdx.x * 256 + threadIdx.x;
    const int b = gid >> 11, t = gid & (TOUT - 1);
    float acc = bias[0];
#pragma unroll
    for (int k = 0; k < 5; ++k) {
        int t2 = t + k - 2;
        if (t2 < 0 || t2 >= TOUT) continue;
        const unsigned short* row = in + ((size_t)b * TOUT + t2) * 128;
        for (int c = 0; c < 128; ++c) acc = fmaf(b2f(row[c]), w[c * 5 + k], acc);
    }
    out[gid] = acc;
}

// ---------------- orchestration ----------------
extern "C" void kernel_launch(void* const* d_in, const int* in_sizes, int n_in,
                              void* d_out, int out_size, void* d_ws, size_t ws_size,
                              hipStream_t stream)
{
    const int*   text    = (const int*)d_in[0];
    const float* emotion = (const float*)d_in[1];
    const float* emb     = (const float*)d_in[2];
    const float* Wqkv    = (const float*)d_in[3];
    const float* bqkv    = (const float*)d_in[4];
    const float* Wo      = (const float*)d_in[5];
    const float* bo      = (const float*)d_in[6];
    const float* W1      = (const float*)d_in[7];
    const float* b1      = (const float*)d_in[8];
    const float* W2      = (const float*)d_in[9];
    const float* b2      = (const float*)d_in[10];
    const float* ln1g    = (const float*)d_in[11];
    const float* ln1b    = (const float*)d_in[12];
    const float* ln2g    = (const float*)d_in[13];
    const float* ln2b    = (const float*)d_in[14];
    const float* We1     = (const float*)d_in[15];
    const float* be1     = (const float*)d_in[16];
    const float* We2     = (const float*)d_in[17];
    const float* be2     = (const float*)d_in[18];
    const float* dp_w1   = (const float*)d_in[19];
    const float* dp_b1   = (const float*)d_in[20];
    const float* dp_g1   = (const float*)d_in[21];
    const float* dp_bt1  = (const float*)d_in[22];
    const float* dp_m1   = (const float*)d_in[23];
    const float* dp_v1   = (const float*)d_in[24];
    const float* dp_w2   = (const float*)d_in[25];
    const float* dp_b2   = (const float*)d_in[26];
    const float* dp_g2   = (const float*)d_in[27];
    const float* dp_bt2  = (const float*)d_in[28];
    const float* dp_m2   = (const float*)d_in[29];
    const float* dp_v2   = (const float*)d_in[30];
    const float* dp_wo   = (const float*)d_in[31];
    const float* dp_bo   = (const float*)d_in[32];
    const float* dec_w1  = (const float*)d_in[33];
    const float* dec_b1  = (const float*)d_in[34];
    const float* dec_w2  = (const float*)d_in[35];
    const float* dec_b2  = (const float*)d_in[36];
    const float* dec_w3  = (const float*)d_in[37];
    const float* dec_b3  = (const float*)d_in[38];

    float* ws   = (float*)d_ws;
    float* x    = ws + OFF_X;
    float* ffh  = ws + OFF_FFH;
    float* qkvb = ws + OFF_QKV;
    float* attb = ws + OFF_ATTN;
    float* prjb = ws + OFF_PROJ;
    float* ebuf = ws + OFF_E;
    float* wtdp1 = ws + OFF_WT;                          // 196608 f
    float* wtdp2 = wtdp1 + 196608;                       // 196608 f
    unsigned short* wtb1 = (unsigned short*)(wtdp2 + 196608);   // 327680 bf16
    unsigned short* wtb2 = wtb1 + 327680;                       // 163840 bf16
    unsigned short* d1b  = (unsigned short*)ffh;         // [B,2048,256] bf16
    unsigned short* d2b  = (unsigned short*)attb;        // [B,2048,128] bf16
    int*   ip     = (int*)(ws + OFF_INT);
    int*   durb   = ip;
    int*   startb = ip + 16384;
    int*   totb   = ip + 32768;
    int*   tokb   = ip + 32832;

    const int M = NB * NT;   // 16384

    embed_kernel<<<M, 256, 0, stream>>>(text, emb, x);

    for (int l = 0; l < NLAYER; ++l) {
        gemm128_kernel<false><<<dim3(6, M / 128), 256, 0, stream>>>(
            x, Wqkv + (size_t)l * ND * 3 * ND, bqkv + l * 3 * ND, qkvb, M, 3 * ND, ND);
        attn2_kernel<<<dim3(NT / 64, NH, NB), 256, 0, stream>>>(qkvb, attb);
        gemm256_kernel<false><<<dim3(4, M / 128), 256, 0, stream>>>(
            attb, Wo + (size_t)l * ND * ND, bo + l * ND, prjb, M, ND, ND);
        add_ln_kernel<<<M, 256, 0, stream>>>(x, prjb, ln1g + l * ND, ln1b + l * ND);
        gemm128_kernel<true><<<dim3(8, M / 128), 256, 0, stream>>>(
            x, W1 + (size_t)l * ND * 4 * ND, b1 + l * 4 * ND, ffh, M, 4 * ND, ND);
        gemm256_kernel<false><<<dim3(4, M / 128), 256, 0, stream>>>(
            ffh, W2 + (size_t)l * 4 * ND * ND, b2 + l * ND, prjb, M, ND, 4 * ND);
        add_ln_kernel<<<M, 256, 0, stream>>>(x, prjb, ln2g + l * ND, ln2b + l * ND);
    }

    emotion_kernel<<<NB, 256, 0, stream>>>(emotion, We1, be1, We2, be2, ebuf);
    addfuse_kernel<<<M, 256, 0, stream>>>(x, ebuf);

    // weight transposes (qkvb region free of qkv use by now)
    wtrans_kernel<<<(256 * 256 * 3 + 255) / 256, 256, 0, stream>>>(dp_w1, wtdp1, 256, 256, 3);
    wtrans_kernel<<<(256 * 256 * 3 + 255) / 256, 256, 0, stream>>>(dp_w2, wtdp2, 256, 256, 3);
    wtransb_kernel<<<(256 * 256 * 5 + 255) / 256, 256, 0, stream>>>(dec_w1, wtb1, 256, 256, 5);
    wtransb_kernel<<<(128 * 256 * 5 + 255) / 256, 256, 0, stream>>>(dec_w2, wtb2, 256, 128, 5);

    // duration predictor convs (fp32 mandatory: feeds dur rounding)
    convg_kernel<256, 3, true, true, false><<<dim3(NT / 128, 4, NB), 256, 0, stream>>>(
        x, wtdp1, dp_b1, dp_g1, dp_bt1, dp_m1, dp_v1, nullptr, attb, NT, NT, 256);
    convg_kernel<256, 3, true, true, false><<<dim3(NT / 128, 4, NB), 256, 0, stream>>>(
        attb, wtdp2, dp_b2, dp_g2, dp_bt2, dp_m2, dp_v2, nullptr, prjb, NT, NT, 256);
    dur_kernel<<<M, 256, 0, stream>>>(prjb, dp_wo, dp_bo, durb);
    scan_kernel<<<1, 64, 0, stream>>>(durb, startb, totb);
    tok_kernel<<<NB * TOUT / 256, 256, 0, stream>>>(startb, totb, tokb);

    // decoder: bf16 MFMA convs (downstream of dur; continuous error only)
    convmf_kernel<256, 5, true, false><<<dim3(TOUT / 128, 4, NB), 256, 0, stream>>>(
        x, wtb1, dec_b1, tokb, d1b, TOUT, NT, 256);
    convmf_kernel<256, 5, false, true><<<dim3(TOUT / 128, 2, NB), 256, 0, stream>>>(
        d1b, wtb2, dec_b2, nullptr, d2b, TOUT, TOUT, 128);
    conv3_kernel<<<NB * TOUT / 256, 256, 0, stream>>>(d2b, dec_w3, dec_b3, (float*)d_out);
}

// Round 6
// 2517.190 us; speedup vs baseline: 2.1991x; 1.5894x over previous
//
#include <hip/hip_runtime.h>
#include <math.h>

#define NB 32
#define NT 512
#define ND 256
#define NH 4
#define NLAYER 6
#define TOUT 2048

typedef __attribute__((ext_vector_type(8))) short bf16x8;
typedef __attribute__((ext_vector_type(4))) float f32x4;
typedef __attribute__((ext_vector_type(16))) float f32x16;

static __device__ __forceinline__ unsigned short f2b(float f) {
    union { float f; unsigned int u; } x; x.f = f;
    unsigned int u = x.u;
    return (unsigned short)((u + 0x7FFFu + ((u >> 16) & 1u)) >> 16);
}
static __device__ __forceinline__ float b2f(unsigned short s) {
    union { unsigned int u; float f; } x; x.u = ((unsigned int)s) << 16;
    return x.f;
}

// ---------------- workspace layout (float offsets) ----------------
#define OFF_X    0ull          // 4,194,304   x fp32 [B,T,256] (residual stream; dur-critical)
#define OFF_FFH  4194304ull    // 8,388,608   ffh bf16 [16384,1024]; later d1b bf16 [B,2048,256]
#define OFF_WBT  12582912ull   // 2,359,296   transformer weights bf16 [N][K], 6 layers
#define OFF_CWT  14942208ull   // 638,976     conv weights (dp fp32 + dec bf16)
#define OFF_QKV  20971520ull   // 12,582,912  qkv fp32 [16384,768]
#define OFF_ATTN 33554432ull   // 4,194,304   attn out / dp h1; later d2b bf16
#define OFF_PROJ 37748736ull   // 4,194,304   proj / ff2 out / dp h2
#define OFF_E    41943040ull   // 8192        emotion e
#define OFF_INT  41951232ull   // ints: dur, starts, totals, tok

// ---------------- embedding + positional encoding ----------------
__global__ __launch_bounds__(256) void embed_kernel(const int* __restrict__ text,
                                                    const float* __restrict__ emb,
                                                    float* __restrict__ x)
{
    const int row = blockIdx.x;
    const int d = threadIdx.x;
    const int t = row & (NT - 1);
    const int id = text[row];
    const int j2 = (d >> 1) * 2;
    const float c = -9.210340371976184f / 256.0f;
    float freq = expf((float)j2 * c);
    float ang = (float)t * freq;
    float pe = (d & 1) ? cosf(ang) : sinf(ang);
    x[(size_t)row * ND + d] = emb[(size_t)id * ND + d] + pe;
}

// ---------------- weight transpose: fp32 [K,N] -> bf16 [N,K], batched over layers ----------------
__global__ __launch_bounds__(256) void wq_kernel(const float* __restrict__ W,
                                                 unsigned short* __restrict__ out,
                                                 int K, int N, int inLS, int outLS)
{
    __shared__ float tile[32][33];
    const float* Wl = W + (size_t)blockIdx.z * inLS;
    unsigned short* ol = out + (size_t)blockIdx.z * outLS;
    const int n0 = blockIdx.x * 32, k0 = blockIdx.y * 32;
    const int tx = threadIdx.x & 31, ty = threadIdx.x >> 5;
#pragma unroll
    for (int j = 0; j < 4; ++j)
        tile[ty + j * 8][tx] = Wl[(size_t)(k0 + ty + j * 8) * N + n0 + tx];
    __syncthreads();
#pragma unroll
    for (int j = 0; j < 4; ++j)
        ol[(size_t)(n0 + ty + j * 8) * K + k0 + tx] = f2b(tile[tx][ty + j * 8]);
}

// ---------------- bf16 MFMA GEMM: C[M,N] = A[M,K] @ B[K,N] + bias ----------------
// Weights pre-transposed Bt[N][K] bf16. Tile 128m x NTILE-n, BK=32, 4 waves.
// 32x32x16 MFMA; A frag: row=lane&31, k=(lane>>5)*8+i; B frag: col=lane&31, same k.
// LDS rows 32 shorts (64B); 16B blocks XOR-swizzled by (row&3) -> bank-balanced b128.
template<int NTILE, bool RELU, bool ABF16, bool CBF16>
__global__ __launch_bounds__(256) void gemmbf_kernel(const void* __restrict__ A_,
                                                     const unsigned short* __restrict__ Bt,
                                                     const float* __restrict__ bias,
                                                     void* __restrict__ C_,
                                                     int M, int N, int K)
{
    constexpr int MT = (NTILE == 128) ? 2 : 1;
    __shared__ __align__(16) unsigned short Asb[128 * 32];
    __shared__ __align__(16) unsigned short Bsb[NTILE * 32];
    const int tid = threadIdx.x;
    const int lane = tid & 63, wave = tid >> 6;
    const int ln = lane & 31, hi = lane >> 5;
    const int row0 = blockIdx.y * 128, col0 = blockIdx.x * NTILE;
    const int mOff = (NTILE == 128) ? (wave >> 1) * 64 : wave * 32;
    const int nOff = (NTILE == 128) ? (wave & 1) * 64 : 0;
    const float* Af = (const float*)A_;
    const unsigned short* Ab = (const unsigned short*)A_;
    float* Cf = (float*)C_;
    unsigned short* Cb = (unsigned short*)C_;
    f32x16 acc[MT][2] = {};

    for (int k0 = 0; k0 < K; k0 += 32) {
        // stage A: 512 8-elem units (fp32->bf16 or straight bf16)
#pragma unroll
        for (int it = 0; it < 2; ++it) {
            int u = it * 256 + tid;
            int m = u >> 2, blk = u & 3;
            unsigned short s8[8];
            if (ABF16) {
                *(uint4*)s8 = *(const uint4*)&Ab[(size_t)(row0 + m) * K + k0 + blk * 8];
            } else {
                float4 v0 = *(const float4*)&Af[(size_t)(row0 + m) * K + k0 + blk * 8];
                float4 v1 = *(const float4*)&Af[(size_t)(row0 + m) * K + k0 + blk * 8 + 4];
                s8[0] = f2b(v0.x); s8[1] = f2b(v0.y); s8[2] = f2b(v0.z); s8[3] = f2b(v0.w);
                s8[4] = f2b(v1.x); s8[5] = f2b(v1.y); s8[6] = f2b(v1.z); s8[7] = f2b(v1.w);
            }
            *(uint4*)&Asb[m * 32 + ((blk ^ (m & 3)) << 3)] = *(uint4*)s8;
        }
        // stage B (bf16, coalesced rows of Bt)
#pragma unroll
        for (int it = 0; it < NTILE / 64; ++it) {
            int u = it * 256 + tid;
            int n = u >> 2, blk = u & 3;
            *(uint4*)&Bsb[n * 32 + ((blk ^ (n & 3)) << 3)] =
                *(const uint4*)&Bt[(size_t)(col0 + n) * K + k0 + blk * 8];
        }
        __syncthreads();
#pragma unroll
        for (int kh = 0; kh < 2; ++kh) {
            const int kb = kh * 2 + hi;
            bf16x8 af[MT], bfr[2];
#pragma unroll
            for (int mt = 0; mt < MT; ++mt) {
                int r = mOff + mt * 32 + ln;
                af[mt] = *(const bf16x8*)&Asb[r * 32 + ((kb ^ (r & 3)) << 3)];
            }
#pragma unroll
            for (int nt = 0; nt < 2; ++nt) {
                int r = nOff + nt * 32 + ln;
                bfr[nt] = *(const bf16x8*)&Bsb[r * 32 + ((kb ^ (r & 3)) << 3)];
            }
#pragma unroll
            for (int mt = 0; mt < MT; ++mt)
#pragma unroll
                for (int nt = 0; nt < 2; ++nt)
                    acc[mt][nt] = __builtin_amdgcn_mfma_f32_32x32x16_bf16(
                        af[mt], bfr[nt], acc[mt][nt], 0, 0, 0);
        }
        __syncthreads();
    }
    // epilogue: D row = (reg&3) + 8*(reg>>2) + 4*hi, col = ln
#pragma unroll
    for (int mt = 0; mt < MT; ++mt)
#pragma unroll
        for (int nt = 0; nt < 2; ++nt) {
            int col = col0 + nOff + nt * 32 + ln;
            float bi = bias[col];
#pragma unroll
            for (int g = 0; g < 4; ++g)
#pragma unroll
                for (int r4 = 0; r4 < 4; ++r4) {
                    int row = row0 + mOff + mt * 32 + hi * 4 + g * 8 + r4;
                    float v = acc[mt][nt][g * 4 + r4] + bi;
                    if (RELU) v = fmaxf(v, 0.f);
                    if (CBF16) Cb[(size_t)row * N + col] = f2b(v);
                    else       Cf[(size_t)row * N + col] = v;
                }
        }
}

// ---------------- attention v2: online softmax, q-tile 64, chunk 64 (fp32) ----------------
#define SWZ(blk, d) ((((blk) ^ (d)) & 15) << 2)

__global__ __launch_bounds__(256) void attn2_kernel(const float* __restrict__ qkv,
                                                    float* __restrict__ out)
{
    __shared__ float sQT[64 * 64];
    __shared__ float sKV[64 * 68];
    __shared__ float sPT[64 * 68];
    __shared__ float sM[64], sL[64], sA[64];
    const int tid = threadIdx.x;
    const int tb = blockIdx.x, h = blockIdx.y, b = blockIdx.z;
    const int t0 = tb * 64;
    const size_t base = (size_t)b * NT * 768;
    const int qoff = h * 64;
    const int g4 = tid >> 4;
    const int l4 = tid & 15;

#pragma unroll
    for (int it = 0; it < 4; ++it) {
        int i = it * 256 + tid;
        int r = i >> 4, d4 = (i & 15) << 2;
        float4 v = *(const float4*)&qkv[base + (size_t)(t0 + r) * 768 + qoff + d4];
        float vv[4] = {v.x, v.y, v.z, v.w};
#pragma unroll
        for (int j = 0; j < 4; ++j)
            sQT[(d4 + j) * 64 + SWZ(r >> 2, d4 + j) + (r & 3)] = vv[j];
    }
    if (tid < 64) { sM[tid] = -3.0e38f; sL[tid] = 0.0f; }
    __syncthreads();

    float accO[4][4] = {};

    for (int ch = 0; ch < 8; ++ch) {
        const int s0 = ch * 64;
        float4 kreg[4], vreg[4];
#pragma unroll
        for (int it = 0; it < 4; ++it) {
            int i = it * 256 + tid;
            int c = i >> 4, d4 = (i & 15) << 2;
            kreg[it] = *(const float4*)&qkv[base + (size_t)(s0 + c) * 768 + 256 + qoff + d4];
            vreg[it] = *(const float4*)&qkv[base + (size_t)(s0 + c) * 768 + 512 + qoff + d4];
        }
#pragma unroll
        for (int it = 0; it < 4; ++it) {
            int i = it * 256 + tid;
            int c = i >> 4, d4 = (i & 15) << 2;
            float kk[4] = {kreg[it].x, kreg[it].y, kreg[it].z, kreg[it].w};
#pragma unroll
            for (int j = 0; j < 4; ++j)
                sKV[(d4 + j) * 64 + SWZ(c >> 2, d4 + j) + (c & 3)] = kk[j];
        }
        __syncthreads();

        float acc[4][4] = {};
#pragma unroll 8
        for (int d = 0; d < 64; ++d) {
            float4 qa = *(const float4*)&sQT[d * 64 + SWZ(g4, d)];
            float4 kb = *(const float4*)&sKV[d * 64 + SWZ(l4, d)];
            float qq[4] = {qa.x, qa.y, qa.z, qa.w};
            float kk[4] = {kb.x, kb.y, kb.z, kb.w};
#pragma unroll
            for (int i = 0; i < 4; ++i)
#pragma unroll
                for (int j = 0; j < 4; ++j)
                    acc[i][j] = fmaf(qq[i], kk[j], acc[i][j]);
        }
#pragma unroll
        for (int i = 0; i < 4; ++i)
#pragma unroll
            for (int j = 0; j < 4; ++j)
                acc[i][j] *= 0.125f;

#pragma unroll
        for (int i = 0; i < 4; ++i) {
            float m = fmaxf(fmaxf(acc[i][0], acc[i][1]), fmaxf(acc[i][2], acc[i][3]));
#pragma unroll
            for (int o = 1; o < 16; o <<= 1) m = fmaxf(m, __shfl_xor(m, o));
            float mo = sM[g4 * 4 + i];
            float nm = fmaxf(mo, m);
            float al = expf(mo - nm);
            float s = 0.f;
#pragma unroll
            for (int j = 0; j < 4; ++j) {
                float p = expf(acc[i][j] - nm);
                acc[i][j] = p;
                s += p;
            }
#pragma unroll
            for (int o = 1; o < 16; o <<= 1) s += __shfl_xor(s, o);
            if (l4 == 0) {
                sM[g4 * 4 + i] = nm;
                sL[g4 * 4 + i] = sL[g4 * 4 + i] * al + s;
                sA[g4 * 4 + i] = al;
            }
        }
#pragma unroll
        for (int j = 0; j < 4; ++j)
            *(float4*)&sPT[(l4 * 4 + j) * 68 + g4 * 4] =
                make_float4(acc[0][j], acc[1][j], acc[2][j], acc[3][j]);
        __syncthreads();

#pragma unroll
        for (int it = 0; it < 4; ++it) {
            int i = it * 256 + tid;
            int c = i >> 4, d4 = (i & 15) << 2;
            *(float4*)&sKV[c * 68 + d4] = vreg[it];
        }
        __syncthreads();

        float4 alj = *(const float4*)&sA[l4 * 4];
        float alv[4] = {alj.x, alj.y, alj.z, alj.w};
#pragma unroll
        for (int i = 0; i < 4; ++i)
#pragma unroll
            for (int j = 0; j < 4; ++j)
                accO[i][j] *= alv[j];
#pragma unroll 8
        for (int c = 0; c < 64; ++c) {
            float4 va = *(const float4*)&sKV[c * 68 + g4 * 4];
            float4 pb = *(const float4*)&sPT[c * 68 + l4 * 4];
            float vv[4] = {va.x, va.y, va.z, va.w};
            float pp[4] = {pb.x, pb.y, pb.z, pb.w};
#pragma unroll
            for (int i = 0; i < 4; ++i)
#pragma unroll
                for (int j = 0; j < 4; ++j)
                    accO[i][j] = fmaf(vv[i], pp[j], accO[i][j]);
        }
        __syncthreads();
    }

    float4 lf = *(const float4*)&sL[l4 * 4];
    float linv[4] = {1.f / lf.x, 1.f / lf.y, 1.f / lf.z, 1.f / lf.w};
#pragma unroll
    for (int j = 0; j < 4; ++j) {
        float4 r;
        r.x = accO[0][j] * linv[j];
        r.y = accO[1][j] * linv[j];
        r.z = accO[2][j] * linv[j];
        r.w = accO[3][j] * linv[j];
        *(float4*)&out[((size_t)b * NT + t0 + l4 * 4 + j) * ND + qoff + g4 * 4] = r;
    }
}

// ---------------- x = LayerNorm(x + y) ----------------
__global__ __launch_bounds__(256) void add_ln_kernel(float* __restrict__ x,
                                                     const float* __restrict__ y,
                                                     const float* __restrict__ g,
                                                     const float* __restrict__ bta)
{
    __shared__ float red[8];
    const size_t row = blockIdx.x;
    const int d = threadIdx.x;
    float v = x[row * ND + d] + y[row * ND + d];
    float s = v;
#pragma unroll
    for (int o = 32; o; o >>= 1) s += __shfl_down(s, o);
    if ((d & 63) == 0) red[d >> 6] = s;
    __syncthreads();
    float m = (red[0] + red[1] + red[2] + red[3]) * (1.0f / 256.0f);
    float dv = v - m;
    float s2 = dv * dv;
#pragma unroll
    for (int o = 32; o; o >>= 1) s2 += __shfl_down(s2, o);
    if ((d & 63) == 0) red[4 + (d >> 6)] = s2;
    __syncthreads();
    float var = (red[4] + red[5] + red[6] + red[7]) * (1.0f / 256.0f);
    float r = 1.0f / sqrtf(var + 1e-5f);
    x[row * ND + d] = dv * r * g[d] + bta[d];
}

// ---------------- emotion MLP ----------------
__global__ __launch_bounds__(256) void emotion_kernel(const float* __restrict__ emo,
                                                      const float* __restrict__ We1,
                                                      const float* __restrict__ be1,
                                                      const float* __restrict__ We2,
                                                      const float* __restrict__ be2,
                                                      float* __restrict__ e)
{
    const int b = blockIdx.x, d = threadIdx.x;
    const float em = emo[b];
    float acc = be2[d];
    for (int j = 0; j < 64; ++j) {
        float h = fmaxf(em * We1[j] + be1[j], 0.0f);
        acc = fmaf(h, We2[j * ND + d], acc);
    }
    e[b * ND + d] = acc;
}

__global__ __launch_bounds__(256) void addfuse_kernel(float* __restrict__ x,
                                                      const float* __restrict__ e)
{
    const int row = blockIdx.x;
    const int d = threadIdx.x;
    x[(size_t)row * ND + d] += e[(row >> 9) * ND + d];
}

// ---------------- conv weight transpose: w[O,I,K] -> wt[k][c][o] fp32 ----------------
__global__ __launch_bounds__(256) void wtrans_kernel(const float* __restrict__ w,
                                                     float* __restrict__ wt,
                                                     int CIN, int COUT, int KS)
{
    int gid = blockIdx.x * 256 + threadIdx.x;
    int total = CIN * COUT * KS;
    if (gid >= total) return;
    int o = gid % COUT;
    int r = gid / COUT;
    int c = r % CIN;
    int k = r / CIN;
    wt[gid] = w[(o * CIN + c) * KS + k];
}

// ---------------- conv weight transpose: w[O,I,K] -> wtb[k][o][c] bf16 ----------------
__global__ __launch_bounds__(256) void wtransb_kernel(const float* __restrict__ w,
                                                      unsigned short* __restrict__ wtb,
                                                      int CIN, int COUT, int KS)
{
    int gid = blockIdx.x * 256 + threadIdx.x;
    int total = CIN * COUT * KS;
    if (gid >= total) return;
    int c = gid % CIN;
    int r = gid / CIN;
    int o = r % COUT;
    int k = r / COUT;
    wtb[gid] = f2b(w[(o * CIN + c) * KS + k]);
}

// ---------------- fp32 GEMM-style conv (duration predictor; must stay fp32) ----------------
template<int CIN, int KS, bool RELU, bool BN, bool GATHER>
__global__ __launch_bounds__(256, 4) void convg_kernel(const float* __restrict__ in,
                                                       const float* __restrict__ wt,
                                                       const float* __restrict__ bias,
                                                       const float* __restrict__ bng,
                                                       const float* __restrict__ bnb,
                                                       const float* __restrict__ bnm,
                                                       const float* __restrict__ bnv,
                                                       const int* __restrict__ tok,
                                                       float* __restrict__ out,
                                                       int T, int in_T, int COUT)
{
    constexpr int TM = 128;
    constexpr int PAD = (KS - 1) / 2;
    constexpr int TEXT = TM + KS - 1;
    constexpr int PITCH = (TEXT + 3) & ~3;
    __shared__ __align__(16) float As[16 * PITCH];
    __shared__ __align__(16) float Bs[16 * KS * 68];
    const int tid = threadIdx.x;
    const int lane = tid & 63, wave = tid >> 6;
    const int b = blockIdx.z;
    const int t0 = blockIdx.x * TM;
    const int o0 = blockIdx.y * 64;
    const int wt0 = wave * 32;
    const int r0 = (lane >> 3) << 2;
    const int c0 = (lane & 7) << 2;
    float acc[4][8] = {};

    for (int cc = 0; cc < CIN; cc += 16) {
        for (int i = tid; i < TEXT * 4; i += 256) {
            int t = i >> 2, q = i & 3;
            int tg = t0 - PAD + t;
            float4 v = make_float4(0.f, 0.f, 0.f, 0.f);
            if (tg >= 0 && tg < T) {
                long row;
                if (GATHER) {
                    int tk = tok[b * T + tg];
                    row = (tk >= 0) ? ((long)b * in_T + tk) : -1;
                } else {
                    row = (long)b * T + tg;
                }
                if (row >= 0) v = *(const float4*)&in[row * CIN + cc + (q << 2)];
            }
            As[((q << 2) + 0) * PITCH + t] = v.x;
            As[((q << 2) + 1) * PITCH + t] = v.y;
            As[((q << 2) + 2) * PITCH + t] = v.z;
            As[((q << 2) + 3) * PITCH + t] = v.w;
        }
        for (int i = tid; i < KS * 256; i += 256) {
            int row = i >> 4, o4 = (i & 15) << 2;
            int k = row >> 4, ci = row & 15;
            *(float4*)&Bs[row * 68 + o4] =
                *(const float4*)&wt[(size_t)(k * CIN + cc + ci) * COUT + o0 + o4];
        }
        __syncthreads();
#pragma unroll 2
        for (int ci = 0; ci < 16; ++ci) {
            float a[8];
            float4 A0 = *(const float4*)&As[ci * PITCH + wt0 + r0];
            float4 A1 = *(const float4*)&As[ci * PITCH + wt0 + r0 + 4];
            a[0] = A0.x; a[1] = A0.y; a[2] = A0.z; a[3] = A0.w;
            a[4] = A1.x; a[5] = A1.y; a[6] = A1.z; a[7] = A1.w;
#pragma unroll
            for (int k = 0; k < KS; ++k) {
                float4 b0 = *(const float4*)&Bs[(k * 16 + ci) * 68 + c0];
                float4 b1 = *(const float4*)&Bs[(k * 16 + ci) * 68 + 32 + c0];
                float bb[8] = {b0.x, b0.y, b0.z, b0.w, b1.x, b1.y, b1.z, b1.w};
#pragma unroll
                for (int i = 0; i < 4; ++i)
#pragma unroll
                    for (int j = 0; j < 8; ++j)
                        acc[i][j] = fmaf(a[i + k], bb[j], acc[i][j]);
            }
        }
        __syncthreads();
    }

    float4 bi0 = *(const float4*)(bias + o0 + c0);
    float4 bi1 = *(const float4*)(bias + o0 + 32 + c0);
    float bb[8] = {bi0.x, bi0.y, bi0.z, bi0.w, bi1.x, bi1.y, bi1.z, bi1.w};
    float sc[8], sh[8];
    if (BN) {
        float4 g0 = *(const float4*)(bng + o0 + c0);
        float4 g1 = *(const float4*)(bng + o0 + 32 + c0);
        float4 t0v = *(const float4*)(bnb + o0 + c0);
        float4 t1v = *(const float4*)(bnb + o0 + 32 + c0);
        float4 m0 = *(const float4*)(bnm + o0 + c0);
        float4 m1 = *(const float4*)(bnm + o0 + 32 + c0);
        float4 v0 = *(const float4*)(bnv + o0 + c0);
        float4 v1 = *(const float4*)(bnv + o0 + 32 + c0);
        float gg[8] = {g0.x, g0.y, g0.z, g0.w, g1.x, g1.y, g1.z, g1.w};
        float tb[8] = {t0v.x, t0v.y, t0v.z, t0v.w, t1v.x, t1v.y, t1v.z, t1v.w};
        float mm[8] = {m0.x, m0.y, m0.z, m0.w, m1.x, m1.y, m1.z, m1.w};
        float vv[8] = {v0.x, v0.y, v0.z, v0.w, v1.x, v1.y, v1.z, v1.w};
#pragma unroll
        for (int j = 0; j < 8; ++j) {
            sc[j] = gg[j] / sqrtf(vv[j] + 1e-5f);
            sh[j] = tb[j] - mm[j] * sc[j];
        }
    }
#pragma unroll
    for (int i = 0; i < 4; ++i) {
        int r = t0 + wt0 + r0 + i;
#pragma unroll
        for (int jh = 0; jh < 2; ++jh) {
            float o4[4];
#pragma unroll
            for (int j = 0; j < 4; ++j) {
                float yv = acc[i][jh * 4 + j] + bb[jh * 4 + j];
                if (RELU) yv = fmaxf(yv, 0.0f);
                if (BN) yv = yv * sc[jh * 4 + j] + sh[jh * 4 + j];
                o4[j] = yv;
            }
            *(float4*)&out[((size_t)b * T + r) * COUT + o0 + jh * 32 + c0] =
                make_float4(o4[0], o4[1], o4[2], o4[3]);
        }
    }
}

// ---------------- bf16 MFMA conv (decoder; downstream of dur) ----------------
template<int CIN, int KS, bool GATHER, bool IN_BF16>
__global__ __launch_bounds__(256) void convmf_kernel(const void* __restrict__ in_,
                                                     const unsigned short* __restrict__ wtb,
                                                     const float* __restrict__ bias,
                                                     const int* __restrict__ tok,
                                                     unsigned short* __restrict__ out,
                                                     int T, int in_T, int COUT)
{
    constexpr int TM = 128;
    constexpr int PAD = (KS - 1) / 2;
    constexpr int TEXT = TM + KS - 1;
    constexpr int PITCHA = 40;
    __shared__ __align__(16) unsigned short As[TEXT * PITCHA];
    const int tid = threadIdx.x;
    const int lane = tid & 63, wave = tid >> 6;
    const int m = lane & 15, quad = lane >> 4;
    const int b = blockIdx.z;
    const int t0 = blockIdx.x * TM;
    const int o0 = blockIdx.y * 64;
    const int woff = wave * 32;
    f32x4 acc[2][4] = {};

    const float* inf = (const float*)in_;
    const unsigned short* inb = (const unsigned short*)in_;

    for (int cc = 0; cc < CIN; cc += 32) {
        for (int i = tid; i < TEXT * 8; i += 256) {
            int t = i >> 3, ci4 = (i & 7) << 2;
            int tg = t0 - PAD + t;
            long row = -1;
            if (tg >= 0 && tg < T) {
                if (GATHER) {
                    int tk = tok[b * T + tg];
                    if (tk >= 0) row = (long)b * in_T + tk;
                } else {
                    row = (long)b * T + tg;
                }
            }
            unsigned short s4[4] = {0, 0, 0, 0};
            if (row >= 0) {
                if (IN_BF16) {
                    *(uint2*)s4 = *(const uint2*)&inb[row * CIN + cc + ci4];
                } else {
                    float4 v = *(const float4*)&inf[row * CIN + cc + ci4];
                    s4[0] = f2b(v.x); s4[1] = f2b(v.y);
                    s4[2] = f2b(v.z); s4[3] = f2b(v.w);
                }
            }
            *(uint2*)&As[t * PITCHA + ci4] = *(uint2*)s4;
        }
        __syncthreads();
#pragma unroll
        for (int tap = 0; tap < KS; ++tap) {
            bf16x8 a0 = *(const bf16x8*)&As[(woff + 0  + m + tap) * PITCHA + quad * 8];
            bf16x8 a1 = *(const bf16x8*)&As[(woff + 16 + m + tap) * PITCHA + quad * 8];
#pragma unroll
            for (int ot = 0; ot < 4; ++ot) {
                bf16x8 bf = *(const bf16x8*)&wtb[((size_t)tap * COUT + o0 + ot * 16 + m) * CIN + cc + quad * 8];
                acc[0][ot] = __builtin_amdgcn_mfma_f32_16x16x32_bf16(a0, bf, acc[0][ot], 0, 0, 0);
                acc[1][ot] = __builtin_amdgcn_mfma_f32_16x16x32_bf16(a1, bf, acc[1][ot], 0, 0, 0);
            }
        }
        __syncthreads();
    }

#pragma unroll
    for (int ot = 0; ot < 4; ++ot) {
        int o = o0 + ot * 16 + m;
        float bi = bias[o];
#pragma unroll
        for (int mt = 0; mt < 2; ++mt)
#pragma unroll
            for (int r = 0; r < 4; ++r) {
                int t = t0 + woff + mt * 16 + quad * 4 + r;
                float yv = fmaxf(acc[mt][ot][r] + bi, 0.0f);
                out[((size_t)b * T + t) * COUT + o] = f2b(yv);
            }
    }
}

// ---------------- duration: log_dur -> dur ----------------
__global__ __launch_bounds__(256) void dur_kernel(const float* __restrict__ h2,
                                                  const float* __restrict__ wo,
                                                  const float* __restrict__ bo,
                                                  int* __restrict__ dur)
{
    __shared__ float red[4];
    const int row = blockIdx.x;
    const int c = threadIdx.x;
    float s = h2[(size_t)row * ND + c] * wo[c];
#pragma unroll
    for (int o = 32; o; o >>= 1) s += __shfl_down(s, o);
    if ((c & 63) == 0) red[c >> 6] = s;
    __syncthreads();
    if (c == 0) {
        float ld = red[0] + red[1] + red[2] + red[3] + bo[0];
        float d = rintf(expf(ld));
        d = fminf(fmaxf(d, 1.0f), 8.0f);
        dur[row] = (int)d;
    }
}

__global__ __launch_bounds__(64) void scan_kernel(const int* __restrict__ dur,
                                                  int* __restrict__ starts,
                                                  int* __restrict__ totals)
{
    const int b = threadIdx.x;
    if (b >= NB) return;
    int acc = 0;
    for (int t = 0; t < NT; ++t) {
        starts[b * NT + t] = acc;
        acc += dur[b * NT + t];
    }
    totals[b] = acc;
}

__global__ __launch_bounds__(256) void tok_kernel(const int* __restrict__ starts,
                                                  const int* __restrict__ totals,
                                                  int* __restrict__ tok)
{
    const int gid = blockIdx.x * 256 + threadIdx.x;
    const int b = gid >> 11, p = gid & (TOUT - 1);
    const int total = totals[b];
    int res = -1;
    if (p < total) {
        const int* st = starts + b * NT;
        int lo = 0, hi = NT - 1;
        while (lo < hi) {
            int mid = (lo + hi + 1) >> 1;
            if (st[mid] <= p) lo = mid; else hi = mid - 1;
        }
        res = lo;
    }
    tok[gid] = res;
}

// ---------------- decoder conv3: bf16 [B,2048,128] -> wav fp32 [B,2048] ----------------
__global__ __launch_bounds__(256) void conv3_kernel(const unsigned short* __restrict__ in,
                                                    const float* __restrict__ w,
                                                    const float* __restrict__ bias,
                                                    float* __restrict__ out)
{
    const int gid = blockIdx.x * 256 + threadIdx.x;
    const int b = gid >> 11, t = gid & (TOUT - 1);
    float acc = bias[0];
#pragma unroll
    for (int k = 0; k < 5; ++k) {
        int t2 = t + k - 2;
        if (t2 < 0 || t2 >= TOUT) continue;
        const unsigned short* row = in + ((size_t)b * TOUT + t2) * 128;
        for (int c = 0; c < 128; ++c) acc = fmaf(b2f(row[c]), w[c * 5 + k], acc);
    }
    out[gid] = acc;
}

// ---------------- orchestration ----------------
extern "C" void kernel_launch(void* const* d_in, const int* in_sizes, int n_in,
                              void* d_out, int out_size, void* d_ws, size_t ws_size,
                              hipStream_t stream)
{
    const int*   text    = (const int*)d_in[0];
    const float* emotion = (const float*)d_in[1];
    const float* emb     = (const float*)d_in[2];
    const float* Wqkv    = (const float*)d_in[3];
    const float* bqkv    = (const float*)d_in[4];
    const float* Wo      = (const float*)d_in[5];
    const float* bo      = (const float*)d_in[6];
    const float* W1      = (const float*)d_in[7];
    const float* b1      = (const float*)d_in[8];
    const float* W2      = (const float*)d_in[9];
    const float* b2      = (const float*)d_in[10];
    const float* ln1g    = (const float*)d_in[11];
    const float* ln1b    = (const float*)d_in[12];
    const float* ln2g    = (const float*)d_in[13];
    const float* ln2b    = (const float*)d_in[14];
    const float* We1     = (const float*)d_in[15];
    const float* be1     = (const float*)d_in[16];
    const float* We2     = (const float*)d_in[17];
    const float* be2     = (const float*)d_in[18];
    const float* dp_w1   = (const float*)d_in[19];
    const float* dp_b1   = (const float*)d_in[20];
    const float* dp_g1   = (const float*)d_in[21];
    const float* dp_bt1  = (const float*)d_in[22];
    const float* dp_m1   = (const float*)d_in[23];
    const float* dp_v1   = (const float*)d_in[24];
    const float* dp_w2   = (const float*)d_in[25];
    const float* dp_b2   = (const float*)d_in[26];
    const float* dp_g2   = (const float*)d_in[27];
    const float* dp_bt2  = (const float*)d_in[28];
    const float* dp_m2   = (const float*)d_in[29];
    const float* dp_v2   = (const float*)d_in[30];
    const float* dp_wo   = (const float*)d_in[31];
    const float* dp_bo   = (const float*)d_in[32];
    const float* dec_w1  = (const float*)d_in[33];
    const float* dec_b1  = (const float*)d_in[34];
    const float* dec_w2  = (const float*)d_in[35];
    const float* dec_b2  = (const float*)d_in[36];
    const float* dec_w3  = (const float*)d_in[37];
    const float* dec_b3  = (const float*)d_in[38];

    float* ws   = (float*)d_ws;
    float* x    = ws + OFF_X;
    unsigned short* ffhB = (unsigned short*)(ws + OFF_FFH);   // ff hidden bf16 / d1b
    unsigned short* Wbt  = (unsigned short*)(ws + OFF_WBT);   // transformer weights bf16 [N][K]
    float* wtdp1 = ws + OFF_CWT;                  // 196608 f
    float* wtdp2 = wtdp1 + 196608;                // 196608 f
    unsigned short* wtb1 = (unsigned short*)(wtdp2 + 196608); // 327680 sh
    unsigned short* wtb2 = wtb1 + 327680;                     // 163840 sh
    float* qkvb = ws + OFF_QKV;
    float* attb = ws + OFF_ATTN;
    float* prjb = ws + OFF_PROJ;
    float* ebuf = ws + OFF_E;
    unsigned short* d1b  = ffhB;
    unsigned short* d2b  = (unsigned short*)attb;
    int*   ip     = (int*)(ws + OFF_INT);
    int*   durb   = ip;
    int*   startb = ip + 16384;
    int*   totb   = ip + 32768;
    int*   tokb   = ip + 32832;

    const int M = NB * NT;   // 16384

    embed_kernel<<<M, 256, 0, stream>>>(text, emb, x);

    // transformer weights -> bf16 [N][K], per-layer stride 786432 shorts
    wq_kernel<<<dim3(24, 8, 6), 256, 0, stream>>>(Wqkv, Wbt + 0,      256, 768,  196608, 786432);
    wq_kernel<<<dim3(8,  8, 6), 256, 0, stream>>>(Wo,   Wbt + 196608, 256, 256,  65536,  786432);
    wq_kernel<<<dim3(32, 8, 6), 256, 0, stream>>>(W1,   Wbt + 262144, 256, 1024, 262144, 786432);
    wq_kernel<<<dim3(8, 32, 6), 256, 0, stream>>>(W2,   Wbt + 524288, 1024, 256, 262144, 786432);

    for (int l = 0; l < NLAYER; ++l) {
        const unsigned short* WQ  = Wbt + (size_t)l * 786432;
        const unsigned short* WO  = WQ + 196608;
        const unsigned short* WF1 = WQ + 262144;
        const unsigned short* WF2 = WQ + 524288;
        gemmbf_kernel<128, false, false, false><<<dim3(6, 128), 256, 0, stream>>>(
            x, WQ, bqkv + l * 768, qkvb, M, 768, 256);
        attn2_kernel<<<dim3(NT / 64, NH, NB), 256, 0, stream>>>(qkvb, attb);
        gemmbf_kernel<64, false, false, false><<<dim3(4, 128), 256, 0, stream>>>(
            attb, WO, bo + l * 256, prjb, M, 256, 256);
        add_ln_kernel<<<M, 256, 0, stream>>>(x, prjb, ln1g + l * ND, ln1b + l * ND);
        gemmbf_kernel<128, true, false, true><<<dim3(8, 128), 256, 0, stream>>>(
            x, WF1, b1 + l * 1024, ffhB, M, 1024, 256);
        gemmbf_kernel<64, false, true, false><<<dim3(4, 128), 256, 0, stream>>>(
            ffhB, WF2, b2 + l * 256, prjb, M, 256, 1024);
        add_ln_kernel<<<M, 256, 0, stream>>>(x, prjb, ln2g + l * ND, ln2b + l * ND);
    }

    emotion_kernel<<<NB, 256, 0, stream>>>(emotion, We1, be1, We2, be2, ebuf);
    addfuse_kernel<<<M, 256, 0, stream>>>(x, ebuf);

    // conv weight transposes
    wtrans_kernel<<<(256 * 256 * 3 + 255) / 256, 256, 0, stream>>>(dp_w1, wtdp1, 256, 256, 3);
    wtrans_kernel<<<(256 * 256 * 3 + 255) / 256, 256, 0, stream>>>(dp_w2, wtdp2, 256, 256, 3);
    wtransb_kernel<<<(256 * 256 * 5 + 255) / 256, 256, 0, stream>>>(dec_w1, wtb1, 256, 256, 5);
    wtransb_kernel<<<(128 * 256 * 5 + 255) / 256, 256, 0, stream>>>(dec_w2, wtb2, 256, 128, 5);

    // duration predictor convs (fp32 mandatory: feeds dur rounding)
    convg_kernel<256, 3, true, true, false><<<dim3(NT / 128, 4, NB), 256, 0, stream>>>(
        x, wtdp1, dp_b1, dp_g1, dp_bt1, dp_m1, dp_v1, nullptr, attb, NT, NT, 256);
    convg_kernel<256, 3, true, true, false><<<dim3(NT / 128, 4, NB), 256, 0, stream>>>(
        attb, wtdp2, dp_b2, dp_g2, dp_bt2, dp_m2, dp_v2, nullptr, prjb, NT, NT, 256);
    dur_kernel<<<M, 256, 0, stream>>>(prjb, dp_wo, dp_bo, durb);
    scan_kernel<<<1, 64, 0, stream>>>(durb, startb, totb);
    tok_kernel<<<NB * TOUT / 256, 256, 0, stream>>>(startb, totb, tokb);

    // decoder: bf16 MFMA convs (downstream of dur)
    convmf_kernel<256, 5, true, false><<<dim3(TOUT / 128, 4, NB), 256, 0, stream>>>(
        x, wtb1, dec_b1, tokb, d1b, TOUT, NT, 256);
    convmf_kernel<256, 5, false, true><<<dim3(TOUT / 128, 2, NB), 256, 0, stream>>>(
        d1b, wtb2, dec_b2, nullptr, d2b, TOUT, TOUT, 128);
    conv3_kernel<<<NB * TOUT / 256, 256, 0, stream>>>(d2b, dec_w3, dec_b3, (float*)d_out);
}

// Round 7
// 1688.571 us; speedup vs baseline: 3.2783x; 1.4907x over previous
//
#include <hip/hip_runtime.h>
#include <math.h>

#define NB 32
#define NT 512
#define ND 256
#define NH 4
#define NLAYER 6
#define TOUT 2048

typedef __attribute__((ext_vector_type(8))) short bf16x8;
typedef __attribute__((ext_vector_type(4))) float f32x4;
typedef __attribute__((ext_vector_type(16))) float f32x16;

static __device__ __forceinline__ unsigned short f2b(float f) {
    union { float f; unsigned int u; } x; x.f = f;
    unsigned int u = x.u;
    return (unsigned short)((u + 0x7FFFu + ((u >> 16) & 1u)) >> 16);
}
static __device__ __forceinline__ float b2f(unsigned short s) {
    union { unsigned int u; float f; } x; x.u = ((unsigned int)s) << 16;
    return x.f;
}

// ---------------- workspace layout (float offsets) ----------------
#define OFF_X    0ull          // 4,194,304   x fp32 [B,T,256] (residual; dur-critical)
#define OFF_FFH  4194304ull    // 8,388,608   ffh bf16 [16384,1024]; later d1b bf16
#define OFF_WBT  12582912ull   // 2,359,296   transformer weights bf16 [N][K]
#define OFF_CWT  14942208ull   // 638,976     conv weights (dp fp32 + dec bf16)
#define OFF_QKV  20971520ull   // qkv bf16 [16384,768] (6.29M f) + vt bf16 [128,64,512] (2.1M f)
#define OFF_ATTN 33554432ull   // attn out bf16 / dp h1 fp32; later d2b bf16
#define OFF_PROJ 37748736ull   // proj / ff2 out fp32 / dp h2
#define OFF_E    41943040ull   // emotion e
#define OFF_INT  41951232ull   // ints: dur, starts, totals, tok

// ---------------- embedding + positional encoding ----------------
__global__ __launch_bounds__(256) void embed_kernel(const int* __restrict__ text,
                                                    const float* __restrict__ emb,
                                                    float* __restrict__ x)
{
    const int row = blockIdx.x;
    const int d = threadIdx.x;
    const int t = row & (NT - 1);
    const int id = text[row];
    const int j2 = (d >> 1) * 2;
    const float c = -9.210340371976184f / 256.0f;
    float freq = expf((float)j2 * c);
    float ang = (float)t * freq;
    float pe = (d & 1) ? cosf(ang) : sinf(ang);
    x[(size_t)row * ND + d] = emb[(size_t)id * ND + d] + pe;
}

// ---------------- weight transpose: fp32 [K,N] -> bf16 [N,K], batched over layers ----------------
__global__ __launch_bounds__(256) void wq_kernel(const float* __restrict__ W,
                                                 unsigned short* __restrict__ out,
                                                 int K, int N, int inLS, int outLS)
{
    __shared__ float tile[32][33];
    const float* Wl = W + (size_t)blockIdx.z * inLS;
    unsigned short* ol = out + (size_t)blockIdx.z * outLS;
    const int n0 = blockIdx.x * 32, k0 = blockIdx.y * 32;
    const int tx = threadIdx.x & 31, ty = threadIdx.x >> 5;
#pragma unroll
    for (int j = 0; j < 4; ++j)
        tile[ty + j * 8][tx] = Wl[(size_t)(k0 + ty + j * 8) * N + n0 + tx];
    __syncthreads();
#pragma unroll
    for (int j = 0; j < 4; ++j)
        ol[(size_t)(n0 + ty + j * 8) * K + k0 + tx] = f2b(tile[tx][ty + j * 8]);
}

// ---------------- bf16 MFMA GEMM: C[M,N] = A[M,K] @ B[K,N] + bias ----------------
template<int NTILE, bool RELU, bool ABF16, bool CBF16>
__global__ __launch_bounds__(256) void gemmbf_kernel(const void* __restrict__ A_,
                                                     const unsigned short* __restrict__ Bt,
                                                     const float* __restrict__ bias,
                                                     void* __restrict__ C_,
                                                     int M, int N, int K)
{
    constexpr int MT = (NTILE == 128) ? 2 : 1;
    __shared__ __align__(16) unsigned short Asb[128 * 32];
    __shared__ __align__(16) unsigned short Bsb[NTILE * 32];
    const int tid = threadIdx.x;
    const int lane = tid & 63, wave = tid >> 6;
    const int ln = lane & 31, hi = lane >> 5;
    const int row0 = blockIdx.y * 128, col0 = blockIdx.x * NTILE;
    const int mOff = (NTILE == 128) ? (wave >> 1) * 64 : wave * 32;
    const int nOff = (NTILE == 128) ? (wave & 1) * 64 : 0;
    const float* Af = (const float*)A_;
    const unsigned short* Ab = (const unsigned short*)A_;
    float* Cf = (float*)C_;
    unsigned short* Cb = (unsigned short*)C_;
    f32x16 acc[MT][2] = {};

    for (int k0 = 0; k0 < K; k0 += 32) {
#pragma unroll
        for (int it = 0; it < 2; ++it) {
            int u = it * 256 + tid;
            int m = u >> 2, blk = u & 3;
            unsigned short s8[8];
            if (ABF16) {
                *(uint4*)s8 = *(const uint4*)&Ab[(size_t)(row0 + m) * K + k0 + blk * 8];
            } else {
                float4 v0 = *(const float4*)&Af[(size_t)(row0 + m) * K + k0 + blk * 8];
                float4 v1 = *(const float4*)&Af[(size_t)(row0 + m) * K + k0 + blk * 8 + 4];
                s8[0] = f2b(v0.x); s8[1] = f2b(v0.y); s8[2] = f2b(v0.z); s8[3] = f2b(v0.w);
                s8[4] = f2b(v1.x); s8[5] = f2b(v1.y); s8[6] = f2b(v1.z); s8[7] = f2b(v1.w);
            }
            *(uint4*)&Asb[m * 32 + ((blk ^ (m & 3)) << 3)] = *(uint4*)s8;
        }
#pragma unroll
        for (int it = 0; it < NTILE / 64; ++it) {
            int u = it * 256 + tid;
            int n = u >> 2, blk = u & 3;
            *(uint4*)&Bsb[n * 32 + ((blk ^ (n & 3)) << 3)] =
                *(const uint4*)&Bt[(size_t)(col0 + n) * K + k0 + blk * 8];
        }
        __syncthreads();
#pragma unroll
        for (int kh = 0; kh < 2; ++kh) {
            const int kb = kh * 2 + hi;
            bf16x8 af[MT], bfr[2];
#pragma unroll
            for (int mt = 0; mt < MT; ++mt) {
                int r = mOff + mt * 32 + ln;
                af[mt] = *(const bf16x8*)&Asb[r * 32 + ((kb ^ (r & 3)) << 3)];
            }
#pragma unroll
            for (int nt = 0; nt < 2; ++nt) {
                int r = nOff + nt * 32 + ln;
                bfr[nt] = *(const bf16x8*)&Bsb[r * 32 + ((kb ^ (r & 3)) << 3)];
            }
#pragma unroll
            for (int mt = 0; mt < MT; ++mt)
#pragma unroll
                for (int nt = 0; nt < 2; ++nt)
                    acc[mt][nt] = __builtin_amdgcn_mfma_f32_32x32x16_bf16(
                        af[mt], bfr[nt], acc[mt][nt], 0, 0, 0);
        }
        __syncthreads();
    }
#pragma unroll
    for (int mt = 0; mt < MT; ++mt)
#pragma unroll
        for (int nt = 0; nt < 2; ++nt) {
            int col = col0 + nOff + nt * 32 + ln;
            float bi = bias[col];
#pragma unroll
            for (int g = 0; g < 4; ++g)
#pragma unroll
                for (int r4 = 0; r4 < 4; ++r4) {
                    int row = row0 + mOff + mt * 32 + hi * 4 + g * 8 + r4;
                    float v = acc[mt][nt][g * 4 + r4] + bi;
                    if (RELU) v = fmaxf(v, 0.f);
                    if (CBF16) Cb[(size_t)row * N + col] = f2b(v);
                    else       Cf[(size_t)row * N + col] = v;
                }
        }
}

// ---------------- V transpose per layer: qkv bf16 -> vt[b,h,d,t] bf16 ----------------
__global__ __launch_bounds__(256) void vtrans_kernel(const unsigned short* __restrict__ qkv,
                                                     unsigned short* __restrict__ vt)
{
    __shared__ unsigned short tile[64][65];
    const int t0 = blockIdx.x * 64, h = blockIdx.y, b = blockIdx.z;
    const int tid = threadIdx.x;
#pragma unroll
    for (int it = 0; it < 2; ++it) {
        int u = it * 256 + tid;
        int t = u >> 3, d8 = (u & 7) * 8;
        bf16x8 v = *(const bf16x8*)&qkv[((size_t)(b * NT) + t0 + t) * 768 + 512 + h * 64 + d8];
#pragma unroll
        for (int j = 0; j < 8; ++j) tile[t][d8 + j] = (unsigned short)v[j];
    }
    __syncthreads();
#pragma unroll
    for (int it = 0; it < 2; ++it) {
        int u = it * 256 + tid;
        int d = u >> 3, t8 = (u & 7) * 8;
        unsigned short s8[8];
#pragma unroll
        for (int j = 0; j < 8; ++j) s8[j] = tile[t8 + j][d];
        *(uint4*)&vt[((size_t)(b * NH + h) * 64 + d) * NT + t0 + t8] = *(uint4*)s8;
    }
}

// ---------------- attention v3: bf16 MFMA flash, computes O^T ----------------
// Per WG: (qtile of 128, h, b); wave owns 32 q-rows. S: A=Q(row=q), B=K(col=key).
// PV as O^T: A = vt frags from global (row=d), B = P natural LDS (col=q).
__global__ __launch_bounds__(256, 2) void attn3_kernel(const unsigned short* __restrict__ qkv,
                                                       const unsigned short* __restrict__ vt,
                                                       unsigned short* __restrict__ out)
{
    __shared__ __align__(16) unsigned short sP[4][32 * 64];
    const int tid = threadIdx.x;
    const int lane = tid & 63, wave = tid >> 6;
    const int ln = lane & 31, hi = lane >> 5;
    const int h = blockIdx.y, b = blockIdx.z;
    const int q0 = blockIdx.x * 128 + wave * 32;
    const size_t base = (size_t)b * NT * 768;
    const int qoff = h * 64;
    const unsigned short* vbh = vt + (size_t)(b * NH + h) * 64 * NT;

    bf16x8 qf[4];
#pragma unroll
    for (int s = 0; s < 4; ++s)
        qf[s] = *(const bf16x8*)&qkv[base + (size_t)(q0 + ln) * 768 + qoff + s * 16 + hi * 8];

    float mrow[16], lrow[16];
#pragma unroll
    for (int i = 0; i < 16; ++i) { mrow[i] = -1e30f; lrow[i] = 0.f; }
    f32x16 oacc[2] = {};
    const float sc = 0.18033688011112042f;   // 0.125 * log2(e): softmax in exp2 domain
    const int i0 = (ln & 3) | (((ln >> 3) & 3) << 2);
    const bool own = (((ln >> 2) & 1) == hi);
    unsigned short* Pw = &sP[wave][0];

    for (int ch = 0; ch < 8; ++ch) {
        const int s0 = ch * 64;
        f32x16 sacc[2] = {};
#pragma unroll
        for (int ct = 0; ct < 2; ++ct)
#pragma unroll
            for (int s = 0; s < 4; ++s) {
                bf16x8 kf = *(const bf16x8*)&qkv[base + (size_t)(s0 + ct * 32 + ln) * 768
                                                 + 256 + qoff + s * 16 + hi * 8];
                sacc[ct] = __builtin_amdgcn_mfma_f32_32x32x16_bf16(qf[s], kf, sacc[ct], 0, 0, 0);
            }
        float alpha[16];
#pragma unroll
        for (int i = 0; i < 16; ++i) {
            float s20 = sacc[0][i] * sc, s21 = sacc[1][i] * sc;
            float mx = fmaxf(s20, s21);
#pragma unroll
            for (int o = 1; o < 32; o <<= 1) mx = fmaxf(mx, __shfl_xor(mx, o));
            float mn = fmaxf(mrow[i], mx);
            alpha[i] = exp2f(mrow[i] - mn);
            mrow[i] = mn;
            float p0 = exp2f(s20 - mn);
            float p1 = exp2f(s21 - mn);
            sacc[0][i] = p0; sacc[1][i] = p1;
            float rs = p0 + p1;
#pragma unroll
            for (int o = 1; o < 32; o <<= 1) rs += __shfl_xor(rs, o);
            lrow[i] = lrow[i] * alpha[i] + rs;
        }
        // write P natural [q][key] with 16B-block xor swizzle (pitch 64 shorts)
#pragma unroll
        for (int ct = 0; ct < 2; ++ct) {
            int kb = ct * 4 + (ln >> 3), k7 = ln & 7;
#pragma unroll
            for (int i = 0; i < 16; ++i) {
                int q = (i & 3) + 8 * (i >> 2) + 4 * hi;
                Pw[q * 64 + (((kb ^ (q & 7)) << 3) | k7)] = f2b(sacc[ct][i]);
            }
        }
        __syncthreads();
        // rescale O^T cols by alpha[q=ln]
        {
            float av = alpha[i0];
            float ao = __shfl_xor(av, 32);
            float aq = own ? av : ao;
#pragma unroll
            for (int ct = 0; ct < 2; ++ct)
#pragma unroll
                for (int i = 0; i < 16; ++i)
                    oacc[ct][i] *= aq;
        }
        // O^T += VT * P
#pragma unroll
        for (int s = 0; s < 4; ++s) {
            bf16x8 pf = *(const bf16x8*)&Pw[ln * 64 + (((s * 2 + hi) ^ (ln & 7)) << 3)];
#pragma unroll
            for (int ct = 0; ct < 2; ++ct) {
                bf16x8 vf = *(const bf16x8*)&vbh[(size_t)(ct * 32 + ln) * NT + s0 + s * 16 + hi * 8];
                oacc[ct] = __builtin_amdgcn_mfma_f32_32x32x16_bf16(vf, pf, oacc[ct], 0, 0, 0);
            }
        }
        __syncthreads();
    }
    float lv = lrow[i0];
    float lo = __shfl_xor(lv, 32);
    float linv = 1.0f / (own ? lv : lo);
    const int q = q0 + ln;
#pragma unroll
    for (int ct = 0; ct < 2; ++ct)
#pragma unroll
        for (int i = 0; i < 16; ++i) {
            int d = ct * 32 + (i & 3) + 8 * (i >> 2) + 4 * hi;
            out[(size_t)(b * NT + q) * ND + qoff + d] = f2b(oacc[ct][i] * linv);
        }
}

// ---------------- x = LayerNorm(x + y), wave-per-row ----------------
__global__ __launch_bounds__(256) void add_ln_kernel(float* __restrict__ x,
                                                     const float* __restrict__ y,
                                                     const float* __restrict__ g,
                                                     const float* __restrict__ bta)
{
    const int w = threadIdx.x >> 6, lane = threadIdx.x & 63;
    const size_t row = (size_t)blockIdx.x * 4 + w;
    const int c4 = lane * 4;
    float4 xv = *(const float4*)&x[row * ND + c4];
    float4 yv = *(const float4*)&y[row * ND + c4];
    float4 v = make_float4(xv.x + yv.x, xv.y + yv.y, xv.z + yv.z, xv.w + yv.w);
    float s = v.x + v.y + v.z + v.w;
#pragma unroll
    for (int o = 1; o < 64; o <<= 1) s += __shfl_xor(s, o);
    float m = s * (1.0f / 256.0f);
    float4 dv = make_float4(v.x - m, v.y - m, v.z - m, v.w - m);
    float s2 = dv.x * dv.x + dv.y * dv.y + dv.z * dv.z + dv.w * dv.w;
#pragma unroll
    for (int o = 1; o < 64; o <<= 1) s2 += __shfl_xor(s2, o);
    float r = 1.0f / sqrtf(s2 * (1.0f / 256.0f) + 1e-5f);
    float4 gv = *(const float4*)&g[c4];
    float4 bv = *(const float4*)&bta[c4];
    float4 o4 = make_float4(dv.x * r * gv.x + bv.x, dv.y * r * gv.y + bv.y,
                            dv.z * r * gv.z + bv.z, dv.w * r * gv.w + bv.w);
    *(float4*)&x[row * ND + c4] = o4;
}

// ---------------- emotion MLP ----------------
__global__ __launch_bounds__(256) void emotion_kernel(const float* __restrict__ emo,
                                                      const float* __restrict__ We1,
                                                      const float* __restrict__ be1,
                                                      const float* __restrict__ We2,
                                                      const float* __restrict__ be2,
                                                      float* __restrict__ e)
{
    const int b = blockIdx.x, d = threadIdx.x;
    const float em = emo[b];
    float acc = be2[d];
    for (int j = 0; j < 64; ++j) {
        float h = fmaxf(em * We1[j] + be1[j], 0.0f);
        acc = fmaf(h, We2[j * ND + d], acc);
    }
    e[b * ND + d] = acc;
}

__global__ __launch_bounds__(256) void addfuse_kernel(float* __restrict__ x,
                                                      const float* __restrict__ e)
{
    const int row = blockIdx.x;
    const int d = threadIdx.x;
    x[(size_t)row * ND + d] += e[(row >> 9) * ND + d];
}

// ---------------- conv weight transposes ----------------
__global__ __launch_bounds__(256) void wtrans_kernel(const float* __restrict__ w,
                                                     float* __restrict__ wt,
                                                     int CIN, int COUT, int KS)
{
    int gid = blockIdx.x * 256 + threadIdx.x;
    int total = CIN * COUT * KS;
    if (gid >= total) return;
    int o = gid % COUT;
    int r = gid / COUT;
    int c = r % CIN;
    int k = r / CIN;
    wt[gid] = w[(o * CIN + c) * KS + k];
}

__global__ __launch_bounds__(256) void wtransb_kernel(const float* __restrict__ w,
                                                      unsigned short* __restrict__ wtb,
                                                      int CIN, int COUT, int KS)
{
    int gid = blockIdx.x * 256 + threadIdx.x;
    int total = CIN * COUT * KS;
    if (gid >= total) return;
    int c = gid % CIN;
    int r = gid / CIN;
    int o = r % COUT;
    int k = r / COUT;
    wtb[gid] = f2b(w[(o * CIN + c) * KS + k]);
}

// ---------------- fp32 GEMM-style conv (duration predictor; must stay fp32) ----------------
template<int CIN, int KS, bool RELU, bool BN, bool GATHER>
__global__ __launch_bounds__(256, 4) void convg_kernel(const float* __restrict__ in,
                                                       const float* __restrict__ wt,
                                                       const float* __restrict__ bias,
                                                       const float* __restrict__ bng,
                                                       const float* __restrict__ bnb,
                                                       const float* __restrict__ bnm,
                                                       const float* __restrict__ bnv,
                                                       const int* __restrict__ tok,
                                                       float* __restrict__ out,
                                                       int T, int in_T, int COUT)
{
    constexpr int TM = 128;
    constexpr int PAD = (KS - 1) / 2;
    constexpr int TEXT = TM + KS - 1;
    constexpr int PITCH = (TEXT + 3) & ~3;
    __shared__ __align__(16) float As[16 * PITCH];
    __shared__ __align__(16) float Bs[16 * KS * 68];
    const int tid = threadIdx.x;
    const int lane = tid & 63, wave = tid >> 6;
    const int b = blockIdx.z;
    const int t0 = blockIdx.x * TM;
    const int o0 = blockIdx.y * 64;
    const int wt0 = wave * 32;
    const int r0 = (lane >> 3) << 2;
    const int c0 = (lane & 7) << 2;
    float acc[4][8] = {};

    for (int cc = 0; cc < CIN; cc += 16) {
        for (int i = tid; i < TEXT * 4; i += 256) {
            int t = i >> 2, q = i & 3;
            int tg = t0 - PAD + t;
            float4 v = make_float4(0.f, 0.f, 0.f, 0.f);
            if (tg >= 0 && tg < T) {
                long row;
                if (GATHER) {
                    int tk = tok[b * T + tg];
                    row = (tk >= 0) ? ((long)b * in_T + tk) : -1;
                } else {
                    row = (long)b * T + tg;
                }
                if (row >= 0) v = *(const float4*)&in[row * CIN + cc + (q << 2)];
            }
            As[((q << 2) + 0) * PITCH + t] = v.x;
            As[((q << 2) + 1) * PITCH + t] = v.y;
            As[((q << 2) + 2) * PITCH + t] = v.z;
            As[((q << 2) + 3) * PITCH + t] = v.w;
        }
        for (int i = tid; i < KS * 256; i += 256) {
            int row = i >> 4, o4 = (i & 15) << 2;
            int k = row >> 4, ci = row & 15;
            *(float4*)&Bs[row * 68 + o4] =
                *(const float4*)&wt[(size_t)(k * CIN + cc + ci) * COUT + o0 + o4];
        }
        __syncthreads();
#pragma unroll 2
        for (int ci = 0; ci < 16; ++ci) {
            float a[8];
            float4 A0 = *(const float4*)&As[ci * PITCH + wt0 + r0];
            float4 A1 = *(const float4*)&As[ci * PITCH + wt0 + r0 + 4];
            a[0] = A0.x; a[1] = A0.y; a[2] = A0.z; a[3] = A0.w;
            a[4] = A1.x; a[5] = A1.y; a[6] = A1.z; a[7] = A1.w;
#pragma unroll
            for (int k = 0; k < KS; ++k) {
                float4 b0 = *(const float4*)&Bs[(k * 16 + ci) * 68 + c0];
                float4 b1 = *(const float4*)&Bs[(k * 16 + ci) * 68 + 32 + c0];
                float bb[8] = {b0.x, b0.y, b0.z, b0.w, b1.x, b1.y, b1.z, b1.w};
#pragma unroll
                for (int i = 0; i < 4; ++i)
#pragma unroll
                    for (int j = 0; j < 8; ++j)
                        acc[i][j] = fmaf(a[i + k], bb[j], acc[i][j]);
            }
        }
        __syncthreads();
    }

    float4 bi0 = *(const float4*)(bias + o0 + c0);
    float4 bi1 = *(const float4*)(bias + o0 + 32 + c0);
    float bb[8] = {bi0.x, bi0.y, bi0.z, bi0.w, bi1.x, bi1.y, bi1.z, bi1.w};
    float sc[8], sh[8];
    if (BN) {
        float4 g0 = *(const float4*)(bng + o0 + c0);
        float4 g1 = *(const float4*)(bng + o0 + 32 + c0);
        float4 t0v = *(const float4*)(bnb + o0 + c0);
        float4 t1v = *(const float4*)(bnb + o0 + 32 + c0);
        float4 m0 = *(const float4*)(bnm + o0 + c0);
        float4 m1 = *(const float4*)(bnm + o0 + 32 + c0);
        float4 v0 = *(const float4*)(bnv + o0 + c0);
        float4 v1 = *(const float4*)(bnv + o0 + 32 + c0);
        float gg[8] = {g0.x, g0.y, g0.z, g0.w, g1.x, g1.y, g1.z, g1.w};
        float tb[8] = {t0v.x, t0v.y, t0v.z, t0v.w, t1v.x, t1v.y, t1v.z, t1v.w};
        float mm[8] = {m0.x, m0.y, m0.z, m0.w, m1.x, m1.y, m1.z, m1.w};
        float vv[8] = {v0.x, v0.y, v0.z, v0.w, v1.x, v1.y, v1.z, v1.w};
#pragma unroll
        for (int j = 0; j < 8; ++j) {
            sc[j] = gg[j] / sqrtf(vv[j] + 1e-5f);
            sh[j] = tb[j] - mm[j] * sc[j];
        }
    }
#pragma unroll
    for (int i = 0; i < 4; ++i) {
        int r = t0 + wt0 + r0 + i;
#pragma unroll
        for (int jh = 0; jh < 2; ++jh) {
            float o4[4];
#pragma unroll
            for (int j = 0; j < 4; ++j) {
                float yv = acc[i][jh * 4 + j] + bb[jh * 4 + j];
                if (RELU) yv = fmaxf(yv, 0.0f);
                if (BN) yv = yv * sc[jh * 4 + j] + sh[jh * 4 + j];
                o4[j] = yv;
            }
            *(float4*)&out[((size_t)b * T + r) * COUT + o0 + jh * 32 + c0] =
                make_float4(o4[0], o4[1], o4[2], o4[3]);
        }
    }
}

// ---------------- bf16 MFMA conv (decoder): TM=256, wave owns 64 t-rows ----------------
template<int CIN, int KS, bool GATHER, bool IN_BF16>
__global__ __launch_bounds__(256) void convmf_kernel(const void* __restrict__ in_,
                                                     const unsigned short* __restrict__ wtb,
                                                     const float* __restrict__ bias,
                                                     const int* __restrict__ tok,
                                                     unsigned short* __restrict__ out,
                                                     int T, int in_T, int COUT)
{
    constexpr int TM = 256;
    constexpr int PAD = (KS - 1) / 2;
    constexpr int TEXT = TM + KS - 1;          // 260
    constexpr int PITCHA = 40;
    __shared__ __align__(16) unsigned short As[TEXT * PITCHA];
    const int tid = threadIdx.x;
    const int lane = tid & 63, wave = tid >> 6;
    const int m = lane & 15, quad = lane >> 4;
    const int b = blockIdx.z;
    const int t0 = blockIdx.x * TM;
    const int o0 = blockIdx.y * 64;
    const int woff = wave * 64;
    f32x4 acc[4][4] = {};

    const float* inf = (const float*)in_;
    const unsigned short* inb = (const unsigned short*)in_;

    for (int cc = 0; cc < CIN; cc += 32) {
        for (int i = tid; i < TEXT * 8; i += 256) {
            int t = i >> 3, ci4 = (i & 7) << 2;
            int tg = t0 - PAD + t;
            long row = -1;
            if (tg >= 0 && tg < T) {
                if (GATHER) {
                    int tk = tok[b * T + tg];
                    if (tk >= 0) row = (long)b * in_T + tk;
                } else {
                    row = (long)b * T + tg;
                }
            }
            unsigned short s4[4] = {0, 0, 0, 0};
            if (row >= 0) {
                if (IN_BF16) {
                    *(uint2*)s4 = *(const uint2*)&inb[row * CIN + cc + ci4];
                } else {
                    float4 v = *(const float4*)&inf[row * CIN + cc + ci4];
                    s4[0] = f2b(v.x); s4[1] = f2b(v.y);
                    s4[2] = f2b(v.z); s4[3] = f2b(v.w);
                }
            }
            *(uint2*)&As[t * PITCHA + ci4] = *(uint2*)s4;
        }
        __syncthreads();
#pragma unroll
        for (int tap = 0; tap < KS; ++tap) {
            bf16x8 a[4];
#pragma unroll
            for (int mt = 0; mt < 4; ++mt)
                a[mt] = *(const bf16x8*)&As[(woff + mt * 16 + m + tap) * PITCHA + quad * 8];
#pragma unroll
            for (int ot = 0; ot < 4; ++ot) {
                bf16x8 bf = *(const bf16x8*)&wtb[((size_t)tap * COUT + o0 + ot * 16 + m) * CIN + cc + quad * 8];
#pragma unroll
                for (int mt = 0; mt < 4; ++mt)
                    acc[mt][ot] = __builtin_amdgcn_mfma_f32_16x16x32_bf16(a[mt], bf, acc[mt][ot], 0, 0, 0);
            }
        }
        __syncthreads();
    }

#pragma unroll
    for (int ot = 0; ot < 4; ++ot) {
        int o = o0 + ot * 16 + m;
        float bi = bias[o];
#pragma unroll
        for (int mt = 0; mt < 4; ++mt)
#pragma unroll
            for (int r = 0; r < 4; ++r) {
                int t = t0 + woff + mt * 16 + quad * 4 + r;
                float yv = fmaxf(acc[mt][ot][r] + bi, 0.0f);
                out[((size_t)b * T + t) * COUT + o] = f2b(yv);
            }
    }
}

// ---------------- duration: log_dur -> dur ----------------
__global__ __launch_bounds__(256) void dur_kernel(const float* __restrict__ h2,
                                                  const float* __restrict__ wo,
                                                  const float* __restrict__ bo,
                                                  int* __restrict__ dur)
{
    __shared__ float red[4];
    const int row = blockIdx.x;
    const int c = threadIdx.x;
    float s = h2[(size_t)row * ND + c] * wo[c];
#pragma unroll
    for (int o = 32; o; o >>= 1) s += __shfl_down(s, o);
    if ((c & 63) == 0) red[c >> 6] = s;
    __syncthreads();
    if (c == 0) {
        float ld = red[0] + red[1] + red[2] + red[3] + bo[0];
        float d = rintf(expf(ld));
        d = fminf(fmaxf(d, 1.0f), 8.0f);
        dur[row] = (int)d;
    }
}

__global__ __launch_bounds__(64) void scan_kernel(const int* __restrict__ dur,
                                                  int* __restrict__ starts,
                                                  int* __restrict__ totals)
{
    const int b = threadIdx.x;
    if (b >= NB) return;
    int acc = 0;
    for (int t = 0; t < NT; ++t) {
        starts[b * NT + t] = acc;
        acc += dur[b * NT + t];
    }
    totals[b] = acc;
}

__global__ __launch_bounds__(256) void tok_kernel(const int* __restrict__ starts,
                                                  const int* __restrict__ totals,
                                                  int* __restrict__ tok)
{
    const int gid = blockIdx.x * 256 + threadIdx.x;
    const int b = gid >> 11, p = gid & (TOUT - 1);
    const int total = totals[b];
    int res = -1;
    if (p < total) {
        const int* st = starts + b * NT;
        int lo = 0, hi = NT - 1;
        while (lo < hi) {
            int mid = (lo + hi + 1) >> 1;
            if (st[mid] <= p) lo = mid; else hi = mid - 1;
        }
        res = lo;
    }
    tok[gid] = res;
}

// ---------------- decoder conv3: bf16 [B,2048,128] -> wav fp32 [B,2048] ----------------
__global__ __launch_bounds__(256) void conv3_kernel(const unsigned short* __restrict__ in,
                                                    const float* __restrict__ w,
                                                    const float* __restrict__ bias,
                                                    float* __restrict__ out)
{
    const int gid = blockIdx.x * 256 + threadIdx.x;
    const int b = gid >> 11, t = gid & (TOUT - 1);
    float acc = bias[0];
#pragma unroll
    for (int k = 0; k < 5; ++k) {
        int t2 = t + k - 2;
        if (t2 < 0 || t2 >= TOUT) continue;
        const unsigned short* row = in + ((size_t)b * TOUT + t2) * 128;
        for (int c = 0; c < 128; ++c) acc = fmaf(b2f(row[c]), w[c * 5 + k], acc);
    }
    out[gid] = acc;
}

// ---------------- orchestration ----------------
extern "C" void kernel_launch(void* const* d_in, const int* in_sizes, int n_in,
                              void* d_out, int out_size, void* d_ws, size_t ws_size,
                              hipStream_t stream)
{
    const int*   text    = (const int*)d_in[0];
    const float* emotion = (const float*)d_in[1];
    const float* emb     = (const float*)d_in[2];
    const float* Wqkv    = (const float*)d_in[3];
    const float* bqkv    = (const float*)d_in[4];
    const float* Wo      = (const float*)d_in[5];
    const float* bo      = (const float*)d_in[6];
    const float* W1      = (const float*)d_in[7];
    const float* b1      = (const float*)d_in[8];
    const float* W2      = (const float*)d_in[9];
    const float* b2      = (const float*)d_in[10];
    const float* ln1g    = (const float*)d_in[11];
    const float* ln1b    = (const float*)d_in[12];
    const float* ln2g    = (const float*)d_in[13];
    const float* ln2b    = (const float*)d_in[14];
    const float* We1     = (const float*)d_in[15];
    const float* be1     = (const float*)d_in[16];
    const float* We2     = (const float*)d_in[17];
    const float* be2     = (const float*)d_in[18];
    const float* dp_w1   = (const float*)d_in[19];
    const float* dp_b1   = (const float*)d_in[20];
    const float* dp_g1   = (const float*)d_in[21];
    const float* dp_bt1  = (const float*)d_in[22];
    const float* dp_m1   = (const float*)d_in[23];
    const float* dp_v1   = (const float*)d_in[24];
    const float* dp_w2   = (const float*)d_in[25];
    const float* dp_b2   = (const float*)d_in[26];
    const float* dp_g2   = (const float*)d_in[27];
    const float* dp_bt2  = (const float*)d_in[28];
    const float* dp_m2   = (const float*)d_in[29];
    const float* dp_v2   = (const float*)d_in[30];
    const float* dp_wo   = (const float*)d_in[31];
    const float* dp_bo   = (const float*)d_in[32];
    const float* dec_w1  = (const float*)d_in[33];
    const float* dec_b1  = (const float*)d_in[34];
    const float* dec_w2  = (const float*)d_in[35];
    const float* dec_b2  = (const float*)d_in[36];
    const float* dec_w3  = (const float*)d_in[37];
    const float* dec_b3  = (const float*)d_in[38];

    float* ws   = (float*)d_ws;
    float* x    = ws + OFF_X;
    unsigned short* ffhB = (unsigned short*)(ws + OFF_FFH);
    unsigned short* Wbt  = (unsigned short*)(ws + OFF_WBT);
    float* wtdp1 = ws + OFF_CWT;
    float* wtdp2 = wtdp1 + 196608;
    unsigned short* wtb1 = (unsigned short*)(wtdp2 + 196608);
    unsigned short* wtb2 = wtb1 + 327680;
    unsigned short* qkvB = (unsigned short*)(ws + OFF_QKV);   // 12,582,912 shorts
    unsigned short* vtb  = qkvB + 12582912;                   //  4,194,304 shorts
    float* attb = ws + OFF_ATTN;
    float* prjb = ws + OFF_PROJ;
    float* ebuf = ws + OFF_E;
    unsigned short* attbB = (unsigned short*)attb;
    unsigned short* d1b  = ffhB;
    unsigned short* d2b  = (unsigned short*)attb;
    int*   ip     = (int*)(ws + OFF_INT);
    int*   durb   = ip;
    int*   startb = ip + 16384;
    int*   totb   = ip + 32768;
    int*   tokb   = ip + 32832;

    const int M = NB * NT;   // 16384

    embed_kernel<<<M, 256, 0, stream>>>(text, emb, x);

    wq_kernel<<<dim3(24, 8, 6), 256, 0, stream>>>(Wqkv, Wbt + 0,      256, 768,  196608, 786432);
    wq_kernel<<<dim3(8,  8, 6), 256, 0, stream>>>(Wo,   Wbt + 196608, 256, 256,  65536,  786432);
    wq_kernel<<<dim3(32, 8, 6), 256, 0, stream>>>(W1,   Wbt + 262144, 256, 1024, 262144, 786432);
    wq_kernel<<<dim3(8, 32, 6), 256, 0, stream>>>(W2,   Wbt + 524288, 1024, 256, 262144, 786432);

    for (int l = 0; l < NLAYER; ++l) {
        const unsigned short* WQ  = Wbt + (size_t)l * 786432;
        const unsigned short* WO  = WQ + 196608;
        const unsigned short* WF1 = WQ + 262144;
        const unsigned short* WF2 = WQ + 524288;
        gemmbf_kernel<128, false, false, true><<<dim3(6, 128), 256, 0, stream>>>(
            x, WQ, bqkv + l * 768, qkvB, M, 768, 256);
        vtrans_kernel<<<dim3(NT / 64, NH, NB), 256, 0, stream>>>(qkvB, vtb);
        attn3_kernel<<<dim3(NT / 128, NH, NB), 256, 0, stream>>>(qkvB, vtb, attbB);
        gemmbf_kernel<64, false, true, false><<<dim3(4, 128), 256, 0, stream>>>(
            attbB, WO, bo + l * 256, prjb, M, 256, 256);
        add_ln_kernel<<<M / 4, 256, 0, stream>>>(x, prjb, ln1g + l * ND, ln1b + l * ND);
        gemmbf_kernel<128, true, false, true><<<dim3(8, 128), 256, 0, stream>>>(
            x, WF1, b1 + l * 1024, ffhB, M, 1024, 256);
        gemmbf_kernel<64, false, true, false><<<dim3(4, 128), 256, 0, stream>>>(
            ffhB, WF2, b2 + l * 256, prjb, M, 256, 1024);
        add_ln_kernel<<<M / 4, 256, 0, stream>>>(x, prjb, ln2g + l * ND, ln2b + l * ND);
    }

    emotion_kernel<<<NB, 256, 0, stream>>>(emotion, We1, be1, We2, be2, ebuf);
    addfuse_kernel<<<M, 256, 0, stream>>>(x, ebuf);

    wtrans_kernel<<<(256 * 256 * 3 + 255) / 256, 256, 0, stream>>>(dp_w1, wtdp1, 256, 256, 3);
    wtrans_kernel<<<(256 * 256 * 3 + 255) / 256, 256, 0, stream>>>(dp_w2, wtdp2, 256, 256, 3);
    wtransb_kernel<<<(256 * 256 * 5 + 255) / 256, 256, 0, stream>>>(dec_w1, wtb1, 256, 256, 5);
    wtransb_kernel<<<(128 * 256 * 5 + 255) / 256, 256, 0, stream>>>(dec_w2, wtb2, 256, 128, 5);

    convg_kernel<256, 3, true, true, false><<<dim3(NT / 128, 4, NB), 256, 0, stream>>>(
        x, wtdp1, dp_b1, dp_g1, dp_bt1, dp_m1, dp_v1, nullptr, attb, NT, NT, 256);
    convg_kernel<256, 3, true, true, false><<<dim3(NT / 128, 4, NB), 256, 0, stream>>>(
        attb, wtdp2, dp_b2, dp_g2, dp_bt2, dp_m2, dp_v2, nullptr, prjb, NT, NT, 256);
    dur_kernel<<<M, 256, 0, stream>>>(prjb, dp_wo, dp_bo, durb);
    scan_kernel<<<1, 64, 0, stream>>>(durb, startb, totb);
    tok_kernel<<<NB * TOUT / 256, 256, 0, stream>>>(startb, totb, tokb);

    convmf_kernel<256, 5, true, false><<<dim3(TOUT / 256, 4, NB), 256, 0, stream>>>(
        x, wtb1, dec_b1, tokb, d1b, TOUT, NT, 256);
    convmf_kernel<256, 5, false, true><<<dim3(TOUT / 256, 2, NB), 256, 0, stream>>>(
        d1b, wtb2, dec_b2, nullptr, d2b, TOUT, TOUT, 128);
    conv3_kernel<<<NB * TOUT / 256, 256, 0, stream>>>(d2b, dec_w3, dec_b3, (float*)d_out);
}

// Round 8
// 1619.053 us; speedup vs baseline: 3.4191x; 1.0429x over previous
//
#include <hip/hip_runtime.h>
#include <math.h>

#define NB 32
#define NT 512
#define ND 256
#define NH 4
#define NLAYER 6
#define TOUT 2048

typedef __attribute__((ext_vector_type(8))) short bf16x8;
typedef __attribute__((ext_vector_type(4))) float f32x4;
typedef __attribute__((ext_vector_type(16))) float f32x16;

static __device__ __forceinline__ unsigned short f2b(float f) {
    union { float f; unsigned int u; } x; x.f = f;
    unsigned int u = x.u;
    return (unsigned short)((u + 0x7FFFu + ((u >> 16) & 1u)) >> 16);
}
static __device__ __forceinline__ float b2f(unsigned short s) {
    union { unsigned int u; float f; } x; x.u = ((unsigned int)s) << 16;
    return x.f;
}

// ---------------- workspace layout (float offsets) ----------------
#define OFF_X    0ull          // 4,194,304   x fp32 [B,T,256] (residual; dur-critical)
#define OFF_FFH  4194304ull    // 8,388,608   ffh bf16 [16384,1024]; later d1b bf16 [B,2048,256]
#define OFF_WBT  12582912ull   // 2,359,296   transformer weights bf16 [N][K]
#define OFF_CWT  14942208ull   // 638,976     conv weights (dp fp32 + dec bf16)
#define OFF_QKV  20971520ull   // qkv bf16 + vt bf16; later reg bf16 [B,2048,256]
#define OFF_ATTN 33554432ull   // attn out bf16 / dp h1 fp32; later d2b bf16
#define OFF_PROJ 37748736ull   // proj / ff2 out fp32 / dp h2
#define OFF_E    41943040ull   // emotion e
#define OFF_INT  41951232ull   // ints: dur, starts, totals, tok

// ---------------- embedding + positional encoding ----------------
__global__ __launch_bounds__(256) void embed_kernel(const int* __restrict__ text,
                                                    const float* __restrict__ emb,
                                                    float* __restrict__ x)
{
    const int row = blockIdx.x;
    const int d = threadIdx.x;
    const int t = row & (NT - 1);
    const int id = text[row];
    const int j2 = (d >> 1) * 2;
    const float c = -9.210340371976184f / 256.0f;
    float freq = expf((float)j2 * c);
    float ang = (float)t * freq;
    float pe = (d & 1) ? cosf(ang) : sinf(ang);
    x[(size_t)row * ND + d] = emb[(size_t)id * ND + d] + pe;
}

// ---------------- weight transpose: fp32 [K,N] -> bf16 [N,K], batched over layers ----------------
__global__ __launch_bounds__(256) void wq_kernel(const float* __restrict__ W,
                                                 unsigned short* __restrict__ out,
                                                 int K, int N, int inLS, int outLS)
{
    __shared__ float tile[32][33];
    const float* Wl = W + (size_t)blockIdx.z * inLS;
    unsigned short* ol = out + (size_t)blockIdx.z * outLS;
    const int n0 = blockIdx.x * 32, k0 = blockIdx.y * 32;
    const int tx = threadIdx.x & 31, ty = threadIdx.x >> 5;
#pragma unroll
    for (int j = 0; j < 4; ++j)
        tile[ty + j * 8][tx] = Wl[(size_t)(k0 + ty + j * 8) * N + n0 + tx];
    __syncthreads();
#pragma unroll
    for (int j = 0; j < 4; ++j)
        ol[(size_t)(n0 + ty + j * 8) * K + k0 + tx] = f2b(tile[tx][ty + j * 8]);
}

// ---------------- bf16 MFMA GEMM: C[M,N] = A[M,K] @ B[K,N] + bias ----------------
template<int NTILE, bool RELU, bool ABF16, bool CBF16>
__global__ __launch_bounds__(256) void gemmbf_kernel(const void* __restrict__ A_,
                                                     const unsigned short* __restrict__ Bt,
                                                     const float* __restrict__ bias,
                                                     void* __restrict__ C_,
                                                     int M, int N, int K)
{
    constexpr int MT = (NTILE == 128) ? 2 : 1;
    __shared__ __align__(16) unsigned short Asb[128 * 32];
    __shared__ __align__(16) unsigned short Bsb[NTILE * 32];
    const int tid = threadIdx.x;
    const int lane = tid & 63, wave = tid >> 6;
    const int ln = lane & 31, hi = lane >> 5;
    const int row0 = blockIdx.y * 128, col0 = blockIdx.x * NTILE;
    const int mOff = (NTILE == 128) ? (wave >> 1) * 64 : wave * 32;
    const int nOff = (NTILE == 128) ? (wave & 1) * 64 : 0;
    const float* Af = (const float*)A_;
    const unsigned short* Ab = (const unsigned short*)A_;
    float* Cf = (float*)C_;
    unsigned short* Cb = (unsigned short*)C_;
    f32x16 acc[MT][2] = {};

    for (int k0 = 0; k0 < K; k0 += 32) {
#pragma unroll
        for (int it = 0; it < 2; ++it) {
            int u = it * 256 + tid;
            int m = u >> 2, blk = u & 3;
            unsigned short s8[8];
            if (ABF16) {
                *(uint4*)s8 = *(const uint4*)&Ab[(size_t)(row0 + m) * K + k0 + blk * 8];
            } else {
                float4 v0 = *(const float4*)&Af[(size_t)(row0 + m) * K + k0 + blk * 8];
                float4 v1 = *(const float4*)&Af[(size_t)(row0 + m) * K + k0 + blk * 8 + 4];
                s8[0] = f2b(v0.x); s8[1] = f2b(v0.y); s8[2] = f2b(v0.z); s8[3] = f2b(v0.w);
                s8[4] = f2b(v1.x); s8[5] = f2b(v1.y); s8[6] = f2b(v1.z); s8[7] = f2b(v1.w);
            }
            *(uint4*)&Asb[m * 32 + ((blk ^ (m & 3)) << 3)] = *(uint4*)s8;
        }
#pragma unroll
        for (int it = 0; it < NTILE / 64; ++it) {
            int u = it * 256 + tid;
            int n = u >> 2, blk = u & 3;
            *(uint4*)&Bsb[n * 32 + ((blk ^ (n & 3)) << 3)] =
                *(const uint4*)&Bt[(size_t)(col0 + n) * K + k0 + blk * 8];
        }
        __syncthreads();
#pragma unroll
        for (int kh = 0; kh < 2; ++kh) {
            const int kb = kh * 2 + hi;
            bf16x8 af[MT], bfr[2];
#pragma unroll
            for (int mt = 0; mt < MT; ++mt) {
                int r = mOff + mt * 32 + ln;
                af[mt] = *(const bf16x8*)&Asb[r * 32 + ((kb ^ (r & 3)) << 3)];
            }
#pragma unroll
            for (int nt = 0; nt < 2; ++nt) {
                int r = nOff + nt * 32 + ln;
                bfr[nt] = *(const bf16x8*)&Bsb[r * 32 + ((kb ^ (r & 3)) << 3)];
            }
#pragma unroll
            for (int mt = 0; mt < MT; ++mt)
#pragma unroll
                for (int nt = 0; nt < 2; ++nt)
                    acc[mt][nt] = __builtin_amdgcn_mfma_f32_32x32x16_bf16(
                        af[mt], bfr[nt], acc[mt][nt], 0, 0, 0);
        }
        __syncthreads();
    }
#pragma unroll
    for (int mt = 0; mt < MT; ++mt)
#pragma unroll
        for (int nt = 0; nt < 2; ++nt) {
            int col = col0 + nOff + nt * 32 + ln;
            float bi = bias[col];
#pragma unroll
            for (int g = 0; g < 4; ++g)
#pragma unroll
                for (int r4 = 0; r4 < 4; ++r4) {
                    int row = row0 + mOff + mt * 32 + hi * 4 + g * 8 + r4;
                    float v = acc[mt][nt][g * 4 + r4] + bi;
                    if (RELU) v = fmaxf(v, 0.f);
                    if (CBF16) Cb[(size_t)row * N + col] = f2b(v);
                    else       Cf[(size_t)row * N + col] = v;
                }
        }
}

// ---------------- V transpose per layer: qkv bf16 -> vt[b,h,d,t] bf16 ----------------
__global__ __launch_bounds__(256) void vtrans_kernel(const unsigned short* __restrict__ qkv,
                                                     unsigned short* __restrict__ vt)
{
    __shared__ unsigned short tile[64][65];
    const int t0 = blockIdx.x * 64, h = blockIdx.y, b = blockIdx.z;
    const int tid = threadIdx.x;
#pragma unroll
    for (int it = 0; it < 2; ++it) {
        int u = it * 256 + tid;
        int t = u >> 3, d8 = (u & 7) * 8;
        bf16x8 v = *(const bf16x8*)&qkv[((size_t)(b * NT) + t0 + t) * 768 + 512 + h * 64 + d8];
#pragma unroll
        for (int j = 0; j < 8; ++j) tile[t][d8 + j] = (unsigned short)v[j];
    }
    __syncthreads();
#pragma unroll
    for (int it = 0; it < 2; ++it) {
        int u = it * 256 + tid;
        int d = u >> 3, t8 = (u & 7) * 8;
        unsigned short s8[8];
#pragma unroll
        for (int j = 0; j < 8; ++j) s8[j] = tile[t8 + j][d];
        *(uint4*)&vt[((size_t)(b * NH + h) * 64 + d) * NT + t0 + t8] = *(uint4*)s8;
    }
}

// ---------------- attention v3: bf16 MFMA flash, computes O^T ----------------
__global__ __launch_bounds__(256, 2) void attn3_kernel(const unsigned short* __restrict__ qkv,
                                                       const unsigned short* __restrict__ vt,
                                                       unsigned short* __restrict__ out)
{
    __shared__ __align__(16) unsigned short sP[4][32 * 64];
    const int tid = threadIdx.x;
    const int lane = tid & 63, wave = tid >> 6;
    const int ln = lane & 31, hi = lane >> 5;
    const int h = blockIdx.y, b = blockIdx.z;
    const int q0 = blockIdx.x * 128 + wave * 32;
    const size_t base = (size_t)b * NT * 768;
    const int qoff = h * 64;
    const unsigned short* vbh = vt + (size_t)(b * NH + h) * 64 * NT;

    bf16x8 qf[4];
#pragma unroll
    for (int s = 0; s < 4; ++s)
        qf[s] = *(const bf16x8*)&qkv[base + (size_t)(q0 + ln) * 768 + qoff + s * 16 + hi * 8];

    float mrow[16], lrow[16];
#pragma unroll
    for (int i = 0; i < 16; ++i) { mrow[i] = -1e30f; lrow[i] = 0.f; }
    f32x16 oacc[2] = {};
    const float sc = 0.18033688011112042f;   // 0.125 * log2(e)
    const int i0 = (ln & 3) | (((ln >> 3) & 3) << 2);
    const bool own = (((ln >> 2) & 1) == hi);
    unsigned short* Pw = &sP[wave][0];

    for (int ch = 0; ch < 8; ++ch) {
        const int s0 = ch * 64;
        f32x16 sacc[2] = {};
#pragma unroll
        for (int ct = 0; ct < 2; ++ct)
#pragma unroll
            for (int s = 0; s < 4; ++s) {
                bf16x8 kf = *(const bf16x8*)&qkv[base + (size_t)(s0 + ct * 32 + ln) * 768
                                                 + 256 + qoff + s * 16 + hi * 8];
                sacc[ct] = __builtin_amdgcn_mfma_f32_32x32x16_bf16(qf[s], kf, sacc[ct], 0, 0, 0);
            }
        float alpha[16];
#pragma unroll
        for (int i = 0; i < 16; ++i) {
            float s20 = sacc[0][i] * sc, s21 = sacc[1][i] * sc;
            float mx = fmaxf(s20, s21);
#pragma unroll
            for (int o = 1; o < 32; o <<= 1) mx = fmaxf(mx, __shfl_xor(mx, o));
            float mn = fmaxf(mrow[i], mx);
            alpha[i] = exp2f(mrow[i] - mn);
            mrow[i] = mn;
            float p0 = exp2f(s20 - mn);
            float p1 = exp2f(s21 - mn);
            sacc[0][i] = p0; sacc[1][i] = p1;
            float rs = p0 + p1;
#pragma unroll
            for (int o = 1; o < 32; o <<= 1) rs += __shfl_xor(rs, o);
            lrow[i] = lrow[i] * alpha[i] + rs;
        }
#pragma unroll
        for (int ct = 0; ct < 2; ++ct) {
            int kb = ct * 4 + (ln >> 3), k7 = ln & 7;
#pragma unroll
            for (int i = 0; i < 16; ++i) {
                int q = (i & 3) + 8 * (i >> 2) + 4 * hi;
                Pw[q * 64 + (((kb ^ (q & 7)) << 3) | k7)] = f2b(sacc[ct][i]);
            }
        }
        __syncthreads();
        {
            float av = alpha[i0];
            float ao = __shfl_xor(av, 32);
            float aq = own ? av : ao;
#pragma unroll
            for (int ct = 0; ct < 2; ++ct)
#pragma unroll
                for (int i = 0; i < 16; ++i)
                    oacc[ct][i] *= aq;
        }
#pragma unroll
        for (int s = 0; s < 4; ++s) {
            bf16x8 pf = *(const bf16x8*)&Pw[ln * 64 + (((s * 2 + hi) ^ (ln & 7)) << 3)];
#pragma unroll
            for (int ct = 0; ct < 2; ++ct) {
                bf16x8 vf = *(const bf16x8*)&vbh[(size_t)(ct * 32 + ln) * NT + s0 + s * 16 + hi * 8];
                oacc[ct] = __builtin_amdgcn_mfma_f32_32x32x16_bf16(vf, pf, oacc[ct], 0, 0, 0);
            }
        }
        __syncthreads();
    }
    float lv = lrow[i0];
    float lo = __shfl_xor(lv, 32);
    float linv = 1.0f / (own ? lv : lo);
    const int q = q0 + ln;
#pragma unroll
    for (int ct = 0; ct < 2; ++ct)
#pragma unroll
        for (int i = 0; i < 16; ++i) {
            int d = ct * 32 + (i & 3) + 8 * (i >> 2) + 4 * hi;
            out[(size_t)(b * NT + q) * ND + qoff + d] = f2b(oacc[ct][i] * linv);
        }
}

// ---------------- x = LayerNorm(x + y), wave-per-row ----------------
__global__ __launch_bounds__(256) void add_ln_kernel(float* __restrict__ x,
                                                     const float* __restrict__ y,
                                                     const float* __restrict__ g,
                                                     const float* __restrict__ bta)
{
    const int w = threadIdx.x >> 6, lane = threadIdx.x & 63;
    const size_t row = (size_t)blockIdx.x * 4 + w;
    const int c4 = lane * 4;
    float4 xv = *(const float4*)&x[row * ND + c4];
    float4 yv = *(const float4*)&y[row * ND + c4];
    float4 v = make_float4(xv.x + yv.x, xv.y + yv.y, xv.z + yv.z, xv.w + yv.w);
    float s = v.x + v.y + v.z + v.w;
#pragma unroll
    for (int o = 1; o < 64; o <<= 1) s += __shfl_xor(s, o);
    float m = s * (1.0f / 256.0f);
    float4 dv = make_float4(v.x - m, v.y - m, v.z - m, v.w - m);
    float s2 = dv.x * dv.x + dv.y * dv.y + dv.z * dv.z + dv.w * dv.w;
#pragma unroll
    for (int o = 1; o < 64; o <<= 1) s2 += __shfl_xor(s2, o);
    float r = 1.0f / sqrtf(s2 * (1.0f / 256.0f) + 1e-5f);
    float4 gv = *(const float4*)&g[c4];
    float4 bv = *(const float4*)&bta[c4];
    float4 o4 = make_float4(dv.x * r * gv.x + bv.x, dv.y * r * gv.y + bv.y,
                            dv.z * r * gv.z + bv.z, dv.w * r * gv.w + bv.w);
    *(float4*)&x[row * ND + c4] = o4;
}

// ---------------- emotion MLP ----------------
__global__ __launch_bounds__(256) void emotion_kernel(const float* __restrict__ emo,
                                                      const float* __restrict__ We1,
                                                      const float* __restrict__ be1,
                                                      const float* __restrict__ We2,
                                                      const float* __restrict__ be2,
                                                      float* __restrict__ e)
{
    const int b = blockIdx.x, d = threadIdx.x;
    const float em = emo[b];
    float acc = be2[d];
    for (int j = 0; j < 64; ++j) {
        float h = fmaxf(em * We1[j] + be1[j], 0.0f);
        acc = fmaf(h, We2[j * ND + d], acc);
    }
    e[b * ND + d] = acc;
}

__global__ __launch_bounds__(256) void addfuse_kernel(float* __restrict__ x,
                                                      const float* __restrict__ e)
{
    const int row = blockIdx.x;
    const int d = threadIdx.x;
    x[(size_t)row * ND + d] += e[(row >> 9) * ND + d];
}

// ---------------- conv weight transposes ----------------
__global__ __launch_bounds__(256) void wtrans_kernel(const float* __restrict__ w,
                                                     float* __restrict__ wt,
                                                     int CIN, int COUT, int KS)
{
    int gid = blockIdx.x * 256 + threadIdx.x;
    int total = CIN * COUT * KS;
    if (gid >= total) return;
    int o = gid % COUT;
    int r = gid / COUT;
    int c = r % CIN;
    int k = r / CIN;
    wt[gid] = w[(o * CIN + c) * KS + k];
}

__global__ __launch_bounds__(256) void wtransb_kernel(const float* __restrict__ w,
                                                      unsigned short* __restrict__ wtb,
                                                      int CIN, int COUT, int KS)
{
    int gid = blockIdx.x * 256 + threadIdx.x;
    int total = CIN * COUT * KS;
    if (gid >= total) return;
    int c = gid % CIN;
    int r = gid / CIN;
    int o = r % COUT;
    int k = r / COUT;
    wtb[gid] = f2b(w[(o * CIN + c) * KS + k]);
}

// ---------------- fp32 GEMM-style conv (duration predictor; must stay fp32) ----------------
template<int CIN, int KS, bool RELU, bool BN, bool GATHER>
__global__ __launch_bounds__(256, 4) void convg_kernel(const float* __restrict__ in,
                                                       const float* __restrict__ wt,
                                                       const float* __restrict__ bias,
                                                       const float* __restrict__ bng,
                                                       const float* __restrict__ bnb,
                                                       const float* __restrict__ bnm,
                                                       const float* __restrict__ bnv,
                                                       const int* __restrict__ tok,
                                                       float* __restrict__ out,
                                                       int T, int in_T, int COUT)
{
    constexpr int TM = 128;
    constexpr int PAD = (KS - 1) / 2;
    constexpr int TEXT = TM + KS - 1;
    constexpr int PITCH = (TEXT + 3) & ~3;
    __shared__ __align__(16) float As[16 * PITCH];
    __shared__ __align__(16) float Bs[16 * KS * 68];
    const int tid = threadIdx.x;
    const int lane = tid & 63, wave = tid >> 6;
    const int b = blockIdx.z;
    const int t0 = blockIdx.x * TM;
    const int o0 = blockIdx.y * 64;
    const int wt0 = wave * 32;
    const int r0 = (lane >> 3) << 2;
    const int c0 = (lane & 7) << 2;
    float acc[4][8] = {};

    for (int cc = 0; cc < CIN; cc += 16) {
        for (int i = tid; i < TEXT * 4; i += 256) {
            int t = i >> 2, q = i & 3;
            int tg = t0 - PAD + t;
            float4 v = make_float4(0.f, 0.f, 0.f, 0.f);
            if (tg >= 0 && tg < T) {
                long row;
                if (GATHER) {
                    int tk = tok[b * T + tg];
                    row = (tk >= 0) ? ((long)b * in_T + tk) : -1;
                } else {
                    row = (long)b * T + tg;
                }
                if (row >= 0) v = *(const float4*)&in[row * CIN + cc + (q << 2)];
            }
            As[((q << 2) + 0) * PITCH + t] = v.x;
            As[((q << 2) + 1) * PITCH + t] = v.y;
            As[((q << 2) + 2) * PITCH + t] = v.z;
            As[((q << 2) + 3) * PITCH + t] = v.w;
        }
        for (int i = tid; i < KS * 256; i += 256) {
            int row = i >> 4, o4 = (i & 15) << 2;
            int k = row >> 4, ci = row & 15;
            *(float4*)&Bs[row * 68 + o4] =
                *(const float4*)&wt[(size_t)(k * CIN + cc + ci) * COUT + o0 + o4];
        }
        __syncthreads();
#pragma unroll 2
        for (int ci = 0; ci < 16; ++ci) {
            float a[8];
            float4 A0 = *(const float4*)&As[ci * PITCH + wt0 + r0];
            float4 A1 = *(const float4*)&As[ci * PITCH + wt0 + r0 + 4];
            a[0] = A0.x; a[1] = A0.y; a[2] = A0.z; a[3] = A0.w;
            a[4] = A1.x; a[5] = A1.y; a[6] = A1.z; a[7] = A1.w;
#pragma unroll
            for (int k = 0; k < KS; ++k) {
                float4 b0 = *(const float4*)&Bs[(k * 16 + ci) * 68 + c0];
                float4 b1 = *(const float4*)&Bs[(k * 16 + ci) * 68 + 32 + c0];
                float bb[8] = {b0.x, b0.y, b0.z, b0.w, b1.x, b1.y, b1.z, b1.w};
#pragma unroll
                for (int i = 0; i < 4; ++i)
#pragma unroll
                    for (int j = 0; j < 8; ++j)
                        acc[i][j] = fmaf(a[i + k], bb[j], acc[i][j]);
            }
        }
        __syncthreads();
    }

    float4 bi0 = *(const float4*)(bias + o0 + c0);
    float4 bi1 = *(const float4*)(bias + o0 + 32 + c0);
    float bb[8] = {bi0.x, bi0.y, bi0.z, bi0.w, bi1.x, bi1.y, bi1.z, bi1.w};
    float sc[8], sh[8];
    if (BN) {
        float4 g0 = *(const float4*)(bng + o0 + c0);
        float4 g1 = *(const float4*)(bng + o0 + 32 + c0);
        float4 t0v = *(const float4*)(bnb + o0 + c0);
        float4 t1v = *(const float4*)(bnb + o0 + 32 + c0);
        float4 m0 = *(const float4*)(bnm + o0 + c0);
        float4 m1 = *(const float4*)(bnm + o0 + 32 + c0);
        float4 v0 = *(const float4*)(bnv + o0 + c0);
        float4 v1 = *(const float4*)(bnv + o0 + 32 + c0);
        float gg[8] = {g0.x, g0.y, g0.z, g0.w, g1.x, g1.y, g1.z, g1.w};
        float tb[8] = {t0v.x, t0v.y, t0v.z, t0v.w, t1v.x, t1v.y, t1v.z, t1v.w};
        float mm[8] = {m0.x, m0.y, m0.z, m0.w, m1.x, m1.y, m1.z, m1.w};
        float vv[8] = {v0.x, v0.y, v0.z, v0.w, v1.x, v1.y, v1.z, v1.w};
#pragma unroll
        for (int j = 0; j < 8; ++j) {
            sc[j] = gg[j] / sqrtf(vv[j] + 1e-5f);
            sh[j] = tb[j] - mm[j] * sc[j];
        }
    }
#pragma unroll
    for (int i = 0; i < 4; ++i) {
        int r = t0 + wt0 + r0 + i;
#pragma unroll
        for (int jh = 0; jh < 2; ++jh) {
            float o4[4];
#pragma unroll
            for (int j = 0; j < 4; ++j) {
                float yv = acc[i][jh * 4 + j] + bb[jh * 4 + j];
                if (RELU) yv = fmaxf(yv, 0.0f);
                if (BN) yv = yv * sc[jh * 4 + j] + sh[jh * 4 + j];
                o4[j] = yv;
            }
            *(float4*)&out[((size_t)b * T + r) * COUT + o0 + jh * 32 + c0] =
                make_float4(o4[0], o4[1], o4[2], o4[3]);
        }
    }
}

// ---------------- regulated-sequence materialization: reg[b,p,c] = bf16(x[tok]) ----------------
__global__ __launch_bounds__(256) void reg_kernel(const float* __restrict__ x,
                                                  const int* __restrict__ tok,
                                                  unsigned short* __restrict__ reg)
{
    const int wave = threadIdx.x >> 6, lane = threadIdx.x & 63;
    const int row = blockIdx.x * 4 + wave;        // 0..65535 = b*2048+p
    const int tk = tok[row];
    const int b = row >> 11;
    const int c4 = lane * 4;
    unsigned short s4[4] = {0, 0, 0, 0};
    if (tk >= 0) {
        float4 v = *(const float4*)&x[((size_t)(b * NT) + tk) * ND + c4];
        s4[0] = f2b(v.x); s4[1] = f2b(v.y); s4[2] = f2b(v.z); s4[3] = f2b(v.w);
    }
    *(uint2*)&reg[(size_t)row * ND + c4] = *(uint2*)s4;
}

// ---------------- decoder conv v2: bf16 MFMA on gemmbf skeleton, B in LDS ----------------
// in bf16 [B,T,CIN] contiguous; weights wtb[k][o][c]; tile 128t x 64o; BK=32.
template<int CIN, int KS, bool RELU>
__global__ __launch_bounds__(256) void convmf2_kernel(const unsigned short* __restrict__ in,
                                                      const unsigned short* __restrict__ wtb,
                                                      const float* __restrict__ bias,
                                                      unsigned short* __restrict__ out,
                                                      int T, int COUT)
{
    constexpr int PAD = (KS - 1) / 2;
    constexpr int TEXT = 128 + KS - 1;               // 132
    __shared__ __align__(16) unsigned short Asb[TEXT * 32];
    __shared__ __align__(16) unsigned short Bsb[KS * 64 * 32];
    const int tid = threadIdx.x;
    const int lane = tid & 63, wave = tid >> 6;
    const int ln = lane & 31, hi = lane >> 5;
    const int b = blockIdx.z;
    const int t0 = blockIdx.x * 128;
    const int o0 = blockIdx.y * 64;
    const int mOff = wave * 32;
    f32x16 acc[2] = {};

    for (int cc = 0; cc < CIN; cc += 32) {
        // stage A: TEXT rows x 32 shorts, xor-swizzled 16B blocks
        for (int u = tid; u < TEXT * 4; u += 256) {
            int t = u >> 2, blk = u & 3;
            int tg = t0 - PAD + t;
            uint4 v = make_uint4(0, 0, 0, 0);
            if (tg >= 0 && tg < T)
                v = *(const uint4*)&in[((size_t)(b * T) + tg) * CIN + cc + blk * 8];
            *(uint4*)&Asb[t * 32 + ((blk ^ (t & 3)) << 3)] = v;
        }
        // stage B: KS*64 rows x 32 shorts from wtb[k][o][c] (rows contiguous in c)
        for (int u = tid; u < KS * 256; u += 256) {
            int row = u >> 2, blk = u & 3;    // row = k*64 + o
            int k = row >> 6, o = row & 63;
            *(uint4*)&Bsb[row * 32 + ((blk ^ (row & 3)) << 3)] =
                *(const uint4*)&wtb[((size_t)k * COUT + o0 + o) * CIN + cc + blk * 8];
        }
        __syncthreads();
#pragma unroll
        for (int kh = 0; kh < 2; ++kh) {
            const int kb = kh * 2 + hi;
            bf16x8 af[KS];
#pragma unroll
            for (int tap = 0; tap < KS; ++tap) {
                int r = mOff + ln + tap;
                af[tap] = *(const bf16x8*)&Asb[r * 32 + ((kb ^ (r & 3)) << 3)];
            }
#pragma unroll
            for (int nt = 0; nt < 2; ++nt) {
                int rb = nt * 32 + ln;
#pragma unroll
                for (int tap = 0; tap < KS; ++tap) {
                    bf16x8 bfr = *(const bf16x8*)&Bsb[(tap * 64 + rb) * 32 + ((kb ^ (rb & 3)) << 3)];
                    acc[nt] = __builtin_amdgcn_mfma_f32_32x32x16_bf16(af[tap], bfr, acc[nt], 0, 0, 0);
                }
            }
        }
        __syncthreads();
    }
    // epilogue (gemmbf layout): row = mOff + hi*4 + g*8 + r4, col = nt*32 + ln
#pragma unroll
    for (int nt = 0; nt < 2; ++nt) {
        int col = o0 + nt * 32 + ln;
        float bi = bias[col];
#pragma unroll
        for (int g = 0; g < 4; ++g)
#pragma unroll
            for (int r4 = 0; r4 < 4; ++r4) {
                int row = t0 + mOff + hi * 4 + g * 8 + r4;
                float v = acc[nt][g * 4 + r4] + bi;
                if (RELU) v = fmaxf(v, 0.f);
                out[((size_t)(b * T) + row) * COUT + col] = f2b(v);
            }
    }
}

// ---------------- duration: wave-per-row dot -> dur ----------------
__global__ __launch_bounds__(256) void dur_kernel(const float* __restrict__ h2,
                                                  const float* __restrict__ wo,
                                                  const float* __restrict__ bo,
                                                  int* __restrict__ dur)
{
    const int wave = threadIdx.x >> 6, lane = threadIdx.x & 63;
    const int row = blockIdx.x * 4 + wave;
    const int c4 = lane * 4;
    float4 h = *(const float4*)&h2[(size_t)row * ND + c4];
    float4 w4 = *(const float4*)&wo[c4];
    float s = h.x * w4.x + h.y * w4.y + h.z * w4.z + h.w * w4.w;
#pragma unroll
    for (int o = 1; o < 64; o <<= 1) s += __shfl_xor(s, o);
    if (lane == 0) {
        float d = rintf(expf(s + bo[0]));
        d = fminf(fmaxf(d, 1.0f), 8.0f);
        dur[row] = (int)d;
    }
}

__global__ __launch_bounds__(64) void scan_kernel(const int* __restrict__ dur,
                                                  int* __restrict__ starts,
                                                  int* __restrict__ totals)
{
    const int b = threadIdx.x;
    if (b >= NB) return;
    int acc = 0;
    for (int t = 0; t < NT; ++t) {
        starts[b * NT + t] = acc;
        acc += dur[b * NT + t];
    }
    totals[b] = acc;
}

__global__ __launch_bounds__(256) void tok_kernel(const int* __restrict__ starts,
                                                  const int* __restrict__ totals,
                                                  int* __restrict__ tok)
{
    const int gid = blockIdx.x * 256 + threadIdx.x;
    const int b = gid >> 11, p = gid & (TOUT - 1);
    const int total = totals[b];
    int res = -1;
    if (p < total) {
        const int* st = starts + b * NT;
        int lo = 0, hi = NT - 1;
        while (lo < hi) {
            int mid = (lo + hi + 1) >> 1;
            if (st[mid] <= p) lo = mid; else hi = mid - 1;
        }
        res = lo;
    }
    tok[gid] = res;
}

// ---------------- decoder conv3: wave-per-output, coalesced ----------------
__global__ __launch_bounds__(256) void conv3_kernel(const unsigned short* __restrict__ in,
                                                    const float* __restrict__ w,
                                                    const float* __restrict__ bias,
                                                    float* __restrict__ out)
{
    const int wave = threadIdx.x >> 6, lane = threadIdx.x & 63;
    const int gid = blockIdx.x * 4 + wave;     // 65536
    const int b = gid >> 11, t = gid & (TOUT - 1);
    const int c = lane * 2;
    float w0[5], w1[5];
#pragma unroll
    for (int k = 0; k < 5; ++k) { w0[k] = w[c * 5 + k]; w1[k] = w[(c + 1) * 5 + k]; }
    float acc = 0.f;
#pragma unroll
    for (int k = 0; k < 5; ++k) {
        int t2 = t + k - 2;
        if (t2 < 0 || t2 >= TOUT) continue;
        unsigned int u = *(const unsigned int*)&in[((size_t)(b * TOUT) + t2) * 128 + c];
        acc = fmaf(b2f((unsigned short)(u & 0xFFFF)), w0[k], acc);
        acc = fmaf(b2f((unsigned short)(u >> 16)), w1[k], acc);
    }
#pragma unroll
    for (int o = 1; o < 64; o <<= 1) acc += __shfl_xor(acc, o);
    if (lane == 0) out[gid] = acc + bias[0];
}

// ---------------- orchestration ----------------
extern "C" void kernel_launch(void* const* d_in, const int* in_sizes, int n_in,
                              void* d_out, int out_size, void* d_ws, size_t ws_size,
                              hipStream_t stream)
{
    const int*   text    = (const int*)d_in[0];
    const float* emotion = (const float*)d_in[1];
    const float* emb     = (const float*)d_in[2];
    const float* Wqkv    = (const float*)d_in[3];
    const float* bqkv    = (const float*)d_in[4];
    const float* Wo      = (const float*)d_in[5];
    const float* bo      = (const float*)d_in[6];
    const float* W1      = (const float*)d_in[7];
    const float* b1      = (const float*)d_in[8];
    const float* W2      = (const float*)d_in[9];
    const float* b2      = (const float*)d_in[10];
    const float* ln1g    = (const float*)d_in[11];
    const float* ln1b    = (const float*)d_in[12];
    const float* ln2g    = (const float*)d_in[13];
    const float* ln2b    = (const float*)d_in[14];
    const float* We1     = (const float*)d_in[15];
    const float* be1     = (const float*)d_in[16];
    const float* We2     = (const float*)d_in[17];
    const float* be2     = (const float*)d_in[18];
    const float* dp_w1   = (const float*)d_in[19];
    const float* dp_b1   = (const float*)d_in[20];
    const float* dp_g1   = (const float*)d_in[21];
    const float* dp_bt1  = (const float*)d_in[22];
    const float* dp_m1   = (const float*)d_in[23];
    const float* dp_v1   = (const float*)d_in[24];
    const float* dp_w2   = (const float*)d_in[25];
    const float* dp_b2   = (const float*)d_in[26];
    const float* dp_g2   = (const float*)d_in[27];
    const float* dp_bt2  = (const float*)d_in[28];
    const float* dp_m2   = (const float*)d_in[29];
    const float* dp_v2   = (const float*)d_in[30];
    const float* dp_wo   = (const float*)d_in[31];
    const float* dp_bo   = (const float*)d_in[32];
    const float* dec_w1  = (const float*)d_in[33];
    const float* dec_b1  = (const float*)d_in[34];
    const float* dec_w2  = (const float*)d_in[35];
    const float* dec_b2  = (const float*)d_in[36];
    const float* dec_w3  = (const float*)d_in[37];
    const float* dec_b3  = (const float*)d_in[38];

    float* ws   = (float*)d_ws;
    float* x    = ws + OFF_X;
    unsigned short* ffhB = (unsigned short*)(ws + OFF_FFH);
    unsigned short* Wbt  = (unsigned short*)(ws + OFF_WBT);
    float* wtdp1 = ws + OFF_CWT;
    float* wtdp2 = wtdp1 + 196608;
    unsigned short* wtb1 = (unsigned short*)(wtdp2 + 196608);
    unsigned short* wtb2 = wtb1 + 327680;
    unsigned short* qkvB = (unsigned short*)(ws + OFF_QKV);   // qkv bf16; later reg
    unsigned short* vtb  = qkvB + 12582912;
    unsigned short* regB = qkvB;                              // [B*2048, 256] bf16
    float* attb = ws + OFF_ATTN;
    float* prjb = ws + OFF_PROJ;
    float* ebuf = ws + OFF_E;
    unsigned short* attbB = (unsigned short*)attb;
    unsigned short* d1b  = ffhB;
    unsigned short* d2b  = (unsigned short*)attb;
    int*   ip     = (int*)(ws + OFF_INT);
    int*   durb   = ip;
    int*   startb = ip + 16384;
    int*   totb   = ip + 32768;
    int*   tokb   = ip + 32832;

    const int M = NB * NT;   // 16384

    embed_kernel<<<M, 256, 0, stream>>>(text, emb, x);

    wq_kernel<<<dim3(24, 8, 6), 256, 0, stream>>>(Wqkv, Wbt + 0,      256, 768,  196608, 786432);
    wq_kernel<<<dim3(8,  8, 6), 256, 0, stream>>>(Wo,   Wbt + 196608, 256, 256,  65536,  786432);
    wq_kernel<<<dim3(32, 8, 6), 256, 0, stream>>>(W1,   Wbt + 262144, 256, 1024, 262144, 786432);
    wq_kernel<<<dim3(8, 32, 6), 256, 0, stream>>>(W2,   Wbt + 524288, 1024, 256, 262144, 786432);

    for (int l = 0; l < NLAYER; ++l) {
        const unsigned short* WQ  = Wbt + (size_t)l * 786432;
        const unsigned short* WO  = WQ + 196608;
        const unsigned short* WF1 = WQ + 262144;
        const unsigned short* WF2 = WQ + 524288;
        gemmbf_kernel<128, false, false, true><<<dim3(6, 128), 256, 0, stream>>>(
            x, WQ, bqkv + l * 768, qkvB, M, 768, 256);
        vtrans_kernel<<<dim3(NT / 64, NH, NB), 256, 0, stream>>>(qkvB, vtb);
        attn3_kernel<<<dim3(NT / 128, NH, NB), 256, 0, stream>>>(qkvB, vtb, attbB);
        gemmbf_kernel<64, false, true, false><<<dim3(4, 128), 256, 0, stream>>>(
            attbB, WO, bo + l * 256, prjb, M, 256, 256);
        add_ln_kernel<<<M / 4, 256, 0, stream>>>(x, prjb, ln1g + l * ND, ln1b + l * ND);
        gemmbf_kernel<128, true, false, true><<<dim3(8, 128), 256, 0, stream>>>(
            x, WF1, b1 + l * 1024, ffhB, M, 1024, 256);
        gemmbf_kernel<64, false, true, false><<<dim3(4, 128), 256, 0, stream>>>(
            ffhB, WF2, b2 + l * 256, prjb, M, 256, 1024);
        add_ln_kernel<<<M / 4, 256, 0, stream>>>(x, prjb, ln2g + l * ND, ln2b + l * ND);
    }

    emotion_kernel<<<NB, 256, 0, stream>>>(emotion, We1, be1, We2, be2, ebuf);
    addfuse_kernel<<<M, 256, 0, stream>>>(x, ebuf);

    wtrans_kernel<<<(256 * 256 * 3 + 255) / 256, 256, 0, stream>>>(dp_w1, wtdp1, 256, 256, 3);
    wtrans_kernel<<<(256 * 256 * 3 + 255) / 256, 256, 0, stream>>>(dp_w2, wtdp2, 256, 256, 3);
    wtransb_kernel<<<(256 * 256 * 5 + 255) / 256, 256, 0, stream>>>(dec_w1, wtb1, 256, 256, 5);
    wtransb_kernel<<<(128 * 256 * 5 + 255) / 256, 256, 0, stream>>>(dec_w2, wtb2, 256, 128, 5);

    // duration predictor convs (fp32 mandatory: feeds dur rounding)
    convg_kernel<256, 3, true, true, false><<<dim3(NT / 128, 4, NB), 256, 0, stream>>>(
        x, wtdp1, dp_b1, dp_g1, dp_bt1, dp_m1, dp_v1, nullptr, attb, NT, NT, 256);
    convg_kernel<256, 3, true, true, false><<<dim3(NT / 128, 4, NB), 256, 0, stream>>>(
        attb, wtdp2, dp_b2, dp_g2, dp_bt2, dp_m2, dp_v2, nullptr, prjb, NT, NT, 256);
    dur_kernel<<<M / 4, 256, 0, stream>>>(prjb, dp_wo, dp_bo, durb);
    scan_kernel<<<1, 64, 0, stream>>>(durb, startb, totb);
    tok_kernel<<<NB * TOUT / 256, 256, 0, stream>>>(startb, totb, tokb);

    // materialize regulated sequence (bf16), then contiguous MFMA decoder convs
    reg_kernel<<<NB * TOUT / 4, 256, 0, stream>>>(x, tokb, regB);
    convmf2_kernel<256, 5, true><<<dim3(TOUT / 128, 4, NB), 256, 0, stream>>>(
        regB, wtb1, dec_b1, d1b, TOUT, 256);
    convmf2_kernel<256, 5, true><<<dim3(TOUT / 128, 2, NB), 256, 0, stream>>>(
        d1b, wtb2, dec_b2, d2b, TOUT, 128);
    conv3_kernel<<<NB * TOUT / 4, 256, 0, stream>>>(d2b, dec_w3, dec_b3, (float*)d_out);
}

// Round 9
// 1497.722 us; speedup vs baseline: 3.6961x; 1.0810x over previous
//
#include <hip/hip_runtime.h>
#include <math.h>

#define NB 32
#define NT 512
#define ND 256
#define NH 4
#define NLAYER 6
#define TOUT 2048

typedef __attribute__((ext_vector_type(8))) short bf16x8;
typedef __attribute__((ext_vector_type(4))) float f32x4;
typedef __attribute__((ext_vector_type(16))) float f32x16;

static __device__ __forceinline__ unsigned short f2b(float f) {
    union { float f; unsigned int u; } x; x.f = f;
    unsigned int u = x.u;
    return (unsigned short)((u + 0x7FFFu + ((u >> 16) & 1u)) >> 16);
}
static __device__ __forceinline__ float b2f(unsigned short s) {
    union { unsigned int u; float f; } x; x.u = ((unsigned int)s) << 16;
    return x.f;
}

// bank-balanced 16B-block swizzle: 8 consecutive rows cover all 32 banks once
#define SW(r) (((r) >> 1) & 3)

// ---------------- workspace layout (float offsets) ----------------
#define OFF_X    0ull          // 4,194,304   x fp32 [B,T,256] (residual; dur-critical)
#define OFF_FFH  4194304ull    // 8,388,608   ffh bf16 [16384,1024]; later d1b bf16
#define OFF_WBT  12582912ull   // 2,359,296   transformer weights bf16 [N][K]
#define OFF_CWT  14942208ull   // 442,368     conv weights bf16 [k][o][c] x4
#define OFF_QKV  20971520ull   // qkv bf16 + vt bf16; later reg bf16 [B,2048,256]
#define OFF_ATTN 33554432ull   // attn out bf16 / dp h1 bf16; later d2b bf16
#define OFF_PROJ 37748736ull   // proj / ff2 out fp32 / dp h2 fp32
#define OFF_INT  41951232ull   // ints: dur, tok

// ---------------- embedding + positional encoding ----------------
__global__ __launch_bounds__(256) void embed_kernel(const int* __restrict__ text,
                                                    const float* __restrict__ emb,
                                                    float* __restrict__ x)
{
    const int row = blockIdx.x;
    const int d = threadIdx.x;
    const int t = row & (NT - 1);
    const int id = text[row];
    const int j2 = (d >> 1) * 2;
    const float c = -9.210340371976184f / 256.0f;
    float freq = expf((float)j2 * c);
    float ang = (float)t * freq;
    float pe = (d & 1) ? cosf(ang) : sinf(ang);
    x[(size_t)row * ND + d] = emb[(size_t)id * ND + d] + pe;
}

// ---------------- merged transformer weight transpose: fp32 [K,N] -> bf16 [N,K] ----------------
__global__ __launch_bounds__(256) void wqall_kernel(const float* __restrict__ Wqkv,
                                                    const float* __restrict__ Wo,
                                                    const float* __restrict__ W1,
                                                    const float* __restrict__ W2,
                                                    unsigned short* __restrict__ Wbt)
{
    __shared__ float tile[32][33];
    const int tt = blockIdx.x, layer = blockIdx.y;
    const float* src; int K, N, n0, k0, inLS; size_t outSeg;
    if (tt < 192)      { src = Wqkv; K = 256;  N = 768;  n0 = (tt % 24) * 32; k0 = (tt / 24) * 32; inLS = 196608; outSeg = 0; }
    else if (tt < 256) { int t2 = tt - 192; src = Wo; K = 256; N = 256;  n0 = (t2 & 7) * 32;  k0 = (t2 >> 3) * 32; inLS = 65536;  outSeg = 196608; }
    else if (tt < 512) { int t3 = tt - 256; src = W1; K = 256; N = 1024; n0 = (t3 & 31) * 32; k0 = (t3 >> 5) * 32; inLS = 262144; outSeg = 262144; }
    else               { int t4 = tt - 512; src = W2; K = 1024; N = 256; n0 = (t4 & 7) * 32;  k0 = (t4 >> 3) * 32; inLS = 262144; outSeg = 524288; }
    const float* Wl = src + (size_t)layer * inLS;
    unsigned short* ol = Wbt + (size_t)layer * 786432 + outSeg;
    const int tx = threadIdx.x & 31, ty = threadIdx.x >> 5;
#pragma unroll
    for (int j = 0; j < 4; ++j)
        tile[ty + j * 8][tx] = Wl[(size_t)(k0 + ty + j * 8) * N + n0 + tx];
    __syncthreads();
#pragma unroll
    for (int j = 0; j < 4; ++j)
        ol[(size_t)(n0 + ty + j * 8) * K + k0 + tx] = f2b(tile[tx][ty + j * 8]);
}

// ---------------- merged conv weight transpose: w[O,I,K] -> wtb[k][o][c] bf16 ----------------
__global__ __launch_bounds__(256) void wtransball_kernel(const float* __restrict__ dp_w1,
                                                         const float* __restrict__ dp_w2,
                                                         const float* __restrict__ dec_w1,
                                                         const float* __restrict__ dec_w2,
                                                         unsigned short* __restrict__ cw)
{
    int gid = blockIdx.x * 256 + threadIdx.x;
    if (gid >= 884736) return;
    const float* src; int CIN = 256, COUT, KS, idx;
    if (gid < 196608)      { src = dp_w1;  COUT = 256; KS = 3; idx = gid; }
    else if (gid < 393216) { src = dp_w2;  COUT = 256; KS = 3; idx = gid - 196608; }
    else if (gid < 720896) { src = dec_w1; COUT = 256; KS = 5; idx = gid - 393216; }
    else                   { src = dec_w2; COUT = 128; KS = 5; idx = gid - 720896; }
    int c = idx % CIN;
    int r = idx / CIN;
    int o = r % COUT;
    int k = r / COUT;
    cw[gid] = f2b(src[(o * CIN + c) * KS + k]);
}

// ---------------- bf16 MFMA GEMM: C[M,N] = A[M,K] @ B[K,N] + bias ----------------
// VOUT: for the qkv GEMM, V columns (>=512) are also written transposed to vt[b,h,d,t].
template<int NTILE, bool RELU, bool ABF16, bool CBF16, bool VOUT>
__global__ __launch_bounds__(256) void gemmbf_kernel(const void* __restrict__ A_,
                                                     const unsigned short* __restrict__ Bt,
                                                     const float* __restrict__ bias,
                                                     void* __restrict__ C_,
                                                     unsigned short* __restrict__ vt,
                                                     int M, int N, int K)
{
    constexpr int MT = (NTILE == 128) ? 2 : 1;
    __shared__ __align__(16) unsigned short Asb[128 * 32];
    __shared__ __align__(16) unsigned short Bsb[NTILE * 32];
    const int tid = threadIdx.x;
    const int lane = tid & 63, wave = tid >> 6;
    const int ln = lane & 31, hi = lane >> 5;
    const int row0 = blockIdx.y * 128, col0 = blockIdx.x * NTILE;
    const int mOff = (NTILE == 128) ? (wave >> 1) * 64 : wave * 32;
    const int nOff = (NTILE == 128) ? (wave & 1) * 64 : 0;
    const float* Af = (const float*)A_;
    const unsigned short* Ab = (const unsigned short*)A_;
    float* Cf = (float*)C_;
    unsigned short* Cb = (unsigned short*)C_;
    f32x16 acc[MT][2] = {};

    for (int k0 = 0; k0 < K; k0 += 32) {
#pragma unroll
        for (int it = 0; it < 2; ++it) {
            int u = it * 256 + tid;
            int m = u >> 2, blk = u & 3;
            unsigned short s8[8];
            if (ABF16) {
                *(uint4*)s8 = *(const uint4*)&Ab[(size_t)(row0 + m) * K + k0 + blk * 8];
            } else {
                float4 v0 = *(const float4*)&Af[(size_t)(row0 + m) * K + k0 + blk * 8];
                float4 v1 = *(const float4*)&Af[(size_t)(row0 + m) * K + k0 + blk * 8 + 4];
                s8[0] = f2b(v0.x); s8[1] = f2b(v0.y); s8[2] = f2b(v0.z); s8[3] = f2b(v0.w);
                s8[4] = f2b(v1.x); s8[5] = f2b(v1.y); s8[6] = f2b(v1.z); s8[7] = f2b(v1.w);
            }
            *(uint4*)&Asb[m * 32 + ((blk ^ SW(m)) << 3)] = *(uint4*)s8;
        }
#pragma unroll
        for (int it = 0; it < NTILE / 64; ++it) {
            int u = it * 256 + tid;
            int n = u >> 2, blk = u & 3;
            *(uint4*)&Bsb[n * 32 + ((blk ^ SW(n)) << 3)] =
                *(const uint4*)&Bt[(size_t)(col0 + n) * K + k0 + blk * 8];
        }
        __syncthreads();
#pragma unroll
        for (int kh = 0; kh < 2; ++kh) {
            const int kb = kh * 2 + hi;
            bf16x8 af[MT], bfr[2];
#pragma unroll
            for (int mt = 0; mt < MT; ++mt) {
                int r = mOff + mt * 32 + ln;
                af[mt] = *(const bf16x8*)&Asb[r * 32 + ((kb ^ SW(r)) << 3)];
            }
#pragma unroll
            for (int nt = 0; nt < 2; ++nt) {
                int r = nOff + nt * 32 + ln;
                bfr[nt] = *(const bf16x8*)&Bsb[r * 32 + ((kb ^ SW(r)) << 3)];
            }
#pragma unroll
            for (int mt = 0; mt < MT; ++mt)
#pragma unroll
                for (int nt = 0; nt < 2; ++nt)
                    acc[mt][nt] = __builtin_amdgcn_mfma_f32_32x32x16_bf16(
                        af[mt], bfr[nt], acc[mt][nt], 0, 0, 0);
        }
        __syncthreads();
    }
#pragma unroll
    for (int mt = 0; mt < MT; ++mt)
#pragma unroll
        for (int nt = 0; nt < 2; ++nt) {
            int col = col0 + nOff + nt * 32 + ln;
            float bi = bias[col];
#pragma unroll
            for (int g = 0; g < 4; ++g) {
                unsigned short s4[4];
#pragma unroll
                for (int r4 = 0; r4 < 4; ++r4) {
                    int row = row0 + mOff + mt * 32 + hi * 4 + g * 8 + r4;
                    float v = acc[mt][nt][g * 4 + r4] + bi;
                    if (RELU) v = fmaxf(v, 0.f);
                    if (CBF16) { s4[r4] = f2b(v); Cb[(size_t)row * N + col] = s4[r4]; }
                    else       Cf[(size_t)row * N + col] = v;
                }
                if (VOUT && col >= 512) {
                    int rowg = row0 + mOff + mt * 32 + hi * 4 + g * 8;
                    int b = rowg >> 9, t = rowg & (NT - 1);
                    int hh = (col - 512) >> 6, dd = (col - 512) & 63;
                    *(uint2*)&vt[((size_t)(b * NH + hh) * 64 + dd) * NT + t] = *(uint2*)s4;
                }
            }
        }
}

// ---------------- attention v3: bf16 MFMA flash, computes O^T ----------------
__global__ __launch_bounds__(256, 2) void attn3_kernel(const unsigned short* __restrict__ qkv,
                                                       const unsigned short* __restrict__ vt,
                                                       unsigned short* __restrict__ out)
{
    __shared__ __align__(16) unsigned short sP[4][32 * 64];
    const int tid = threadIdx.x;
    const int lane = tid & 63, wave = tid >> 6;
    const int ln = lane & 31, hi = lane >> 5;
    const int h = blockIdx.y, b = blockIdx.z;
    const int q0 = blockIdx.x * 128 + wave * 32;
    const size_t base = (size_t)b * NT * 768;
    const int qoff = h * 64;
    const unsigned short* vbh = vt + (size_t)(b * NH + h) * 64 * NT;

    bf16x8 qf[4];
#pragma unroll
    for (int s = 0; s < 4; ++s)
        qf[s] = *(const bf16x8*)&qkv[base + (size_t)(q0 + ln) * 768 + qoff + s * 16 + hi * 8];

    float mrow[16], lrow[16];
#pragma unroll
    for (int i = 0; i < 16; ++i) { mrow[i] = -1e30f; lrow[i] = 0.f; }
    f32x16 oacc[2] = {};
    const float sc = 0.18033688011112042f;   // 0.125 * log2(e)
    const int i0 = (ln & 3) | (((ln >> 3) & 3) << 2);
    const bool own = (((ln >> 2) & 1) == hi);
    unsigned short* Pw = &sP[wave][0];

    for (int ch = 0; ch < 8; ++ch) {
        const int s0 = ch * 64;
        f32x16 sacc[2] = {};
#pragma unroll
        for (int ct = 0; ct < 2; ++ct)
#pragma unroll
            for (int s = 0; s < 4; ++s) {
                bf16x8 kf = *(const bf16x8*)&qkv[base + (size_t)(s0 + ct * 32 + ln) * 768
                                                 + 256 + qoff + s * 16 + hi * 8];
                sacc[ct] = __builtin_amdgcn_mfma_f32_32x32x16_bf16(qf[s], kf, sacc[ct], 0, 0, 0);
            }
        float alpha[16];
#pragma unroll
        for (int i = 0; i < 16; ++i) {
            float s20 = sacc[0][i] * sc, s21 = sacc[1][i] * sc;
            float mx = fmaxf(s20, s21);
#pragma unroll
            for (int o = 1; o < 32; o <<= 1) mx = fmaxf(mx, __shfl_xor(mx, o));
            float mn = fmaxf(mrow[i], mx);
            alpha[i] = exp2f(mrow[i] - mn);
            mrow[i] = mn;
            float p0 = exp2f(s20 - mn);
            float p1 = exp2f(s21 - mn);
            sacc[0][i] = p0; sacc[1][i] = p1;
            float rs = p0 + p1;
#pragma unroll
            for (int o = 1; o < 32; o <<= 1) rs += __shfl_xor(rs, o);
            lrow[i] = lrow[i] * alpha[i] + rs;
        }
#pragma unroll
        for (int ct = 0; ct < 2; ++ct) {
            int kb = ct * 4 + (ln >> 3), k7 = ln & 7;
#pragma unroll
            for (int i = 0; i < 16; ++i) {
                int q = (i & 3) + 8 * (i >> 2) + 4 * hi;
                Pw[q * 64 + (((kb ^ (q & 7)) << 3) | k7)] = f2b(sacc[ct][i]);
            }
        }
        __syncthreads();
        {
            float av = alpha[i0];
            float ao = __shfl_xor(av, 32);
            float aq = own ? av : ao;
#pragma unroll
            for (int ct = 0; ct < 2; ++ct)
#pragma unroll
                for (int i = 0; i < 16; ++i)
                    oacc[ct][i] *= aq;
        }
#pragma unroll
        for (int s = 0; s < 4; ++s) {
            bf16x8 pf = *(const bf16x8*)&Pw[ln * 64 + (((s * 2 + hi) ^ (ln & 7)) << 3)];
#pragma unroll
            for (int ct = 0; ct < 2; ++ct) {
                bf16x8 vf = *(const bf16x8*)&vbh[(size_t)(ct * 32 + ln) * NT + s0 + s * 16 + hi * 8];
                oacc[ct] = __builtin_amdgcn_mfma_f32_32x32x16_bf16(vf, pf, oacc[ct], 0, 0, 0);
            }
        }
        __syncthreads();
    }
    float lv = lrow[i0];
    float lo = __shfl_xor(lv, 32);
    float linv = 1.0f / (own ? lv : lo);
    const int q = q0 + ln;
#pragma unroll
    for (int ct = 0; ct < 2; ++ct)
#pragma unroll
        for (int i = 0; i < 16; ++i) {
            int d = ct * 32 + (i & 3) + 8 * (i >> 2) + 4 * hi;
            out[(size_t)(b * NT + q) * ND + qoff + d] = f2b(oacc[ct][i] * linv);
        }
}

// ---------------- x = LayerNorm(x + y), wave-per-row ----------------
__global__ __launch_bounds__(256) void add_ln_kernel(float* __restrict__ x,
                                                     const float* __restrict__ y,
                                                     const float* __restrict__ g,
                                                     const float* __restrict__ bta)
{
    const int w = threadIdx.x >> 6, lane = threadIdx.x & 63;
    const size_t row = (size_t)blockIdx.x * 4 + w;
    const int c4 = lane * 4;
    float4 xv = *(const float4*)&x[row * ND + c4];
    float4 yv = *(const float4*)&y[row * ND + c4];
    float4 v = make_float4(xv.x + yv.x, xv.y + yv.y, xv.z + yv.z, xv.w + yv.w);
    float s = v.x + v.y + v.z + v.w;
#pragma unroll
    for (int o = 1; o < 64; o <<= 1) s += __shfl_xor(s, o);
    float m = s * (1.0f / 256.0f);
    float4 dv = make_float4(v.x - m, v.y - m, v.z - m, v.w - m);
    float s2 = dv.x * dv.x + dv.y * dv.y + dv.z * dv.z + dv.w * dv.w;
#pragma unroll
    for (int o = 1; o < 64; o <<= 1) s2 += __shfl_xor(s2, o);
    float r = 1.0f / sqrtf(s2 * (1.0f / 256.0f) + 1e-5f);
    float4 gv = *(const float4*)&g[c4];
    float4 bv = *(const float4*)&bta[c4];
    float4 o4 = make_float4(dv.x * r * gv.x + bv.x, dv.y * r * gv.y + bv.y,
                            dv.z * r * gv.z + bv.z, dv.w * r * gv.w + bv.w);
    *(float4*)&x[row * ND + c4] = o4;
}

// ---------------- fused emotion MLP + add: x += MLP(emotion)[b] ----------------
__global__ __launch_bounds__(256) void fuse_kernel(const float* __restrict__ emo,
                                                   const float* __restrict__ We1,
                                                   const float* __restrict__ be1,
                                                   const float* __restrict__ We2,
                                                   const float* __restrict__ be2,
                                                   float* __restrict__ x)
{
    const int row = blockIdx.x;
    const int d = threadIdx.x;
    const float em = emo[row >> 9];
    float acc = be2[d];
    for (int j = 0; j < 64; ++j) {
        float h = fmaxf(em * We1[j] + be1[j], 0.0f);
        acc = fmaf(h, We2[j * ND + d], acc);
    }
    x[(size_t)row * ND + d] += acc;
}

// ---------------- unified bf16 MFMA conv: tile 128t x 64o, BK=32, B in LDS ----------------
// in [B,T,CIN] (fp32 or bf16); weights wtb[k][o][c] bf16; relu always; optional BN epilogue.
template<int CIN, int KS, bool IN_BF16, bool OUT_BF16, bool BN>
__global__ __launch_bounds__(256) void convk_kernel(const void* __restrict__ in_,
                                                    const unsigned short* __restrict__ wtb,
                                                    const float* __restrict__ bias,
                                                    const float* __restrict__ bng,
                                                    const float* __restrict__ bnb,
                                                    const float* __restrict__ bnm,
                                                    const float* __restrict__ bnv,
                                                    void* __restrict__ out_,
                                                    int T, int COUT)
{
    constexpr int PAD = (KS - 1) / 2;
    constexpr int TEXT = 128 + KS - 1;
    __shared__ __align__(16) unsigned short Asb[TEXT * 32];
    __shared__ __align__(16) unsigned short Bsb[KS * 64 * 32];
    const int tid = threadIdx.x;
    const int lane = tid & 63, wave = tid >> 6;
    const int ln = lane & 31, hi = lane >> 5;
    const int b = blockIdx.z;
    const int t0 = blockIdx.x * 128;
    const int o0 = blockIdx.y * 64;
    const int mOff = wave * 32;
    const float* inf = (const float*)in_;
    const unsigned short* inb = (const unsigned short*)in_;
    float* outf = (float*)out_;
    unsigned short* outb = (unsigned short*)out_;
    f32x16 acc[2] = {};

    for (int cc = 0; cc < CIN; cc += 32) {
        for (int u = tid; u < TEXT * 4; u += 256) {
            int t = u >> 2, blk = u & 3;
            int tg = t0 - PAD + t;
            unsigned short s8[8] = {0, 0, 0, 0, 0, 0, 0, 0};
            if (tg >= 0 && tg < T) {
                if (IN_BF16) {
                    *(uint4*)s8 = *(const uint4*)&inb[((size_t)(b * T) + tg) * CIN + cc + blk * 8];
                } else {
                    float4 v0 = *(const float4*)&inf[((size_t)(b * T) + tg) * CIN + cc + blk * 8];
                    float4 v1 = *(const float4*)&inf[((size_t)(b * T) + tg) * CIN + cc + blk * 8 + 4];
                    s8[0] = f2b(v0.x); s8[1] = f2b(v0.y); s8[2] = f2b(v0.z); s8[3] = f2b(v0.w);
                    s8[4] = f2b(v1.x); s8[5] = f2b(v1.y); s8[6] = f2b(v1.z); s8[7] = f2b(v1.w);
                }
            }
            *(uint4*)&Asb[t * 32 + ((blk ^ SW(t)) << 3)] = *(uint4*)s8;
        }
        for (int u = tid; u < KS * 256; u += 256) {
            int row = u >> 2, blk = u & 3;    // row = k*64 + o
            int k = row >> 6, o = row & 63;
            *(uint4*)&Bsb[row * 32 + ((blk ^ SW(row)) << 3)] =
                *(const uint4*)&wtb[((size_t)k * COUT + o0 + o) * CIN + cc + blk * 8];
        }
        __syncthreads();
#pragma unroll
        for (int kh = 0; kh < 2; ++kh) {
            const int kb = kh * 2 + hi;
            bf16x8 af[KS];
#pragma unroll
            for (int tap = 0; tap < KS; ++tap) {
                int r = mOff + ln + tap;
                af[tap] = *(const bf16x8*)&Asb[r * 32 + ((kb ^ SW(r)) << 3)];
            }
#pragma unroll
            for (int nt = 0; nt < 2; ++nt) {
#pragma unroll
                for (int tap = 0; tap < KS; ++tap) {
                    int rb = tap * 64 + nt * 32 + ln;
                    bf16x8 bfr = *(const bf16x8*)&Bsb[rb * 32 + ((kb ^ SW(rb)) << 3)];
                    acc[nt] = __builtin_amdgcn_mfma_f32_32x32x16_bf16(af[tap], bfr, acc[nt], 0, 0, 0);
                }
            }
        }
        __syncthreads();
    }
#pragma unroll
    for (int nt = 0; nt < 2; ++nt) {
        int col = o0 + nt * 32 + ln;
        float bi = bias[col];
        float scv = 1.f, shv = 0.f;
        if (BN) {
            scv = bng[col] / sqrtf(bnv[col] + 1e-5f);
            shv = bnb[col] - bnm[col] * scv;
        }
#pragma unroll
        for (int g = 0; g < 4; ++g)
#pragma unroll
            for (int r4 = 0; r4 < 4; ++r4) {
                int row = t0 + mOff + hi * 4 + g * 8 + r4;
                float v = fmaxf(acc[nt][g * 4 + r4] + bi, 0.f);
                if (BN) v = v * scv + shv;
                if (OUT_BF16) outb[((size_t)(b * T) + row) * COUT + col] = f2b(v);
                else          outf[((size_t)(b * T) + row) * COUT + col] = v;
            }
    }
}

// ---------------- regulated-sequence materialization ----------------
__global__ __launch_bounds__(256) void reg_kernel(const float* __restrict__ x,
                                                  const int* __restrict__ tok,
                                                  unsigned short* __restrict__ reg)
{
    const int wave = threadIdx.x >> 6, lane = threadIdx.x & 63;
    const int row = blockIdx.x * 4 + wave;
    const int tk = tok[row];
    const int b = row >> 11;
    const int c4 = lane * 4;
    unsigned short s4[4] = {0, 0, 0, 0};
    if (tk >= 0) {
        float4 v = *(const float4*)&x[((size_t)(b * NT) + tk) * ND + c4];
        s4[0] = f2b(v.x); s4[1] = f2b(v.y); s4[2] = f2b(v.z); s4[3] = f2b(v.w);
    }
    *(uint2*)&reg[(size_t)row * ND + c4] = *(uint2*)s4;
}

// ---------------- duration: wave-per-row dot -> dur ----------------
__global__ __launch_bounds__(256) void dur_kernel(const float* __restrict__ h2,
                                                  const float* __restrict__ wo,
                                                  const float* __restrict__ bo,
                                                  int* __restrict__ dur)
{
    const int wave = threadIdx.x >> 6, lane = threadIdx.x & 63;
    const int row = blockIdx.x * 4 + wave;
    const int c4 = lane * 4;
    float4 h = *(const float4*)&h2[(size_t)row * ND + c4];
    float4 w4 = *(const float4*)&wo[c4];
    float s = h.x * w4.x + h.y * w4.y + h.z * w4.z + h.w * w4.w;
#pragma unroll
    for (int o = 1; o < 64; o <<= 1) s += __shfl_xor(s, o);
    if (lane == 0) {
        float d = rintf(expf(s + bo[0]));
        d = fminf(fmaxf(d, 1.0f), 8.0f);
        dur[row] = (int)d;
    }
}

// ---------------- fused scan + token map: one block per batch ----------------
__global__ __launch_bounds__(256) void scantok_kernel(const int* __restrict__ dur,
                                                      int* __restrict__ tok)
{
    __shared__ int st[NT];
    __shared__ int tot;
    const int b = blockIdx.x, tid = threadIdx.x;
    if (tid == 0) {
        int a = 0;
        for (int t = 0; t < NT; ++t) { st[t] = a; a += dur[b * NT + t]; }
        tot = a;
    }
    __syncthreads();
    for (int p = tid; p < TOUT; p += 256) {
        int res = -1;
        if (p < tot) {
            int lo = 0, hi = NT - 1;
            while (lo < hi) {
                int mid = (lo + hi + 1) >> 1;
                if (st[mid] <= p) lo = mid; else hi = mid - 1;
            }
            res = lo;
        }
        tok[b * TOUT + p] = res;
    }
}

// ---------------- decoder conv3: wave-per-output, coalesced ----------------
__global__ __launch_bounds__(256) void conv3_kernel(const unsigned short* __restrict__ in,
                                                    const float* __restrict__ w,
                                                    const float* __restrict__ bias,
                                                    float* __restrict__ out)
{
    const int wave = threadIdx.x >> 6, lane = threadIdx.x & 63;
    const int gid = blockIdx.x * 4 + wave;
    const int b = gid >> 11, t = gid & (TOUT - 1);
    const int c = lane * 2;
    float w0[5], w1[5];
#pragma unroll
    for (int k = 0; k < 5; ++k) { w0[k] = w[c * 5 + k]; w1[k] = w[(c + 1) * 5 + k]; }
    float acc = 0.f;
#pragma unroll
    for (int k = 0; k < 5; ++k) {
        int t2 = t + k - 2;
        if (t2 < 0 || t2 >= TOUT) continue;
        unsigned int u = *(const unsigned int*)&in[((size_t)(b * TOUT) + t2) * 128 + c];
        acc = fmaf(b2f((unsigned short)(u & 0xFFFF)), w0[k], acc);
        acc = fmaf(b2f((unsigned short)(u >> 16)), w1[k], acc);
    }
#pragma unroll
    for (int o = 1; o < 64; o <<= 1) acc += __shfl_xor(acc, o);
    if (lane == 0) out[gid] = acc + bias[0];
}

// ---------------- orchestration ----------------
extern "C" void kernel_launch(void* const* d_in, const int* in_sizes, int n_in,
                              void* d_out, int out_size, void* d_ws, size_t ws_size,
                              hipStream_t stream)
{
    const int*   text    = (const int*)d_in[0];
    const float* emotion = (const float*)d_in[1];
    const float* emb     = (const float*)d_in[2];
    const float* Wqkv    = (const float*)d_in[3];
    const float* bqkv    = (const float*)d_in[4];
    const float* Wo      = (const float*)d_in[5];
    const float* bo      = (const float*)d_in[6];
    const float* W1      = (const float*)d_in[7];
    const float* b1      = (const float*)d_in[8];
    const float* W2      = (const float*)d_in[9];
    const float* b2      = (const float*)d_in[10];
    const float* ln1g    = (const float*)d_in[11];
    const float* ln1b    = (const float*)d_in[12];
    const float* ln2g    = (const float*)d_in[13];
    const float* ln2b    = (const float*)d_in[14];
    const float* We1     = (const float*)d_in[15];
    const float* be1     = (const float*)d_in[16];
    const float* We2     = (const float*)d_in[17];
    const float* be2     = (const float*)d_in[18];
    const float* dp_w1   = (const float*)d_in[19];
    const float* dp_b1   = (const float*)d_in[20];
    const float* dp_g1   = (const float*)d_in[21];
    const float* dp_bt1  = (const float*)d_in[22];
    const float* dp_m1   = (const float*)d_in[23];
    const float* dp_v1   = (const float*)d_in[24];
    const float* dp_w2   = (const float*)d_in[25];
    const float* dp_b2   = (const float*)d_in[26];
    const float* dp_g2   = (const float*)d_in[27];
    const float* dp_bt2  = (const float*)d_in[28];
    const float* dp_m2   = (const float*)d_in[29];
    const float* dp_v2   = (const float*)d_in[30];
    const float* dp_wo   = (const float*)d_in[31];
    const float* dp_bo   = (const float*)d_in[32];
    const float* dec_w3  = (const float*)d_in[37];
    const float* dec_b1  = (const float*)d_in[34];
    const float* dec_b2  = (const float*)d_in[36];
    const float* dec_b3  = (const float*)d_in[38];

    float* ws   = (float*)d_ws;
    float* x    = ws + OFF_X;
    unsigned short* ffhB = (unsigned short*)(ws + OFF_FFH);
    unsigned short* Wbt  = (unsigned short*)(ws + OFF_WBT);
    unsigned short* cw   = (unsigned short*)(ws + OFF_CWT);
    unsigned short* wtbdp1 = cw;                 // 196608
    unsigned short* wtbdp2 = cw + 196608;        // 196608
    unsigned short* wtb1   = cw + 393216;        // 327680
    unsigned short* wtb2   = cw + 720896;        // 163840
    unsigned short* qkvB = (unsigned short*)(ws + OFF_QKV);
    unsigned short* vtb  = qkvB + 12582912;
    unsigned short* regB = qkvB;
    float* attb = ws + OFF_ATTN;
    float* prjb = ws + OFF_PROJ;
    unsigned short* attbB = (unsigned short*)attb;
    unsigned short* h1b  = (unsigned short*)attb;
    unsigned short* d1b  = ffhB;
    unsigned short* d2b  = (unsigned short*)attb;
    int*   ip     = (int*)(ws + OFF_INT);
    int*   durb   = ip;             // 16384
    int*   tokb   = ip + 16384;     // 65536

    const int M = NB * NT;   // 16384

    embed_kernel<<<M, 256, 0, stream>>>(text, emb, x);
    wqall_kernel<<<dim3(768, 6), 256, 0, stream>>>(Wqkv, Wo, W1, W2, Wbt);
    wtransball_kernel<<<3456, 256, 0, stream>>>(dp_w1, dp_w2,
                                                (const float*)d_in[33], (const float*)d_in[35], cw);

    for (int l = 0; l < NLAYER; ++l) {
        const unsigned short* WQ  = Wbt + (size_t)l * 786432;
        const unsigned short* WO  = WQ + 196608;
        const unsigned short* WF1 = WQ + 262144;
        const unsigned short* WF2 = WQ + 524288;
        gemmbf_kernel<128, false, false, true, true><<<dim3(6, 128), 256, 0, stream>>>(
            x, WQ, bqkv + l * 768, qkvB, vtb, M, 768, 256);
        attn3_kernel<<<dim3(NT / 128, NH, NB), 256, 0, stream>>>(qkvB, vtb, attbB);
        gemmbf_kernel<64, false, true, false, false><<<dim3(4, 128), 256, 0, stream>>>(
            attbB, WO, bo + l * 256, prjb, nullptr, M, 256, 256);
        add_ln_kernel<<<M / 4, 256, 0, stream>>>(x, prjb, ln1g + l * ND, ln1b + l * ND);
        gemmbf_kernel<128, true, false, true, false><<<dim3(8, 128), 256, 0, stream>>>(
            x, WF1, b1 + l * 1024, ffhB, nullptr, M, 1024, 256);
        gemmbf_kernel<64, false, true, false, false><<<dim3(4, 128), 256, 0, stream>>>(
            ffhB, WF2, b2 + l * 256, prjb, nullptr, M, 256, 1024);
        add_ln_kernel<<<M / 4, 256, 0, stream>>>(x, prjb, ln2g + l * ND, ln2b + l * ND);
    }

    fuse_kernel<<<M, 256, 0, stream>>>(emotion, We1, be1, We2, be2, x);

    // duration predictor convs: bf16 MFMA, BN epilogue (dp2 outputs fp32 for dur)
    convk_kernel<256, 3, false, true, true><<<dim3(4, 4, NB), 256, 0, stream>>>(
        x, wtbdp1, dp_b1, dp_g1, dp_bt1, dp_m1, dp_v1, h1b, NT, 256);
    convk_kernel<256, 3, true, false, true><<<dim3(4, 4, NB), 256, 0, stream>>>(
        h1b, wtbdp2, dp_b2, dp_g2, dp_bt2, dp_m2, dp_v2, prjb, NT, 256);
    dur_kernel<<<M / 4, 256, 0, stream>>>(prjb, dp_wo, dp_bo, durb);
    scantok_kernel<<<NB, 256, 0, stream>>>(durb, tokb);

    // decoder: regulated gather then bf16 MFMA convs
    reg_kernel<<<NB * TOUT / 4, 256, 0, stream>>>(x, tokb, regB);
    convk_kernel<256, 5, true, true, false><<<dim3(TOUT / 128, 4, NB), 256, 0, stream>>>(
        regB, wtb1, dec_b1, nullptr, nullptr, nullptr, nullptr, d1b, TOUT, 256);
    convk_kernel<256, 5, true, true, false><<<dim3(TOUT / 128, 2, NB), 256, 0, stream>>>(
        d1b, wtb2, dec_b2, nullptr, nullptr, nullptr, nullptr, d2b, TOUT, 128);
    conv3_kernel<<<NB * TOUT / 4, 256, 0, stream>>>(d2b, dec_w3, dec_b3, (float*)d_out);
}

// Round 10
// 1472.776 us; speedup vs baseline: 3.7587x; 1.0169x over previous
//
#include <hip/hip_runtime.h>
#include <math.h>

#define NB 32
#define NT 512
#define ND 256
#define NH 4
#define NLAYER 6
#define TOUT 2048

typedef __attribute__((ext_vector_type(8))) short bf16x8;
typedef __attribute__((ext_vector_type(4))) float f32x4;
typedef __attribute__((ext_vector_type(16))) float f32x16;

static __device__ __forceinline__ unsigned short f2b(float f) {
    union { float f; unsigned int u; } x; x.f = f;
    unsigned int u = x.u;
    return (unsigned short)((u + 0x7FFFu + ((u >> 16) & 1u)) >> 16);
}
static __device__ __forceinline__ float b2f(unsigned short s) {
    union { unsigned int u; float f; } x; x.u = ((unsigned int)s) << 16;
    return x.f;
}

// bank-balanced 16B-block swizzle: 8 consecutive rows cover all 32 banks once
#define SW(r) (((r) >> 1) & 3)

// ---------------- workspace layout (float offsets) ----------------
#define OFF_X    0ull          // x fp32 [B,T,256] (residual; dur-critical)
#define OFF_FFH  4194304ull    // ffh bf16 [16384,1024]; later d1b bf16
#define OFF_WBT  12582912ull   // transformer weights bf16 [N][K]
#define OFF_CWT  14942208ull   // conv weights bf16 [k][o][c] x4
#define OFF_QKV  20971520ull   // qkv bf16 + vt bf16; later reg bf16
#define OFF_ATTN 33554432ull   // attn out bf16 / dp h1 bf16; later d2b bf16
#define OFF_PROJ 37748736ull   // dp h2 fp32
#define OFF_INT  41951232ull   // ints: dur, tok

// ---------------- embedding + positional encoding ----------------
__global__ __launch_bounds__(256) void embed_kernel(const int* __restrict__ text,
                                                    const float* __restrict__ emb,
                                                    float* __restrict__ x)
{
    const int row = blockIdx.x;
    const int d = threadIdx.x;
    const int t = row & (NT - 1);
    const int id = text[row];
    const int j2 = (d >> 1) * 2;
    const float c = -9.210340371976184f / 256.0f;
    float freq = expf((float)j2 * c);
    float ang = (float)t * freq;
    float pe = (d & 1) ? cosf(ang) : sinf(ang);
    x[(size_t)row * ND + d] = emb[(size_t)id * ND + d] + pe;
}

// ---------------- merged transformer weight transpose: fp32 [K,N] -> bf16 [N,K] ----------------
__global__ __launch_bounds__(256) void wqall_kernel(const float* __restrict__ Wqkv,
                                                    const float* __restrict__ Wo,
                                                    const float* __restrict__ W1,
                                                    const float* __restrict__ W2,
                                                    unsigned short* __restrict__ Wbt)
{
    __shared__ float tile[32][33];
    const int tt = blockIdx.x, layer = blockIdx.y;
    const float* src; int K, N, n0, k0, inLS; size_t outSeg;
    if (tt < 192)      { src = Wqkv; K = 256;  N = 768;  n0 = (tt % 24) * 32; k0 = (tt / 24) * 32; inLS = 196608; outSeg = 0; }
    else if (tt < 256) { int t2 = tt - 192; src = Wo; K = 256; N = 256;  n0 = (t2 & 7) * 32;  k0 = (t2 >> 3) * 32; inLS = 65536;  outSeg = 196608; }
    else if (tt < 512) { int t3 = tt - 256; src = W1; K = 256; N = 1024; n0 = (t3 & 31) * 32; k0 = (t3 >> 5) * 32; inLS = 262144; outSeg = 262144; }
    else               { int t4 = tt - 512; src = W2; K = 1024; N = 256; n0 = (t4 & 7) * 32;  k0 = (t4 >> 3) * 32; inLS = 262144; outSeg = 524288; }
    const float* Wl = src + (size_t)layer * inLS;
    unsigned short* ol = Wbt + (size_t)layer * 786432 + outSeg;
    const int tx = threadIdx.x & 31, ty = threadIdx.x >> 5;
#pragma unroll
    for (int j = 0; j < 4; ++j)
        tile[ty + j * 8][tx] = Wl[(size_t)(k0 + ty + j * 8) * N + n0 + tx];
    __syncthreads();
#pragma unroll
    for (int j = 0; j < 4; ++j)
        ol[(size_t)(n0 + ty + j * 8) * K + k0 + tx] = f2b(tile[tx][ty + j * 8]);
}

// ---------------- merged conv weight transpose: w[O,I,K] -> wtb[k][o][c] bf16 ----------------
__global__ __launch_bounds__(256) void wtransball_kernel(const float* __restrict__ dp_w1,
                                                         const float* __restrict__ dp_w2,
                                                         const float* __restrict__ dec_w1,
                                                         const float* __restrict__ dec_w2,
                                                         unsigned short* __restrict__ cw)
{
    int gid = blockIdx.x * 256 + threadIdx.x;
    if (gid >= 884736) return;
    const float* src; int CIN = 256, COUT, KS, idx;
    if (gid < 196608)      { src = dp_w1;  COUT = 256; KS = 3; idx = gid; }
    else if (gid < 393216) { src = dp_w2;  COUT = 256; KS = 3; idx = gid - 196608; }
    else if (gid < 720896) { src = dec_w1; COUT = 256; KS = 5; idx = gid - 393216; }
    else                   { src = dec_w2; COUT = 128; KS = 5; idx = gid - 720896; }
    int c = idx % CIN;
    int r = idx / CIN;
    int o = r % COUT;
    int k = r / COUT;
    cw[gid] = f2b(src[(o * CIN + c) * KS + k]);
}

// ---------------- bf16 MFMA GEMM (qkv / ff1): C = A @ B + bias ----------------
template<int NTILE, bool RELU, bool ABF16, bool CBF16, bool VOUT>
__global__ __launch_bounds__(256) void gemmbf_kernel(const void* __restrict__ A_,
                                                     const unsigned short* __restrict__ Bt,
                                                     const float* __restrict__ bias,
                                                     void* __restrict__ C_,
                                                     unsigned short* __restrict__ vt,
                                                     int M, int N, int K)
{
    constexpr int MT = (NTILE == 128) ? 2 : 1;
    __shared__ __align__(16) unsigned short Asb[128 * 32];
    __shared__ __align__(16) unsigned short Bsb[NTILE * 32];
    const int tid = threadIdx.x;
    const int lane = tid & 63, wave = tid >> 6;
    const int ln = lane & 31, hi = lane >> 5;
    const int row0 = blockIdx.y * 128, col0 = blockIdx.x * NTILE;
    const int mOff = (NTILE == 128) ? (wave >> 1) * 64 : wave * 32;
    const int nOff = (NTILE == 128) ? (wave & 1) * 64 : 0;
    const float* Af = (const float*)A_;
    const unsigned short* Ab = (const unsigned short*)A_;
    float* Cf = (float*)C_;
    unsigned short* Cb = (unsigned short*)C_;
    f32x16 acc[MT][2] = {};

    for (int k0 = 0; k0 < K; k0 += 32) {
#pragma unroll
        for (int it = 0; it < 2; ++it) {
            int u = it * 256 + tid;
            int m = u >> 2, blk = u & 3;
            unsigned short s8[8];
            if (ABF16) {
                *(uint4*)s8 = *(const uint4*)&Ab[(size_t)(row0 + m) * K + k0 + blk * 8];
            } else {
                float4 v0 = *(const float4*)&Af[(size_t)(row0 + m) * K + k0 + blk * 8];
                float4 v1 = *(const float4*)&Af[(size_t)(row0 + m) * K + k0 + blk * 8 + 4];
                s8[0] = f2b(v0.x); s8[1] = f2b(v0.y); s8[2] = f2b(v0.z); s8[3] = f2b(v0.w);
                s8[4] = f2b(v1.x); s8[5] = f2b(v1.y); s8[6] = f2b(v1.z); s8[7] = f2b(v1.w);
            }
            *(uint4*)&Asb[m * 32 + ((blk ^ SW(m)) << 3)] = *(uint4*)s8;
        }
#pragma unroll
        for (int it = 0; it < NTILE / 64; ++it) {
            int u = it * 256 + tid;
            int n = u >> 2, blk = u & 3;
            *(uint4*)&Bsb[n * 32 + ((blk ^ SW(n)) << 3)] =
                *(const uint4*)&Bt[(size_t)(col0 + n) * K + k0 + blk * 8];
        }
        __syncthreads();
#pragma unroll
        for (int kh = 0; kh < 2; ++kh) {
            const int kb = kh * 2 + hi;
            bf16x8 af[MT], bfr[2];
#pragma unroll
            for (int mt = 0; mt < MT; ++mt) {
                int r = mOff + mt * 32 + ln;
                af[mt] = *(const bf16x8*)&Asb[r * 32 + ((kb ^ SW(r)) << 3)];
            }
#pragma unroll
            for (int nt = 0; nt < 2; ++nt) {
                int r = nOff + nt * 32 + ln;
                bfr[nt] = *(const bf16x8*)&Bsb[r * 32 + ((kb ^ SW(r)) << 3)];
            }
#pragma unroll
            for (int mt = 0; mt < MT; ++mt)
#pragma unroll
                for (int nt = 0; nt < 2; ++nt)
                    acc[mt][nt] = __builtin_amdgcn_mfma_f32_32x32x16_bf16(
                        af[mt], bfr[nt], acc[mt][nt], 0, 0, 0);
        }
        __syncthreads();
    }
#pragma unroll
    for (int mt = 0; mt < MT; ++mt)
#pragma unroll
        for (int nt = 0; nt < 2; ++nt) {
            int col = col0 + nOff + nt * 32 + ln;
            float bi = bias[col];
#pragma unroll
            for (int g = 0; g < 4; ++g) {
                unsigned short s4[4];
#pragma unroll
                for (int r4 = 0; r4 < 4; ++r4) {
                    int row = row0 + mOff + mt * 32 + hi * 4 + g * 8 + r4;
                    float v = acc[mt][nt][g * 4 + r4] + bi;
                    if (RELU) v = fmaxf(v, 0.f);
                    if (CBF16) { s4[r4] = f2b(v); Cb[(size_t)row * N + col] = s4[r4]; }
                    else       Cf[(size_t)row * N + col] = v;
                }
                if (VOUT && col >= 512) {
                    int rowg = row0 + mOff + mt * 32 + hi * 4 + g * 8;
                    int b = rowg >> 9, t = rowg & (NT - 1);
                    int hh = (col - 512) >> 6, dd = (col - 512) & 63;
                    *(uint2*)&vt[((size_t)(b * NH + hh) * 64 + dd) * NT + t] = *(uint2*)s4;
                }
            }
        }
}

// ---------------- bf16 MFMA GEMM + residual + LayerNorm (proj / ff2) ----------------
// Block = 64 rows x full 256 cols; wave = 32r x 128c (MT=1, NT=4). x = LN(x + A@B + bias).
__global__ __launch_bounds__(256) void gemmln_kernel(const unsigned short* __restrict__ A,
                                                     const unsigned short* __restrict__ Bt,
                                                     const float* __restrict__ bias,
                                                     const float* __restrict__ lng,
                                                     const float* __restrict__ lnb,
                                                     float* __restrict__ x,
                                                     int K)
{
    __shared__ __align__(16) unsigned short Asb[64 * 32];
    __shared__ __align__(16) unsigned short Bsb[256 * 32];
    __shared__ float sred[64][2][2];
    const int tid = threadIdx.x;
    const int lane = tid & 63, wave = tid >> 6;
    const int ln = lane & 31, hi = lane >> 5;
    const int row0 = blockIdx.x * 64;
    const int mOff = (wave >> 1) * 32;
    const int colbase = (wave & 1) * 128;
    f32x16 acc[4] = {};

    for (int k0 = 0; k0 < K; k0 += 32) {
        {   // stage A: 64 rows
            int m = tid >> 2, blk = tid & 3;
            *(uint4*)&Asb[m * 32 + ((blk ^ SW(m)) << 3)] =
                *(const uint4*)&A[(size_t)(row0 + m) * K + k0 + blk * 8];
        }
#pragma unroll
        for (int it = 0; it < 4; ++it) {   // stage B: 256 rows
            int u = it * 256 + tid;
            int n = u >> 2, blk = u & 3;
            *(uint4*)&Bsb[n * 32 + ((blk ^ SW(n)) << 3)] =
                *(const uint4*)&Bt[(size_t)n * K + k0 + blk * 8];
        }
        __syncthreads();
#pragma unroll
        for (int kh = 0; kh < 2; ++kh) {
            const int kb = kh * 2 + hi;
            int r = mOff + ln;
            bf16x8 af = *(const bf16x8*)&Asb[r * 32 + ((kb ^ SW(r)) << 3)];
#pragma unroll
            for (int nt = 0; nt < 4; ++nt) {
                int rb = colbase + nt * 32 + ln;
                bf16x8 bfr = *(const bf16x8*)&Bsb[rb * 32 + ((kb ^ SW(rb)) << 3)];
                acc[nt] = __builtin_amdgcn_mfma_f32_32x32x16_bf16(af, bfr, acc[nt], 0, 0, 0);
            }
        }
        __syncthreads();
    }

    // epilogue: u = acc + bias + x; LN across 256 cols (2 waves per row group)
    float bi[4], gv[4], bv[4];
#pragma unroll
    for (int nt = 0; nt < 4; ++nt) {
        int col = colbase + nt * 32 + ln;
        bi[nt] = bias[col]; gv[nt] = lng[col]; bv[nt] = lnb[col];
    }
#pragma unroll
    for (int g = 0; g < 4; ++g)
#pragma unroll
        for (int r4 = 0; r4 < 4; ++r4) {
            int rl = mOff + hi * 4 + g * 8 + r4;
            size_t base = (size_t)(row0 + rl) * ND + colbase + ln;
#pragma unroll
            for (int nt = 0; nt < 4; ++nt)
                acc[nt][g * 4 + r4] += bi[nt] + x[base + nt * 32];
        }
    // per-row partial sums over this wave's 128 cols
#pragma unroll
    for (int g = 0; g < 4; ++g)
#pragma unroll
        for (int r4 = 0; r4 < 4; ++r4) {
            int i = g * 4 + r4;
            float ps = acc[0][i] + acc[1][i] + acc[2][i] + acc[3][i];
            float ps2 = acc[0][i] * acc[0][i] + acc[1][i] * acc[1][i]
                      + acc[2][i] * acc[2][i] + acc[3][i] * acc[3][i];
#pragma unroll
            for (int o = 1; o < 32; o <<= 1) {
                ps += __shfl_xor(ps, o);
                ps2 += __shfl_xor(ps2, o);
            }
            if (ln == 0) {
                int rl = mOff + hi * 4 + g * 8 + r4;
                sred[rl][wave & 1][0] = ps;
                sred[rl][wave & 1][1] = ps2;
            }
        }
    __syncthreads();
#pragma unroll
    for (int g = 0; g < 4; ++g)
#pragma unroll
        for (int r4 = 0; r4 < 4; ++r4) {
            int i = g * 4 + r4;
            int rl = mOff + hi * 4 + g * 8 + r4;
            float s = sred[rl][0][0] + sred[rl][1][0];
            float s2 = sred[rl][0][1] + sred[rl][1][1];
            float m = s * (1.0f / 256.0f);
            float var = fmaxf(s2 * (1.0f / 256.0f) - m * m, 0.0f);
            float rinv = 1.0f / sqrtf(var + 1e-5f);
            size_t base = (size_t)(row0 + rl) * ND + colbase + ln;
#pragma unroll
            for (int nt = 0; nt < 4; ++nt)
                x[base + nt * 32] = (acc[nt][i] - m) * rinv * gv[nt] + bv[nt];
        }
}

// ---------------- attention v3: bf16 MFMA flash, computes O^T ----------------
__global__ __launch_bounds__(256, 2) void attn3_kernel(const unsigned short* __restrict__ qkv,
                                                       const unsigned short* __restrict__ vt,
                                                       unsigned short* __restrict__ out)
{
    __shared__ __align__(16) unsigned short sP[4][32 * 64];
    const int tid = threadIdx.x;
    const int lane = tid & 63, wave = tid >> 6;
    const int ln = lane & 31, hi = lane >> 5;
    const int h = blockIdx.y, b = blockIdx.z;
    const int q0 = blockIdx.x * 128 + wave * 32;
    const size_t base = (size_t)b * NT * 768;
    const int qoff = h * 64;
    const unsigned short* vbh = vt + (size_t)(b * NH + h) * 64 * NT;

    bf16x8 qf[4];
#pragma unroll
    for (int s = 0; s < 4; ++s)
        qf[s] = *(const bf16x8*)&qkv[base + (size_t)(q0 + ln) * 768 + qoff + s * 16 + hi * 8];

    float mrow[16], lrow[16];
#pragma unroll
    for (int i = 0; i < 16; ++i) { mrow[i] = -1e30f; lrow[i] = 0.f; }
    f32x16 oacc[2] = {};
    const float sc = 0.18033688011112042f;   // 0.125 * log2(e)
    const int i0 = (ln & 3) | (((ln >> 3) & 3) << 2);
    const bool own = (((ln >> 2) & 1) == hi);
    unsigned short* Pw = &sP[wave][0];

    for (int ch = 0; ch < 8; ++ch) {
        const int s0 = ch * 64;
        f32x16 sacc[2] = {};
#pragma unroll
        for (int ct = 0; ct < 2; ++ct)
#pragma unroll
            for (int s = 0; s < 4; ++s) {
                bf16x8 kf = *(const bf16x8*)&qkv[base + (size_t)(s0 + ct * 32 + ln) * 768
                                                 + 256 + qoff + s * 16 + hi * 8];
                sacc[ct] = __builtin_amdgcn_mfma_f32_32x32x16_bf16(qf[s], kf, sacc[ct], 0, 0, 0);
            }
        float alpha[16];
#pragma unroll
        for (int i = 0; i < 16; ++i) {
            float s20 = sacc[0][i] * sc, s21 = sacc[1][i] * sc;
            float mx = fmaxf(s20, s21);
#pragma unroll
            for (int o = 1; o < 32; o <<= 1) mx = fmaxf(mx, __shfl_xor(mx, o));
            float mn = fmaxf(mrow[i], mx);
            alpha[i] = exp2f(mrow[i] - mn);
            mrow[i] = mn;
            float p0 = exp2f(s20 - mn);
            float p1 = exp2f(s21 - mn);
            sacc[0][i] = p0; sacc[1][i] = p1;
            float rs = p0 + p1;
#pragma unroll
            for (int o = 1; o < 32; o <<= 1) rs += __shfl_xor(rs, o);
            lrow[i] = lrow[i] * alpha[i] + rs;
        }
#pragma unroll
        for (int ct = 0; ct < 2; ++ct) {
            int kb = ct * 4 + (ln >> 3), k7 = ln & 7;
#pragma unroll
            for (int i = 0; i < 16; ++i) {
                int q = (i & 3) + 8 * (i >> 2) + 4 * hi;
                Pw[q * 64 + (((kb ^ (q & 7)) << 3) | k7)] = f2b(sacc[ct][i]);
            }
        }
        __syncthreads();
        {
            float av = alpha[i0];
            float ao = __shfl_xor(av, 32);
            float aq = own ? av : ao;
#pragma unroll
            for (int ct = 0; ct < 2; ++ct)
#pragma unroll
                for (int i = 0; i < 16; ++i)
                    oacc[ct][i] *= aq;
        }
#pragma unroll
        for (int s = 0; s < 4; ++s) {
            bf16x8 pf = *(const bf16x8*)&Pw[ln * 64 + (((s * 2 + hi) ^ (ln & 7)) << 3)];
#pragma unroll
            for (int ct = 0; ct < 2; ++ct) {
                bf16x8 vf = *(const bf16x8*)&vbh[(size_t)(ct * 32 + ln) * NT + s0 + s * 16 + hi * 8];
                oacc[ct] = __builtin_amdgcn_mfma_f32_32x32x16_bf16(vf, pf, oacc[ct], 0, 0, 0);
            }
        }
        __syncthreads();
    }
    float lv = lrow[i0];
    float lo = __shfl_xor(lv, 32);
    float linv = 1.0f / (own ? lv : lo);
    const int q = q0 + ln;
#pragma unroll
    for (int ct = 0; ct < 2; ++ct)
#pragma unroll
        for (int i = 0; i < 16; ++i) {
            int d = ct * 32 + (i & 3) + 8 * (i >> 2) + 4 * hi;
            out[(size_t)(b * NT + q) * ND + qoff + d] = f2b(oacc[ct][i] * linv);
        }
}

// ---------------- fused emotion MLP + add: x += MLP(emotion)[b] ----------------
__global__ __launch_bounds__(256) void fuse_kernel(const float* __restrict__ emo,
                                                   const float* __restrict__ We1,
                                                   const float* __restrict__ be1,
                                                   const float* __restrict__ We2,
                                                   const float* __restrict__ be2,
                                                   float* __restrict__ x)
{
    const int row = blockIdx.x;
    const int d = threadIdx.x;
    const float em = emo[row >> 9];
    float acc = be2[d];
    for (int j = 0; j < 64; ++j) {
        float h = fmaxf(em * We1[j] + be1[j], 0.0f);
        acc = fmaf(h, We2[j * ND + d], acc);
    }
    x[(size_t)row * ND + d] += acc;
}

// ---------------- unified bf16 MFMA conv: tile 256t x 64o, wave mt=2, B in LDS ----------------
template<int CIN, int KS, bool IN_BF16, bool OUT_BF16, bool BN>
__global__ __launch_bounds__(256) void convk_kernel(const void* __restrict__ in_,
                                                    const unsigned short* __restrict__ wtb,
                                                    const float* __restrict__ bias,
                                                    const float* __restrict__ bng,
                                                    const float* __restrict__ bnb,
                                                    const float* __restrict__ bnm,
                                                    const float* __restrict__ bnv,
                                                    void* __restrict__ out_,
                                                    int T, int COUT)
{
    constexpr int PAD = (KS - 1) / 2;
    constexpr int TEXT = 256 + KS - 1;
    __shared__ __align__(16) unsigned short Asb[TEXT * 32];
    __shared__ __align__(16) unsigned short Bsb[KS * 64 * 32];
    const int tid = threadIdx.x;
    const int lane = tid & 63, wave = tid >> 6;
    const int ln = lane & 31, hi = lane >> 5;
    const int b = blockIdx.z;
    const int t0 = blockIdx.x * 256;
    const int o0 = blockIdx.y * 64;
    const int mOff = wave * 64;
    const float* inf = (const float*)in_;
    const unsigned short* inb = (const unsigned short*)in_;
    float* outf = (float*)out_;
    unsigned short* outb = (unsigned short*)out_;
    f32x16 acc[2][2] = {};

    for (int cc = 0; cc < CIN; cc += 32) {
        for (int u = tid; u < TEXT * 4; u += 256) {
            int t = u >> 2, blk = u & 3;
            int tg = t0 - PAD + t;
            unsigned short s8[8] = {0, 0, 0, 0, 0, 0, 0, 0};
            if (tg >= 0 && tg < T) {
                if (IN_BF16) {
                    *(uint4*)s8 = *(const uint4*)&inb[((size_t)(b * T) + tg) * CIN + cc + blk * 8];
                } else {
                    float4 v0 = *(const float4*)&inf[((size_t)(b * T) + tg) * CIN + cc + blk * 8];
                    float4 v1 = *(const float4*)&inf[((size_t)(b * T) + tg) * CIN + cc + blk * 8 + 4];
                    s8[0] = f2b(v0.x); s8[1] = f2b(v0.y); s8[2] = f2b(v0.z); s8[3] = f2b(v0.w);
                    s8[4] = f2b(v1.x); s8[5] = f2b(v1.y); s8[6] = f2b(v1.z); s8[7] = f2b(v1.w);
                }
            }
            *(uint4*)&Asb[t * 32 + ((blk ^ SW(t)) << 3)] = *(uint4*)s8;
        }
        for (int u = tid; u < KS * 256; u += 256) {
            int row = u >> 2, blk = u & 3;    // row = k*64 + o
            int k = row >> 6, o = row & 63;
            *(uint4*)&Bsb[row * 32 + ((blk ^ SW(row)) << 3)] =
                *(const uint4*)&wtb[((size_t)k * COUT + o0 + o) * CIN + cc + blk * 8];
        }
        __syncthreads();
#pragma unroll
        for (int kh = 0; kh < 2; ++kh) {
            const int kb = kh * 2 + hi;
#pragma unroll
            for (int tap = 0; tap < KS; ++tap) {
                bf16x8 af[2];
#pragma unroll
                for (int mt = 0; mt < 2; ++mt) {
                    int r = mOff + mt * 32 + ln + tap;
                    af[mt] = *(const bf16x8*)&Asb[r * 32 + ((kb ^ SW(r)) << 3)];
                }
#pragma unroll
                for (int nt = 0; nt < 2; ++nt) {
                    int rb = tap * 64 + nt * 32 + ln;
                    bf16x8 bfr = *(const bf16x8*)&Bsb[rb * 32 + ((kb ^ SW(rb)) << 3)];
#pragma unroll
                    for (int mt = 0; mt < 2; ++mt)
                        acc[mt][nt] = __builtin_amdgcn_mfma_f32_32x32x16_bf16(
                            af[mt], bfr, acc[mt][nt], 0, 0, 0);
                }
            }
        }
        __syncthreads();
    }
#pragma unroll
    for (int nt = 0; nt < 2; ++nt) {
        int col = o0 + nt * 32 + ln;
        float bi = bias[col];
        float scv = 1.f, shv = 0.f;
        if (BN) {
            scv = bng[col] / sqrtf(bnv[col] + 1e-5f);
            shv = bnb[col] - bnm[col] * scv;
        }
#pragma unroll
        for (int mt = 0; mt < 2; ++mt)
#pragma unroll
            for (int g = 0; g < 4; ++g)
#pragma unroll
                for (int r4 = 0; r4 < 4; ++r4) {
                    int row = t0 + mOff + mt * 32 + hi * 4 + g * 8 + r4;
                    float v = fmaxf(acc[mt][nt][g * 4 + r4] + bi, 0.f);
                    if (BN) v = v * scv + shv;
                    if (OUT_BF16) outb[((size_t)(b * T) + row) * COUT + col] = f2b(v);
                    else          outf[((size_t)(b * T) + row) * COUT + col] = v;
                }
    }
}

// ---------------- regulated-sequence materialization ----------------
__global__ __launch_bounds__(256) void reg_kernel(const float* __restrict__ x,
                                                  const int* __restrict__ tok,
                                                  unsigned short* __restrict__ reg)
{
    const int wave = threadIdx.x >> 6, lane = threadIdx.x & 63;
    const int row = blockIdx.x * 4 + wave;
    const int tk = tok[row];
    const int b = row >> 11;
    const int c4 = lane * 4;
    unsigned short s4[4] = {0, 0, 0, 0};
    if (tk >= 0) {
        float4 v = *(const float4*)&x[((size_t)(b * NT) + tk) * ND + c4];
        s4[0] = f2b(v.x); s4[1] = f2b(v.y); s4[2] = f2b(v.z); s4[3] = f2b(v.w);
    }
    *(uint2*)&reg[(size_t)row * ND + c4] = *(uint2*)s4;
}

// ---------------- duration: wave-per-row dot -> dur ----------------
__global__ __launch_bounds__(256) void dur_kernel(const float* __restrict__ h2,
                                                  const float* __restrict__ wo,
                                                  const float* __restrict__ bo,
                                                  int* __restrict__ dur)
{
    const int wave = threadIdx.x >> 6, lane = threadIdx.x & 63;
    const int row = blockIdx.x * 4 + wave;
    const int c4 = lane * 4;
    float4 h = *(const float4*)&h2[(size_t)row * ND + c4];
    float4 w4 = *(const float4*)&wo[c4];
    float s = h.x * w4.x + h.y * w4.y + h.z * w4.z + h.w * w4.w;
#pragma unroll
    for (int o = 1; o < 64; o <<= 1) s += __shfl_xor(s, o);
    if (lane == 0) {
        float d = rintf(expf(s + bo[0]));
        d = fminf(fmaxf(d, 1.0f), 8.0f);
        dur[row] = (int)d;
    }
}

// ---------------- fused scan + token map: one block per batch ----------------
__global__ __launch_bounds__(256) void scantok_kernel(const int* __restrict__ dur,
                                                      int* __restrict__ tok)
{
    __shared__ int st[NT];
    __shared__ int tot;
    const int b = blockIdx.x, tid = threadIdx.x;
    if (tid == 0) {
        int a = 0;
        for (int t = 0; t < NT; ++t) { st[t] = a; a += dur[b * NT + t]; }
        tot = a;
    }
    __syncthreads();
    for (int p = tid; p < TOUT; p += 256) {
        int res = -1;
        if (p < tot) {
            int lo = 0, hi = NT - 1;
            while (lo < hi) {
                int mid = (lo + hi + 1) >> 1;
                if (st[mid] <= p) lo = mid; else hi = mid - 1;
            }
            res = lo;
        }
        tok[b * TOUT + p] = res;
    }
}

// ---------------- decoder conv3: wave-per-output, coalesced ----------------
__global__ __launch_bounds__(256) void conv3_kernel(const unsigned short* __restrict__ in,
                                                    const float* __restrict__ w,
                                                    const float* __restrict__ bias,
                                                    float* __restrict__ out)
{
    const int wave = threadIdx.x >> 6, lane = threadIdx.x & 63;
    const int gid = blockIdx.x * 4 + wave;
    const int b = gid >> 11, t = gid & (TOUT - 1);
    const int c = lane * 2;
    float w0[5], w1[5];
#pragma unroll
    for (int k = 0; k < 5; ++k) { w0[k] = w[c * 5 + k]; w1[k] = w[(c + 1) * 5 + k]; }
    float acc = 0.f;
#pragma unroll
    for (int k = 0; k < 5; ++k) {
        int t2 = t + k - 2;
        if (t2 < 0 || t2 >= TOUT) continue;
        unsigned int u = *(const unsigned int*)&in[((size_t)(b * TOUT) + t2) * 128 + c];
        acc = fmaf(b2f((unsigned short)(u & 0xFFFF)), w0[k], acc);
        acc = fmaf(b2f((unsigned short)(u >> 16)), w1[k], acc);
    }
#pragma unroll
    for (int o = 1; o < 64; o <<= 1) acc += __shfl_xor(acc, o);
    if (lane == 0) out[gid] = acc + bias[0];
}

// ---------------- orchestration ----------------
extern "C" void kernel_launch(void* const* d_in, const int* in_sizes, int n_in,
                              void* d_out, int out_size, void* d_ws, size_t ws_size,
                              hipStream_t stream)
{
    const int*   text    = (const int*)d_in[0];
    const float* emotion = (const float*)d_in[1];
    const float* emb     = (const float*)d_in[2];
    const float* Wqkv    = (const float*)d_in[3];
    const float* bqkv    = (const float*)d_in[4];
    const float* Wo      = (const float*)d_in[5];
    const float* bo      = (const float*)d_in[6];
    const float* W1      = (const float*)d_in[7];
    const float* b1      = (const float*)d_in[8];
    const float* W2      = (const float*)d_in[9];
    const float* b2      = (const float*)d_in[10];
    const float* ln1g    = (const float*)d_in[11];
    const float* ln1b    = (const float*)d_in[12];
    const float* ln2g    = (const float*)d_in[13];
    const float* ln2b    = (const float*)d_in[14];
    const float* We1     = (const float*)d_in[15];
    const float* be1     = (const float*)d_in[16];
    const float* We2     = (const float*)d_in[17];
    const float* be2     = (const float*)d_in[18];
    const float* dp_w1   = (const float*)d_in[19];
    const float* dp_b1   = (const float*)d_in[20];
    const float* dp_g1   = (const float*)d_in[21];
    const float* dp_bt1  = (const float*)d_in[22];
    const float* dp_m1   = (const float*)d_in[23];
    const float* dp_v1   = (const float*)d_in[24];
    const float* dp_w2   = (const float*)d_in[25];
    const float* dp_b2   = (const float*)d_in[26];
    const float* dp_g2   = (const float*)d_in[27];
    const float* dp_bt2  = (const float*)d_in[28];
    const float* dp_m2   = (const float*)d_in[29];
    const float* dp_v2   = (const float*)d_in[30];
    const float* dp_wo   = (const float*)d_in[31];
    const float* dp_bo   = (const float*)d_in[32];
    const float* dec_w3  = (const float*)d_in[37];
    const float* dec_b1  = (const float*)d_in[34];
    const float* dec_b2  = (const float*)d_in[36];
    const float* dec_b3  = (const float*)d_in[38];

    float* ws   = (float*)d_ws;
    float* x    = ws + OFF_X;
    unsigned short* ffhB = (unsigned short*)(ws + OFF_FFH);
    unsigned short* Wbt  = (unsigned short*)(ws + OFF_WBT);
    unsigned short* cw   = (unsigned short*)(ws + OFF_CWT);
    unsigned short* wtbdp1 = cw;
    unsigned short* wtbdp2 = cw + 196608;
    unsigned short* wtb1   = cw + 393216;
    unsigned short* wtb2   = cw + 720896;
    unsigned short* qkvB = (unsigned short*)(ws + OFF_QKV);
    unsigned short* vtb  = qkvB + 12582912;
    unsigned short* regB = qkvB;
    float* attb = ws + OFF_ATTN;
    float* prjb = ws + OFF_PROJ;
    unsigned short* attbB = (unsigned short*)attb;
    unsigned short* h1b  = (unsigned short*)attb;
    unsigned short* d1b  = ffhB;
    unsigned short* d2b  = (unsigned short*)attb;
    int*   ip     = (int*)(ws + OFF_INT);
    int*   durb   = ip;
    int*   tokb   = ip + 16384;

    const int M = NB * NT;   // 16384

    embed_kernel<<<M, 256, 0, stream>>>(text, emb, x);
    wqall_kernel<<<dim3(768, 6), 256, 0, stream>>>(Wqkv, Wo, W1, W2, Wbt);
    wtransball_kernel<<<3456, 256, 0, stream>>>(dp_w1, dp_w2,
                                                (const float*)d_in[33], (const float*)d_in[35], cw);

    for (int l = 0; l < NLAYER; ++l) {
        const unsigned short* WQ  = Wbt + (size_t)l * 786432;
        const unsigned short* WO  = WQ + 196608;
        const unsigned short* WF1 = WQ + 262144;
        const unsigned short* WF2 = WQ + 524288;
        gemmbf_kernel<128, false, false, true, true><<<dim3(6, 128), 256, 0, stream>>>(
            x, WQ, bqkv + l * 768, qkvB, vtb, M, 768, 256);
        attn3_kernel<<<dim3(NT / 128, NH, NB), 256, 0, stream>>>(qkvB, vtb, attbB);
        gemmln_kernel<<<M / 64, 256, 0, stream>>>(
            attbB, WO, bo + l * 256, ln1g + l * ND, ln1b + l * ND, x, 256);
        gemmbf_kernel<128, true, false, true, false><<<dim3(8, 128), 256, 0, stream>>>(
            x, WF1, b1 + l * 1024, ffhB, nullptr, M, 1024, 256);
        gemmln_kernel<<<M / 64, 256, 0, stream>>>(
            ffhB, WF2, b2 + l * 256, ln2g + l * ND, ln2b + l * ND, x, 1024);
    }

    fuse_kernel<<<M, 256, 0, stream>>>(emotion, We1, be1, We2, be2, x);

    // duration predictor convs: bf16 MFMA, BN epilogue (dp2 outputs fp32 for dur)
    convk_kernel<256, 3, false, true, true><<<dim3(2, 4, NB), 256, 0, stream>>>(
        x, wtbdp1, dp_b1, dp_g1, dp_bt1, dp_m1, dp_v1, h1b, NT, 256);
    convk_kernel<256, 3, true, false, true><<<dim3(2, 4, NB), 256, 0, stream>>>(
        h1b, wtbdp2, dp_b2, dp_g2, dp_bt2, dp_m2, dp_v2, prjb, NT, 256);
    dur_kernel<<<M / 4, 256, 0, stream>>>(prjb, dp_wo, dp_bo, durb);
    scantok_kernel<<<NB, 256, 0, stream>>>(durb, tokb);

    // decoder: regulated gather then bf16 MFMA convs
    reg_kernel<<<NB * TOUT / 4, 256, 0, stream>>>(x, tokb, regB);
    convk_kernel<256, 5, true, true, false><<<dim3(TOUT / 256, 4, NB), 256, 0, stream>>>(
        regB, wtb1, dec_b1, nullptr, nullptr, nullptr, nullptr, d1b, TOUT, 256);
    convk_kernel<256, 5, true, true, false><<<dim3(TOUT / 256, 2, NB), 256, 0, stream>>>(
        d1b, wtb2, dec_b2, nullptr, nullptr, nullptr, nullptr, d2b, TOUT, 128);
    conv3_kernel<<<NB * TOUT / 4, 256, 0, stream>>>(d2b, dec_w3, dec_b3, (float*)d_out);
}